// Round 3
// baseline (1864.018 us; speedup 1.0000x reference)
//
#include <hip/hip_runtime.h>
#include <hip/hip_bf16.h>
#include <cstdint>
#include <cstddef>

// Sizes: N=256, Cin=64, T=64, V=25, Cout=128, Tout=32
namespace {
constexpr float  EPS_ = 1e-5f;
constexpr size_t SZ_A = 52428800;   // 256*128*64*25
constexpr size_t SZ_C = 26214400;   // 256*128*32*25
}

#define OUTER16(wv, xv) \
  acc[0][0]=fmaf(wv.x,xv.x,acc[0][0]); acc[0][1]=fmaf(wv.x,xv.y,acc[0][1]); \
  acc[0][2]=fmaf(wv.x,xv.z,acc[0][2]); acc[0][3]=fmaf(wv.x,xv.w,acc[0][3]); \
  acc[1][0]=fmaf(wv.y,xv.x,acc[1][0]); acc[1][1]=fmaf(wv.y,xv.y,acc[1][1]); \
  acc[1][2]=fmaf(wv.y,xv.z,acc[1][2]); acc[1][3]=fmaf(wv.y,xv.w,acc[1][3]); \
  acc[2][0]=fmaf(wv.z,xv.x,acc[2][0]); acc[2][1]=fmaf(wv.z,xv.y,acc[2][1]); \
  acc[2][2]=fmaf(wv.z,xv.z,acc[2][2]); acc[2][3]=fmaf(wv.z,xv.w,acc[2][3]); \
  acc[3][0]=fmaf(wv.w,xv.x,acc[3][0]); acc[3][1]=fmaf(wv.w,xv.y,acc[3][1]); \
  acc[3][2]=fmaf(wv.w,xv.z,acc[3][2]); acc[3][3]=fmaf(wv.w,xv.w,acc[3][3]);

// ---------------- prep: msk = tanh(fm)+1 (transposed), weight transposes ----------------
__global__ __launch_bounds__(256) void k_prep(
    const float* __restrict__ fm, const float* __restrict__ dw,
    const float* __restrict__ rw, const float* __restrict__ tw,
    float* __restrict__ mskT, float* __restrict__ dwT,
    float* __restrict__ rwT, float* __restrict__ tlT) {
  int i = blockIdx.x * 256 + threadIdx.x;
  if (i < 1600) { int w = i % 25, c = i / 25; mskT[c*25+w] = tanhf(fm[w*64+c]) + 1.0f; }
  if (i < 8192) { int o = i & 127, c = i >> 7; dwT[c*128+o] = dw[o*64+c]; rwT[c*128+o] = rw[o*64+c]; }
  if (i < 16384){ int o = i & 127, c = i >> 7; tlT[c*128+o] = tw[o*128+c]; }
}

// ---------------- second moments of x: Sxa (all t), Sxe (even t), col sums ----------------
__global__ __launch_bounds__(256) void k_mom(const float* __restrict__ x,
    float* __restrict__ Sxa, float* __restrict__ Sxe,
    float* __restrict__ suma, float* __restrict__ sume) {
  __shared__ float xs[64][208];
  const int n = blockIdx.x >> 1, half = blockIdx.x & 1, tid = threadIdx.x;
  const int ci = (tid >> 4) * 4, cj = (tid & 15) * 4;
  float ae[4][4], ao[4][4], se[4], so[4];
  #pragma unroll
  for (int i = 0; i < 4; i++) {
    se[i] = 0.f; so[i] = 0.f;
    #pragma unroll
    for (int j = 0; j < 4; j++) { ae[i][j] = 0.f; ao[i][j] = 0.f; }
  }

  for (int tc = half*32; tc < half*32 + 32; tc += 8) {
    for (int e = tid; e < 3200; e += 256) {
      int c = e / 50, q = e - c*50;
      *(float4*)&xs[c][q*4] = *(const float4*)&x[(size_t)n*102400 + (size_t)c*1600 + tc*25 + q*4];
    }
    __syncthreads();
    for (int s = 0; s < 200; s += 4) {
      float4 ra0 = *(const float4*)&xs[ci+0][s];
      float4 ra1 = *(const float4*)&xs[ci+1][s];
      float4 ra2 = *(const float4*)&xs[ci+2][s];
      float4 ra3 = *(const float4*)&xs[ci+3][s];
      float4 rb0 = *(const float4*)&xs[cj+0][s];
      float4 rb1 = *(const float4*)&xs[cj+1][s];
      float4 rb2 = *(const float4*)&xs[cj+2][s];
      float4 rb3 = *(const float4*)&xs[cj+3][s];
      #pragma unroll
      for (int k = 0; k < 4; k++) {
        const int tpar = (tc + (s + k) / 25) & 1;
        float xi[4], xj[4];
        xi[0] = ((const float*)&ra0)[k]; xi[1] = ((const float*)&ra1)[k];
        xi[2] = ((const float*)&ra2)[k]; xi[3] = ((const float*)&ra3)[k];
        xj[0] = ((const float*)&rb0)[k]; xj[1] = ((const float*)&rb1)[k];
        xj[2] = ((const float*)&rb2)[k]; xj[3] = ((const float*)&rb3)[k];
        if (!tpar) {
          #pragma unroll
          for (int i = 0; i < 4; i++) {
            #pragma unroll
            for (int j = 0; j < 4; j++) ae[i][j] = fmaf(xi[i], xj[j], ae[i][j]);
          }
          if (cj == 0) {
            #pragma unroll
            for (int i = 0; i < 4; i++) se[i] += xi[i];
          }
        } else {
          #pragma unroll
          for (int i = 0; i < 4; i++) {
            #pragma unroll
            for (int j = 0; j < 4; j++) ao[i][j] = fmaf(xi[i], xj[j], ao[i][j]);
          }
          if (cj == 0) {
            #pragma unroll
            for (int i = 0; i < 4; i++) so[i] += xi[i];
          }
        }
      }
    }
    __syncthreads();
  }
  #pragma unroll
  for (int i = 0; i < 4; i++) {
    #pragma unroll
    for (int j = 0; j < 4; j++) {
      atomicAdd(&Sxa[(ci+i)*64 + cj+j], ae[i][j] + ao[i][j]);
      atomicAdd(&Sxe[(ci+i)*64 + cj+j], ae[i][j]);
    }
  }
  if (cj == 0) {
    #pragma unroll
    for (int i = 0; i < 4; i++) {
      atomicAdd(&suma[ci+i], se[i] + so[i]);
      atomicAdd(&sume[ci+i], se[i]);
    }
  }
}

// ---------------- finalize analytic bn stats for down & res ----------------
__global__ __launch_bounds__(128) void k_fin(
    const float* __restrict__ dw, const float* __restrict__ dbg, const float* __restrict__ dbb,
    const float* __restrict__ rw, const float* __restrict__ rbg, const float* __restrict__ rbb,
    const float* __restrict__ Sxa, const float* __restrict__ Sxe,
    const float* __restrict__ suma, const float* __restrict__ sume,
    float* __restrict__ scD, float* __restrict__ shD,
    float* __restrict__ scR, float* __restrict__ shR) {
  const int o = threadIdx.x;
  const float iSa = 1.0f/409600.0f, iSe = 1.0f/204800.0f;
  {
    float mu = 0.f, q = 0.f;
    for (int c = 0; c < 64; c++) {
      float wv = dw[o*64+c];
      mu = fmaf(wv, suma[c], mu);
      float p = 0.f;
      for (int c2 = 0; c2 < 64; c2++) p = fmaf(Sxa[c*64+c2], dw[o*64+c2], p);
      q = fmaf(wv, p, q);
    }
    mu *= iSa; q *= iSa;
    float var = fmaxf(q - mu*mu, 0.f);
    float sc = dbg[o] * rsqrtf(var + EPS_);
    scD[o] = sc; shD[o] = dbb[o] - mu*sc;
  }
  {
    float mu = 0.f, q = 0.f;
    for (int c = 0; c < 64; c++) {
      float wv = rw[o*64+c];
      mu = fmaf(wv, sume[c], mu);
      float p = 0.f;
      for (int c2 = 0; c2 < 64; c2++) p = fmaf(Sxe[c*64+c2], rw[o*64+c2], p);
      q = fmaf(wv, p, q);
    }
    mu *= iSe; q *= iSe;
    float var = fmaxf(q - mu*mu, 0.f);
    float sc = rbg[o] * rsqrtf(var + EPS_);
    scR[o] = sc; shR[o] = rbb[o] - mu*sc;
  }
}

// ---------------- K1: GCN GEMM (shifted+masked) -> A bf16 ----------------
__global__ __launch_bounds__(256) void k1(
    const float* __restrict__ x, const float* __restrict__ Wl,
    const float* __restrict__ mskT, __hip_bfloat16* __restrict__ A) {
  __shared__ float xm[64][28];
  const int t = blockIdx.x, n = blockIdx.y, tid = threadIdx.x;
  for (int e = tid; e < 192; e += 256) { xm[e/3][25 + e%3] = 0.f; }
  const float* xbase = x + (size_t)n*102400 + t*25;
  for (int e = tid; e < 1600; e += 256) {
    int c = e / 25, w = e - c*25;
    int cm = c; if (cm >= 50) cm -= 50; else if (cm >= 25) cm -= 25;
    int vs = w + cm; if (vs >= 25) vs -= 25;
    xm[c][w] = xbase[(size_t)c*1600 + vs] * mskT[c*25 + w];
  }
  __syncthreads();
  const int dq = tid >> 3, vq = tid & 7;
  if (vq >= 7) return;
  const int d0 = dq*4, v0 = vq*4;
  float acc[4][4];
  #pragma unroll
  for (int j = 0; j < 4; j++) {
    #pragma unroll
    for (int k = 0; k < 4; k++) acc[j][k] = 0.f;
  }
  #pragma unroll 4
  for (int c = 0; c < 64; c++) {
    const float4 xv = *(const float4*)&xm[c][v0];
    const float4 wv = *(const float4*)&Wl[c*128 + d0];
    OUTER16(wv, xv);
  }
  #pragma unroll
  for (int j = 0; j < 4; j++) {
    int d = d0 + j;
    int dm = d; while (dm >= 25) dm -= 25;
    __hip_bfloat16* row = A + ((size_t)n*128 + d)*1600 + t*25;
    #pragma unroll
    for (int k = 0; k < 4; k++) {
      int w = v0 + k;
      if (w < 25) { int v = w + dm; if (v >= 25) v -= 25; row[v] = __float2bfloat16(acc[j][k]); }
    }
  }
}

// ---------------- gcn stats: per-(d,v) sums over (n,t), bf16 input ----------------
__global__ __launch_bounds__(256) void k_statsA(const __hip_bfloat16* __restrict__ A,
                                                float* __restrict__ gs1, float* __restrict__ gs2) {
  const int d = blockIdx.x, nc = blockIdx.y, tid = threadIdx.x;
  __shared__ float sl[64][26];
  float s1 = 0.f, s2 = 0.f;
  const int v = tid % 25, ts = tid / 25;
  for (int n = nc*32; n < nc*32 + 32; n++) {
    const __hip_bfloat16* base = A + ((size_t)n*128 + d)*1600;
    for (int e = tid; e < 1600; e += 256) sl[e/25][e%25] = __bfloat162float(base[e]);
    __syncthreads();
    if (tid < 250) {
      for (int t = ts; t < 64; t += 10) { float val = sl[t][v]; s1 += val; s2 = fmaf(val, val, s2); }
    }
    __syncthreads();
  }
  __shared__ float r1[25], r2[25];
  if (tid < 25) { r1[tid] = 0.f; r2[tid] = 0.f; }
  __syncthreads();
  if (tid < 250) { atomicAdd(&r1[v], s1); atomicAdd(&r2[v], s2); }
  __syncthreads();
  if (tid < 25) { atomicAdd(&gs1[d*25 + tid], r1[tid]); atomicAdd(&gs2[d*25 + tid], r2[tid]); }
}

// ---------------- per-channel stats for bf16 NCHW tensor ----------------
__global__ __launch_bounds__(256) void k_statsP(const __hip_bfloat16* __restrict__ P, int len,
                                                float* __restrict__ s1g, float* __restrict__ s2g) {
  const int o = blockIdx.x, nc = blockIdx.y, tid = threadIdx.x;
  float s1 = 0.f, s2 = 0.f;
  for (int n = nc*16; n < nc*16 + 16; n++) {
    const __hip_bfloat16* base = P + ((size_t)n*128 + o)*(size_t)len;
    for (int i = tid; i < len; i += 256) { float v = __bfloat162float(base[i]); s1 += v; s2 = fmaf(v, v, s2); }
  }
  __shared__ float r1[256], r2[256];
  r1[tid] = s1; r2[tid] = s2; __syncthreads();
  for (int s = 128; s > 0; s >>= 1) {
    if (tid < s) { r1[tid] += r1[tid+s]; r2[tid] += r2[tid+s]; }
    __syncthreads();
  }
  if (tid == 0) { atomicAdd(&s1g[o], r1[0]); atomicAdd(&s2g[o], r2[0]); }
}

// ---------------- K2: down GEMM + y = relu(bn1d(h) + bn2d(down)), A in-place ----------------
__global__ __launch_bounds__(256) void k2(
    const float* __restrict__ x, const float* __restrict__ dwT,
    const float* __restrict__ gg, const float* __restrict__ gb,
    const float* __restrict__ gs1, const float* __restrict__ gs2,
    const float* __restrict__ scD, const float* __restrict__ shD,
    __hip_bfloat16* __restrict__ A) {
  __shared__ float xs[64][28];
  const int t = blockIdx.x, n = blockIdx.y, tid = threadIdx.x;
  for (int e = tid; e < 192; e += 256) { xs[e/3][25 + e%3] = 0.f; }
  const float* xbase = x + (size_t)n*102400 + t*25;
  for (int e = tid; e < 1600; e += 256) {
    int c = e / 25, v = e - c*25;
    xs[c][v] = xbase[(size_t)c*1600 + v];
  }
  __syncthreads();
  const int dq = tid >> 3, vq = tid & 7;
  if (vq >= 7) return;
  const int d0 = dq*4, v0 = vq*4;
  float acc[4][4];
  #pragma unroll
  for (int j = 0; j < 4; j++) {
    #pragma unroll
    for (int k = 0; k < 4; k++) acc[j][k] = 0.f;
  }
  #pragma unroll 4
  for (int c = 0; c < 64; c++) {
    const float4 xv = *(const float4*)&xs[c][v0];
    const float4 wv = *(const float4*)&dwT[c*128 + d0];
    OUTER16(wv, xv);
  }
  const float iG = 1.0f/16384.0f;
  #pragma unroll
  for (int j = 0; j < 4; j++) {
    int d = d0 + j;
    __hip_bfloat16* row = A + ((size_t)n*128 + d)*1600 + t*25;
    float sD = scD[d], hD = shD[d];
    #pragma unroll
    for (int k = 0; k < 4; k++) {
      int v = v0 + k;
      if (v < 25) {
        float h = __bfloat162float(row[v]);
        int f = d*25 + v;
        float m = gs1[f]*iG;
        float var = fmaxf(gs2[f]*iG - m*m, 0.f);
        float r = rsqrtf(var + EPS_);
        int fg = v*128 + d;
        float hb = (h - m)*r*gg[fg] + gb[fg];
        float dd = fmaf(acc[j][k], sD, hD);
        row[v] = __float2bfloat16(fmaxf(hb + dd, 0.f));
      }
    }
  }
}

// ---------------- K3: bn(ts) + shift(theta_in,1) + tl GEMM + relu -> Z bf16 (in d_out) ----------------
__global__ __launch_bounds__(256) void k3(
    const __hip_bfloat16* __restrict__ Y,
    const float* __restrict__ thin, const float* __restrict__ tg, const float* __restrict__ tb,
    const float* __restrict__ ts1, const float* __restrict__ ts2,
    const float* __restrict__ tlT, const float* __restrict__ tlb,
    __hip_bfloat16* __restrict__ Z) {
  __shared__ float zsl[128][28];
  const int t = blockIdx.x, n = blockIdx.y, tid = threadIdx.x;
  const float iS = 1.0f/409600.0f;
  for (int e = tid; e < 384; e += 256) { zsl[e/3][25 + e%3] = 0.f; }
  for (int e = tid; e < 3200; e += 256) {
    int c = e / 25, v = e - c*25;
    float m  = ts1[c]*iS;
    float var = fmaxf(ts2[c]*iS - m*m, 0.f);
    float rs = rsqrtf(var + EPS_);
    float sc = rs * tg[c];
    float sh = tb[c] - m*sc;
    float th = thin[c];
    float kf = floorf(th);
    float fr = th - kf;
    int t0 = t + (int)kf;
    const __hip_bfloat16* base = Y + ((size_t)n*128 + c)*1600 + v;
    float a0 = (t0 >= 0 && t0 < 64) ? fmaf(__bfloat162float(base[t0*25]), sc, sh) : 0.f;
    int t1 = t0 + 1;
    float a1 = (t1 >= 0 && t1 < 64) ? fmaf(__bfloat162float(base[t1*25]), sc, sh) : 0.f;
    zsl[c][v] = (1.f - fr)*a0 + fr*a1;
  }
  __syncthreads();
  const int oq = tid >> 3, vq = tid & 7;
  if (vq >= 7) return;
  const int o0 = oq*4, v0 = vq*4;
  float acc[4][4];
  #pragma unroll
  for (int j = 0; j < 4; j++) {
    float bb = tlb[o0+j];
    #pragma unroll
    for (int k = 0; k < 4; k++) acc[j][k] = bb;
  }
  #pragma unroll 4
  for (int c = 0; c < 128; c++) {
    const float4 xv = *(const float4*)&zsl[c][v0];
    const float4 wv = *(const float4*)&tlT[c*128 + o0];
    OUTER16(wv, xv);
  }
  #pragma unroll
  for (int j = 0; j < 4; j++) {
    __hip_bfloat16* row = Z + ((size_t)n*128 + o0 + j)*1600 + t*25;
    #pragma unroll
    for (int k = 0; k < 4; k++) {
      int v = v0 + k;
      if (v < 25) row[v] = __float2bfloat16(fmaxf(acc[j][k], 0.f));
    }
  }
}

// ---------------- K4: second temporal shift (stride 2): Z(bf16,d_out) -> C(bf16,ws) ----------------
__global__ __launch_bounds__(256) void k4(const __hip_bfloat16* __restrict__ Z,
                                          const float* __restrict__ thout,
                                          __hip_bfloat16* __restrict__ C) {
  for (size_t idx = (size_t)blockIdx.x*256 + threadIdx.x; idx < SZ_C; idx += (size_t)gridDim.x*256) {
    int v  = (int)(idx % 25);
    int tp = (int)((idx / 25) % 32);
    int o  = (int)((idx / 800) % 128);
    int n  = (int)(idx / 102400);
    float th = thout[o];
    float kf = floorf(th);
    float fr = th - kf;
    int t0 = 2*tp + (int)kf;
    const __hip_bfloat16* base = Z + ((size_t)n*128 + o)*1600 + v;
    float a0 = (t0 >= 0 && t0 < 64) ? __bfloat162float(base[t0*25]) : 0.f;
    int t1 = t0 + 1;
    float a1 = (t1 >= 0 && t1 < 64) ? __bfloat162float(base[t1*25]) : 0.f;
    C[idx] = __float2bfloat16((1.f - fr)*a0 + fr*a1);
  }
}

// ---------------- K5: res GEMM + out = relu(bn2(C) + bn(res)) -> d_out fp32 ----------------
__global__ __launch_bounds__(256) void k5(
    const float* __restrict__ x, const __hip_bfloat16* __restrict__ C,
    const float* __restrict__ rwT, const float* __restrict__ scR, const float* __restrict__ shR,
    const float* __restrict__ zg, const float* __restrict__ zb,
    const float* __restrict__ zs1, const float* __restrict__ zs2,
    float* __restrict__ out) {
  __shared__ float xs[64][28];
  const int tp = blockIdx.x, n = blockIdx.y, tid = threadIdx.x;
  for (int e = tid; e < 192; e += 256) { xs[e/3][25 + e%3] = 0.f; }
  const float* xbase = x + (size_t)n*102400 + (size_t)(2*tp)*25;
  for (int e = tid; e < 1600; e += 256) {
    int c = e / 25, v = e - c*25;
    xs[c][v] = xbase[(size_t)c*1600 + v];
  }
  __syncthreads();
  const int dq = tid >> 3, vq = tid & 7;
  if (vq >= 7) return;
  const int o0 = dq*4, v0 = vq*4;
  float acc[4][4];
  #pragma unroll
  for (int j = 0; j < 4; j++) {
    #pragma unroll
    for (int k = 0; k < 4; k++) acc[j][k] = 0.f;
  }
  #pragma unroll 4
  for (int c = 0; c < 64; c++) {
    const float4 xv = *(const float4*)&xs[c][v0];
    const float4 wv = *(const float4*)&rwT[c*128 + o0];
    OUTER16(wv, xv);
  }
  const float iSe = 1.0f/204800.0f;
  #pragma unroll
  for (int j = 0; j < 4; j++) {
    int o = o0 + j;
    float m = zs1[o]*iSe;
    float var = fmaxf(zs2[o]*iSe - m*m, 0.f);
    float rz = rsqrtf(var + EPS_);
    float scz = rz * zg[o];
    float shz = zb[o] - m*scz;
    float sR = scR[o], hR = shR[o];
    const __hip_bfloat16* crow = C + ((size_t)n*128 + o)*800 + tp*25;
    float* orow = out + ((size_t)n*128 + o)*800 + tp*25;
    #pragma unroll
    for (int k = 0; k < 4; k++) {
      int v = v0 + k;
      if (v < 25) {
        float zv = fmaf(__bfloat162float(crow[v]), scz, shz);
        float rv = fmaf(acc[j][k], sR, hR);
        orow[v] = fmaxf(zv + rv, 0.f);
      }
    }
  }
}

extern "C" void kernel_launch(void* const* d_in, const int* in_sizes, int n_in,
                              void* d_out, int out_size, void* d_ws, size_t ws_size,
                              hipStream_t stream) {
  (void)in_sizes; (void)n_in; (void)out_size;
  if (ws_size < 157486848ull) return;  // diagnostic: clean fail instead of OOB crash
  const float* x     = (const float*)d_in[0];
  const float* Wl    = (const float*)d_in[1];
  const float* fm    = (const float*)d_in[3];
  const float* gg    = (const float*)d_in[4];
  const float* gb    = (const float*)d_in[5];
  const float* dw    = (const float*)d_in[6];
  const float* dbg   = (const float*)d_in[8];
  const float* dbb   = (const float*)d_in[9];
  const float* tg    = (const float*)d_in[10];
  const float* tb    = (const float*)d_in[11];
  const float* thin  = (const float*)d_in[12];
  const float* tw    = (const float*)d_in[13];
  const float* tlb   = (const float*)d_in[14];
  const float* thout = (const float*)d_in[15];
  const float* t2g   = (const float*)d_in[16];
  const float* t2b   = (const float*)d_in[17];
  const float* rw    = (const float*)d_in[18];
  const float* rbg   = (const float*)d_in[20];
  const float* rbb   = (const float*)d_in[21];
  float* out = (float*)d_out;
  __hip_bfloat16* Zd = (__hip_bfloat16*)d_out;   // Z (bf16) lives in d_out until k5 overwrites

  char* wsb = (char*)d_ws;
  __hip_bfloat16* A  = (__hip_bfloat16*)wsb;                    // 52,428,800 bf16
  __hip_bfloat16* Cb = (__hip_bfloat16*)(wsb + 104857600);      // 26,214,400 bf16
  float* mskT = (float*)(wsb + 157286400);  // 1600
  float* dwT  = mskT + 1600;   // 8192
  float* rwT  = dwT + 8192;    // 8192
  float* tlT  = rwT + 8192;    // 16384
  float* scD  = tlT + 16384;   // 128
  float* shD  = scD + 128;
  float* scR  = shD + 128;
  float* shR  = scR + 128;
  float* gs1  = shR + 128;     // zeroed region starts here: 3200
  float* gs2  = gs1 + 3200;    // 3200
  float* Sxa  = gs2 + 3200;    // 4096
  float* Sxe  = Sxa + 4096;    // 4096
  float* suma = Sxe + 4096;    // 64
  float* sume = suma + 64;     // 64
  float* ts1  = sume + 64;     // 128
  float* ts2  = ts1 + 128;     // 128
  float* zs1  = ts2 + 128;     // 128
  float* zs2  = zs1 + 128;     // 128

  (void)hipMemsetAsync(gs1, 0, 15232 * sizeof(float), stream);
  k_prep<<<64, 256, 0, stream>>>(fm, dw, rw, tw, mskT, dwT, rwT, tlT);
  k_mom<<<512, 256, 0, stream>>>(x, Sxa, Sxe, suma, sume);
  k_fin<<<1, 128, 0, stream>>>(dw, dbg, dbb, rw, rbg, rbb, Sxa, Sxe, suma, sume, scD, shD, scR, shR);
  k1<<<dim3(64, 256), 256, 0, stream>>>(x, Wl, mskT, A);
  k_statsA<<<dim3(128, 8), 256, 0, stream>>>(A, gs1, gs2);
  k2<<<dim3(64, 256), 256, 0, stream>>>(x, dwT, gg, gb, gs1, gs2, scD, shD, A);
  k_statsP<<<dim3(128, 16), 256, 0, stream>>>(A, 1600, ts1, ts2);
  k3<<<dim3(64, 256), 256, 0, stream>>>(A, thin, tg, tb, ts1, ts2, tlT, tlb, Zd);
  k4<<<2048, 256, 0, stream>>>(Zd, thout, Cb);
  k_statsP<<<dim3(128, 16), 256, 0, stream>>>(Cb, 800, zs1, zs2);
  k5<<<dim3(32, 256), 256, 0, stream>>>(x, Cb, rwT, scR, shR, t2g, t2b, zs1, zs2, out);
}

// Round 5
// 1682.260 us; speedup vs baseline: 1.1080x; 1.1080x over previous
//
#include <hip/hip_runtime.h>
#include <cstdint>
#include <cstddef>

namespace {
constexpr float EPS_ = 1e-5f;
}

using u16 = unsigned short;

static __device__ __forceinline__ float bf2f(u16 u) {
  union { unsigned int i; float f; } x; x.i = ((unsigned int)u) << 16; return x.f;
}
static __device__ __forceinline__ u16 f2bf(float f) {
  union { float f; unsigned int i; } x; x.f = f;
  unsigned int r = x.i + 0x7fff + ((x.i >> 16) & 1);
  return (u16)(r >> 16);
}

#define OUT16(a, wv, xv) \
  a[0][0]=fmaf(wv.x,xv.x,a[0][0]); a[0][1]=fmaf(wv.x,xv.y,a[0][1]); \
  a[0][2]=fmaf(wv.x,xv.z,a[0][2]); a[0][3]=fmaf(wv.x,xv.w,a[0][3]); \
  a[1][0]=fmaf(wv.y,xv.x,a[1][0]); a[1][1]=fmaf(wv.y,xv.y,a[1][1]); \
  a[1][2]=fmaf(wv.y,xv.z,a[1][2]); a[1][3]=fmaf(wv.y,xv.w,a[1][3]); \
  a[2][0]=fmaf(wv.z,xv.x,a[2][0]); a[2][1]=fmaf(wv.z,xv.y,a[2][1]); \
  a[2][2]=fmaf(wv.z,xv.z,a[2][2]); a[2][3]=fmaf(wv.z,xv.w,a[2][3]); \
  a[3][0]=fmaf(wv.w,xv.x,a[3][0]); a[3][1]=fmaf(wv.w,xv.y,a[3][1]); \
  a[3][2]=fmaf(wv.w,xv.z,a[3][2]); a[3][3]=fmaf(wv.w,xv.w,a[3][3]);

// ---------- prep0: channel permutations sorted by floor(theta) ----------
__global__ __launch_bounds__(128) void k_prep0(
    const float* __restrict__ thin, const float* __restrict__ thout,
    int* __restrict__ perm1, int* __restrict__ perm2,
    float* __restrict__ ikPf, float* __restrict__ frP,
    float* __restrict__ ik2Pf, float* __restrict__ fr2P) {
  __shared__ float ikL[128], ik2L[128];
  const int c = threadIdx.x;
  float t1 = thin[c], t2 = thout[c];
  float f1 = floorf(t1), f2 = floorf(t2);
  ikL[c] = f1; ik2L[c] = f2;
  __syncthreads();
  int r1 = 0, r2 = 0;
  for (int j = 0; j < 128; j++) {
    r1 += (ikL[j] < f1) || (ikL[j] == f1 && j < c);
    r2 += (ik2L[j] < f2) || (ik2L[j] == f2 && j < c);
  }
  perm1[r1] = c; ikPf[r1] = f1; frP[r1] = t1 - f1;
  perm2[r2] = c; ik2Pf[r2] = f2; fr2P[r2] = t2 - f2;
}

// ---------- prep1: mask + permuted weight transposes ----------
__global__ __launch_bounds__(256) void k_prep1(
    const float* __restrict__ fm, const float* __restrict__ Wl,
    const float* __restrict__ dw, const float* __restrict__ rw, const float* __restrict__ tw,
    const int* __restrict__ perm1, const int* __restrict__ perm2,
    float* __restrict__ mskT, float* __restrict__ WlP, float* __restrict__ dwTP,
    float* __restrict__ rwTP, float* __restrict__ tlTP) {
  int i = blockIdx.x * 256 + threadIdx.x;
  if (i < 1600) { int c = i / 25, w = i % 25; mskT[c*25 + w] = tanhf(fm[w*64 + c]) + 1.0f; }
  if (i < 8192) {
    int c = i >> 7, dp = i & 127;
    int d = perm1[dp], o = perm2[dp];
    WlP[i]  = Wl[c*128 + d];
    dwTP[i] = dw[d*64 + c];
    rwTP[i] = rw[o*64 + c];
  }
  if (i < 16384) { int cp = i >> 7, op = i & 127; tlTP[i] = tw[perm2[op]*128 + perm1[cp]]; }
}

// ---------- second moments of x (all t / even t) ----------
__global__ __launch_bounds__(256) void k_mom(const float* __restrict__ x,
    float* __restrict__ Sxa, float* __restrict__ Sxe,
    float* __restrict__ suma, float* __restrict__ sume) {
  __shared__ float xs[64][208];
  const int n = blockIdx.x >> 1, half = blockIdx.x & 1, tid = threadIdx.x;
  const int ci = (tid >> 4) * 4, cj = (tid & 15) * 4;
  float ae[4][4], ao[4][4], se[4], so[4];
  #pragma unroll
  for (int i = 0; i < 4; i++) {
    se[i] = 0.f; so[i] = 0.f;
    #pragma unroll
    for (int j = 0; j < 4; j++) { ae[i][j] = 0.f; ao[i][j] = 0.f; }
  }
  for (int tc = half*32; tc < half*32 + 32; tc += 8) {
    for (int e = tid; e < 3200; e += 256) {
      int c = e / 50, q = e - c*50;
      *(float4*)&xs[c][q*4] = *(const float4*)&x[(size_t)n*102400 + (size_t)c*1600 + tc*25 + q*4];
    }
    __syncthreads();
    for (int s = 0; s < 200; s += 4) {
      float4 ra0 = *(const float4*)&xs[ci+0][s];
      float4 ra1 = *(const float4*)&xs[ci+1][s];
      float4 ra2 = *(const float4*)&xs[ci+2][s];
      float4 ra3 = *(const float4*)&xs[ci+3][s];
      float4 rb0 = *(const float4*)&xs[cj+0][s];
      float4 rb1 = *(const float4*)&xs[cj+1][s];
      float4 rb2 = *(const float4*)&xs[cj+2][s];
      float4 rb3 = *(const float4*)&xs[cj+3][s];
      #pragma unroll
      for (int k = 0; k < 4; k++) {
        const int tpar = (tc + (s + k) / 25) & 1;
        float xi[4], xj[4];
        xi[0] = ((const float*)&ra0)[k]; xi[1] = ((const float*)&ra1)[k];
        xi[2] = ((const float*)&ra2)[k]; xi[3] = ((const float*)&ra3)[k];
        xj[0] = ((const float*)&rb0)[k]; xj[1] = ((const float*)&rb1)[k];
        xj[2] = ((const float*)&rb2)[k]; xj[3] = ((const float*)&rb3)[k];
        if (!tpar) {
          #pragma unroll
          for (int i = 0; i < 4; i++) {
            #pragma unroll
            for (int j = 0; j < 4; j++) ae[i][j] = fmaf(xi[i], xj[j], ae[i][j]);
          }
          if (cj == 0) {
            #pragma unroll
            for (int i = 0; i < 4; i++) se[i] += xi[i];
          }
        } else {
          #pragma unroll
          for (int i = 0; i < 4; i++) {
            #pragma unroll
            for (int j = 0; j < 4; j++) ao[i][j] = fmaf(xi[i], xj[j], ao[i][j]);
          }
          if (cj == 0) {
            #pragma unroll
            for (int i = 0; i < 4; i++) so[i] += xi[i];
          }
        }
      }
    }
    __syncthreads();
  }
  #pragma unroll
  for (int i = 0; i < 4; i++) {
    #pragma unroll
    for (int j = 0; j < 4; j++) {
      atomicAdd(&Sxa[(ci+i)*64 + cj+j], ae[i][j] + ao[i][j]);
      atomicAdd(&Sxe[(ci+i)*64 + cj+j], ae[i][j]);
    }
  }
  if (cj == 0) {
    #pragma unroll
    for (int i = 0; i < 4; i++) {
      atomicAdd(&suma[ci+i], se[i] + so[i]);
      atomicAdd(&sume[ci+i], se[i]);
    }
  }
}

// ---------- analytic bn scale/shift for down (perm1) & res (perm2) ----------
__global__ __launch_bounds__(256) void k_fin(
    const float* __restrict__ dw, const float* __restrict__ dbg, const float* __restrict__ dbb,
    const float* __restrict__ rw, const float* __restrict__ rbg, const float* __restrict__ rbb,
    const int* __restrict__ perm1, const int* __restrict__ perm2,
    const float* __restrict__ Sxa, const float* __restrict__ Sxe,
    const float* __restrict__ suma, const float* __restrict__ sume,
    float* __restrict__ scDP, float* __restrict__ shDP,
    float* __restrict__ scRP, float* __restrict__ shRP) {
  __shared__ float SA[4096], SE[4096], sa[64], seL[64];
  const int tid = threadIdx.x;
  for (int i = tid; i < 4096; i += 256) { SA[i] = Sxa[i]; SE[i] = Sxe[i]; }
  if (tid < 64) { sa[tid] = suma[tid]; seL[tid] = sume[tid]; }
  __syncthreads();
  const bool down = tid < 128;
  const int p = tid & 127;
  const int o = down ? perm1[p] : perm2[p];
  const float* w = down ? dw : rw;
  const float* SS = down ? SA : SE;
  const float* sv = down ? sa : seL;
  const float iS = down ? (1.f/409600.f) : (1.f/204800.f);
  float wr[64];
  #pragma unroll
  for (int c = 0; c < 64; c += 4) {
    float4 t = *(const float4*)&w[o*64 + c];
    wr[c] = t.x; wr[c+1] = t.y; wr[c+2] = t.z; wr[c+3] = t.w;
  }
  float mu = 0.f, q = 0.f;
  for (int c = 0; c < 64; c++) {
    mu = fmaf(wr[c], sv[c], mu);
    float pp = 0.f;
    #pragma unroll 8
    for (int c2 = 0; c2 < 64; c2++) pp = fmaf(SS[c*64 + c2], wr[c2], pp);
    q = fmaf(wr[c], pp, q);
  }
  mu *= iS; q *= iS;
  float var = fmaxf(q - mu*mu, 0.f);
  float g = down ? dbg[o] : rbg[o];
  float b = down ? dbb[o] : rbb[o];
  float sc = g * rsqrtf(var + EPS_);
  if (down) { scDP[p] = sc; shDP[p] = b - mu*sc; }
  else      { scRP[p] = sc; shRP[p] = b - mu*sc; }
}

// ---------- K1: GCN GEMM (mask+shift in, vertex shuffle out) -> A[n][t][v][dp] bf16 ----------
__global__ __launch_bounds__(256) void k1(
    const float* __restrict__ x, const float* __restrict__ WlP,
    const float* __restrict__ mskT, const int* __restrict__ perm1,
    u16* __restrict__ A) {
  __shared__ float xm[4][64][28];
  __shared__ u16 ys[12800];
  __shared__ int p1L[128];
  const int tg = blockIdx.x, n = blockIdx.y, tid = threadIdx.x;
  const int t4 = tg * 4;
  if (tid < 128) p1L[tid] = perm1[tid];
  for (int e = tid; e < 768; e += 256) { int q = e / 3; xm[q>>6][q&63][25 + e%3] = 0.f; }
  const float* xb = x + (size_t)n * 102400;
  for (int e = tid; e < 6400; e += 256) {
    int tl = e / 1600, r = e - tl*1600, c = r / 25, w = r - c*25;
    int cm = c; if (cm >= 50) cm -= 50; else if (cm >= 25) cm -= 25;
    int vs = w + cm; if (vs >= 25) vs -= 25;
    xm[tl][c][w] = xb[c*1600 + (t4+tl)*25 + vs] * mskT[c*25 + w];
  }
  __syncthreads();
  const int l = tid & 31, vq = tid >> 5;
  const int d0 = l * 4, v0 = vq * 4;
  if (vq < 7) {
    float acc[4][4][4];
    #pragma unroll
    for (int tl = 0; tl < 4; tl++)
      #pragma unroll
      for (int j = 0; j < 4; j++)
        #pragma unroll
        for (int k = 0; k < 4; k++) acc[tl][j][k] = 0.f;
    for (int c = 0; c < 64; c++) {
      const float4 wv = *(const float4*)&WlP[c*128 + d0];
      #pragma unroll
      for (int tl = 0; tl < 4; tl++) {
        const float4 xv = *(const float4*)&xm[tl][c][v0];
        OUT16(acc[tl], wv, xv);
      }
    }
    #pragma unroll
    for (int tl = 0; tl < 4; tl++) {
      #pragma unroll
      for (int j = 0; j < 4; j++) {
        int d = p1L[d0 + j];
        int dm = d % 25;   // FIX: exact modulo (old chain was wrong for d>=126)
        #pragma unroll
        for (int k = 0; k < 4; k++) {
          int w = v0 + k;
          if (w < 25) {
            int v = w + dm; if (v >= 25) v -= 25;
            ys[(tl*25 + v)*128 + d0 + j] = f2bf(acc[tl][j][k]);
          }
        }
      }
    }
  }
  __syncthreads();
  int4* dst = (int4*)(A + (size_t)n*204800 + (size_t)t4*3200);
  const int4* src = (const int4*)ys;
  for (int i = tid; i < 1600; i += 256) dst[i] = src[i];
}

// ---------- stats over 3200 features (v,dp) of A ----------
__global__ __launch_bounds__(256) void k_statsA(const u16* __restrict__ A,
    float* __restrict__ gs1, float* __restrict__ gs2) {
  const int foct = blockIdx.x*256 + threadIdx.x;
  if (foct >= 400) return;
  const int rb = blockIdx.y * 128;
  const size_t f0 = (size_t)foct * 8;
  float s1[8], s2[8];
  #pragma unroll
  for (int i = 0; i < 8; i++) { s1[i] = 0.f; s2[i] = 0.f; }
  for (int r = 0; r < 128; r++) {
    union { int4 i4; u16 u[8]; } raw;
    raw.i4 = *(const int4*)(A + (size_t)(rb + r)*3200 + f0);
    #pragma unroll
    for (int i = 0; i < 8; i++) { float v = bf2f(raw.u[i]); s1[i] += v; s2[i] = fmaf(v, v, s2[i]); }
  }
  #pragma unroll
  for (int i = 0; i < 8; i++) { atomicAdd(&gs1[f0+i], s1[i]); atomicAdd(&gs2[f0+i], s2[i]); }
}

// ---------- finalize gcn bn scale/shift per (v,dp) ----------
__global__ __launch_bounds__(256) void k_fin2(
    const float* __restrict__ gs1, const float* __restrict__ gs2,
    const float* __restrict__ gg, const float* __restrict__ gb,
    const int* __restrict__ perm1,
    float* __restrict__ scG, float* __restrict__ shG) {
  int f = blockIdx.x*256 + threadIdx.x;
  if (f >= 3200) return;
  int v = f >> 7, dp = f & 127;
  int d = perm1[dp];
  float m = gs1[f] * (1.f/16384.f);
  float var = fmaxf(gs2[f]*(1.f/16384.f) - m*m, 0.f);
  float r = rsqrtf(var + EPS_);
  float sc = gg[v*128 + d] * r;
  scG[f] = sc; shG[f] = gb[v*128 + d] - m*sc;
}

// ---------- K2: down GEMM + y = relu(bn1d(h)+bn(down)), A in place ----------
__global__ __launch_bounds__(256) void k2(
    const float* __restrict__ x, const float* __restrict__ dwTP,
    const float* __restrict__ scG, const float* __restrict__ shG,
    const float* __restrict__ scDP, const float* __restrict__ shDP,
    u16* __restrict__ A) {
  __shared__ float xs[4][64][28];
  __shared__ u16 ah[12800];
  const int tg = blockIdx.x, n = blockIdx.y, tid = threadIdx.x;
  const int t4 = tg * 4;
  for (int e = tid; e < 768; e += 256) { int q = e / 3; xs[q>>6][q&63][25 + e%3] = 0.f; }
  const float* xb = x + (size_t)n * 102400;
  for (int e = tid; e < 6400; e += 256) {
    int tl = e / 1600, r = e - tl*1600, c = r / 25, v = r - c*25;
    xs[tl][c][v] = xb[c*1600 + (t4+tl)*25 + v];
  }
  u16* Aslab = A + (size_t)n*204800 + (size_t)t4*3200;
  {
    int4* dst = (int4*)ah;
    const int4* src = (const int4*)Aslab;
    for (int i = tid; i < 1600; i += 256) dst[i] = src[i];
  }
  __syncthreads();
  const int l = tid & 31, vq = tid >> 5;
  const int d0 = l * 4, v0 = vq * 4;
  if (vq < 7) {
    float acc[4][4][4];
    #pragma unroll
    for (int tl = 0; tl < 4; tl++)
      #pragma unroll
      for (int j = 0; j < 4; j++)
        #pragma unroll
        for (int k = 0; k < 4; k++) acc[tl][j][k] = 0.f;
    for (int c = 0; c < 64; c++) {
      const float4 wv = *(const float4*)&dwTP[c*128 + d0];
      #pragma unroll
      for (int tl = 0; tl < 4; tl++) {
        const float4 xv = *(const float4*)&xs[tl][c][v0];
        OUT16(acc[tl], wv, xv);
      }
    }
    const float4 scd = *(const float4*)&scDP[d0];
    const float4 shd = *(const float4*)&shDP[d0];
    #pragma unroll
    for (int tl = 0; tl < 4; tl++) {
      #pragma unroll
      for (int k = 0; k < 4; k++) {
        int v = v0 + k;
        if (v < 25) {
          union { ushort4 s4; u16 u[4]; } hv, ov;
          hv.s4 = *(const ushort4*)&ah[(tl*25 + v)*128 + d0];
          const float4 sg = *(const float4*)&scG[v*128 + d0];
          const float4 hg = *(const float4*)&shG[v*128 + d0];
          #pragma unroll
          for (int j = 0; j < 4; j++) {
            float hb = fmaf(bf2f(hv.u[j]), ((const float*)&sg)[j], ((const float*)&hg)[j]);
            float dd = fmaf(acc[tl][j][k], ((const float*)&scd)[j], ((const float*)&shd)[j]);
            ov.u[j] = f2bf(fmaxf(hb + dd, 0.f));
          }
          *(ushort4*)(Aslab + (size_t)tl*3200 + v*128 + d0) = ov.s4;
        }
      }
    }
  }
}

// ---------- per-128-channel stats (channel-last rows) ----------
__global__ __launch_bounds__(256) void k_statsP(const u16* __restrict__ P, long nrows,
    float* __restrict__ s1g, float* __restrict__ s2g) {
  const int tid = threadIdx.x;
  const int f0 = (tid & 15) * 8;
  const int rg = tid >> 4;
  long rpb = nrows / gridDim.x;
  long rb = (long)blockIdx.x * rpb;
  float s1[8], s2[8];
  #pragma unroll
  for (int i = 0; i < 8; i++) { s1[i] = 0.f; s2[i] = 0.f; }
  for (long r = rg; r < rpb; r += 16) {
    union { int4 i4; u16 u[8]; } raw;
    raw.i4 = *(const int4*)(P + (rb + r)*128 + f0);
    #pragma unroll
    for (int i = 0; i < 8; i++) { float v = bf2f(raw.u[i]); s1[i] += v; s2[i] = fmaf(v, v, s2[i]); }
  }
  __shared__ float m1[16][128], m2[16][128];
  #pragma unroll
  for (int i = 0; i < 8; i++) { m1[rg][f0+i] = s1[i]; m2[rg][f0+i] = s2[i]; }
  __syncthreads();
  if (tid < 128) {
    float a = 0.f, b = 0.f;
    #pragma unroll
    for (int g = 0; g < 16; g++) { a += m1[g][tid]; b += m2[g][tid]; }
    atomicAdd(&s1g[tid], a); atomicAdd(&s2g[tid], b);
  }
}

// ---------- K3: bn(y)+shift(theta_in,1)+tl GEMM+bias+relu -> Z[n][t][v][op] bf16 (d_out) ----------
__global__ __launch_bounds__(256) void k3(
    const u16* __restrict__ Y,
    const float* __restrict__ ts1, const float* __restrict__ ts2,
    const float* __restrict__ tgamma, const float* __restrict__ tbeta,
    const int* __restrict__ perm1, const int* __restrict__ perm2,
    const float* __restrict__ ikPf, const float* __restrict__ frP,
    const float* __restrict__ tlTP, const float* __restrict__ tlb,
    u16* __restrict__ Z) {
  __shared__ float zsl[4][128][28];
  __shared__ float scL[128], shL[128], frL[128], tlbL[128];
  __shared__ int ikL[128];
  const int tg = blockIdx.x, n = blockIdx.y, tid = threadIdx.x;
  const int t4 = tg * 4;
  if (tid < 128) {
    int cp = tid, c = perm1[cp];
    float m = ts1[cp] * (1.f/409600.f);
    float var = fmaxf(ts2[cp]*(1.f/409600.f) - m*m, 0.f);
    float r = rsqrtf(var + EPS_);
    float sc = tgamma[c] * r;
    scL[cp] = sc; shL[cp] = tbeta[c] - m*sc;
    ikL[cp] = (int)ikPf[cp]; frL[cp] = frP[cp];
    tlbL[cp] = tlb[perm2[cp]];
  }
  for (int e = tid; e < 1536; e += 256) { int q = e / 3; zsl[q>>7][q&127][25 + e%3] = 0.f; }
  __syncthreads();
  const u16* Yb = Y + (size_t)n * 204800;
  for (int e = tid; e < 12800; e += 256) {
    int cp = e & 127, v = (e >> 7) % 25, tl = e / 3200;
    int t0 = t4 + tl + ikL[cp];
    float fr = frL[cp], sc = scL[cp], sh = shL[cp];
    float a0 = (t0 >= 0 && t0 < 64) ? fmaf(bf2f(Yb[(size_t)t0*3200 + v*128 + cp]), sc, sh) : 0.f;
    int t1 = t0 + 1;
    float a1 = (t1 >= 0 && t1 < 64) ? fmaf(bf2f(Yb[(size_t)t1*3200 + v*128 + cp]), sc, sh) : 0.f;
    zsl[tl][cp][v] = (1.f - fr)*a0 + fr*a1;
  }
  __syncthreads();
  const int l = tid & 31, vq = tid >> 5;
  const int o0 = l * 4, v0 = vq * 4;
  if (vq < 7) {
    float acc[4][4][4];
    #pragma unroll
    for (int j = 0; j < 4; j++) {
      float bb = tlbL[o0 + j];
      #pragma unroll
      for (int tl = 0; tl < 4; tl++)
        #pragma unroll
        for (int k = 0; k < 4; k++) acc[tl][j][k] = bb;
    }
    for (int c = 0; c < 128; c++) {
      const float4 wv = *(const float4*)&tlTP[c*128 + o0];
      #pragma unroll
      for (int tl = 0; tl < 4; tl++) {
        const float4 xv = *(const float4*)&zsl[tl][c][v0];
        OUT16(acc[tl], wv, xv);
      }
    }
    u16* Zb = Z + (size_t)n*204800 + (size_t)t4*3200;
    #pragma unroll
    for (int tl = 0; tl < 4; tl++) {
      #pragma unroll
      for (int k = 0; k < 4; k++) {
        int v = v0 + k;
        if (v < 25) {
          union { ushort4 s4; u16 u[4]; } ov;
          #pragma unroll
          for (int j = 0; j < 4; j++) ov.u[j] = f2bf(fmaxf(acc[tl][j][k], 0.f));
          *(ushort4*)(Zb + (size_t)tl*3200 + v*128 + o0) = ov.s4;
        }
      }
    }
  }
}

// ---------- K4: stride-2 shift(theta_out) Z -> C[n][tp][v][op] bf16 ----------
__global__ __launch_bounds__(256) void k4(const u16* __restrict__ Z,
    const float* __restrict__ ik2Pf, const float* __restrict__ fr2P,
    u16* __restrict__ C) {
  __shared__ int ikL[128];
  __shared__ float frL[128];
  if (threadIdx.x < 128) { ikL[threadIdx.x] = (int)ik2Pf[threadIdx.x]; frL[threadIdx.x] = fr2P[threadIdx.x]; }
  __syncthreads();
  for (size_t idx = (size_t)blockIdx.x*256 + threadIdx.x; idx < 26214400ull; idx += (size_t)gridDim.x*256) {
    int op = (int)(idx & 127);
    int v  = (int)((idx >> 7) % 25);
    int tp = (int)((idx / 3200) & 31);
    int n  = (int)(idx / 102400);
    int t0 = 2*tp + ikL[op];
    float fr = frL[op];
    const u16* base = Z + (size_t)n*204800 + v*128 + op;
    float a0 = (t0 >= 0 && t0 < 64) ? bf2f(base[(size_t)t0*3200]) : 0.f;
    int t1 = t0 + 1;
    float a1 = (t1 >= 0 && t1 < 64) ? bf2f(base[(size_t)t1*3200]) : 0.f;
    C[idx] = f2bf((1.f - fr)*a0 + fr*a1);
  }
}

// ---------- K5: res GEMM + out = relu(bn2(C)+bn(res)) -> NCHW fp32 ----------
__global__ __launch_bounds__(256) void k5(
    const float* __restrict__ x, const u16* __restrict__ C,
    const float* __restrict__ rwTP,
    const float* __restrict__ scRP, const float* __restrict__ shRP,
    const float* __restrict__ zs1, const float* __restrict__ zs2,
    const float* __restrict__ t2g, const float* __restrict__ t2b,
    const int* __restrict__ perm2, float* __restrict__ out) {
  __shared__ float xs[4][64][28];
  __shared__ u16 ch[12800];
  __shared__ float sc2L[128], sh2L[128];
  __shared__ int p2L[128];
  const int tpg = blockIdx.x, n = blockIdx.y, tid = threadIdx.x;
  const int tp4 = tpg * 4;
  if (tid < 128) {
    int op = tid, o = perm2[op];
    float m = zs1[op] * (1.f/204800.f);
    float var = fmaxf(zs2[op]*(1.f/204800.f) - m*m, 0.f);
    float r = rsqrtf(var + EPS_);
    float sc = t2g[o] * r;
    sc2L[op] = sc; sh2L[op] = t2b[o] - m*sc;
    p2L[op] = o;
  }
  for (int e = tid; e < 768; e += 256) { int q = e / 3; xs[q>>6][q&63][25 + e%3] = 0.f; }
  const float* xb = x + (size_t)n * 102400;
  for (int e = tid; e < 6400; e += 256) {
    int tl = e / 1600, r = e - tl*1600, c = r / 25, v = r - c*25;
    xs[tl][c][v] = xb[c*1600 + 2*(tp4+tl)*25 + v];
  }
  {
    int4* dst = (int4*)ch;
    const int4* src = (const int4*)(C + (size_t)n*102400 + (size_t)tp4*3200);
    for (int i = tid; i < 1600; i += 256) dst[i] = src[i];
  }
  __syncthreads();
  const int l = tid & 31, vq = tid >> 5;
  const int o0 = l * 4, v0 = vq * 4;
  if (vq < 7) {
    float acc[4][4][4];
    #pragma unroll
    for (int tl = 0; tl < 4; tl++)
      #pragma unroll
      for (int j = 0; j < 4; j++)
        #pragma unroll
        for (int k = 0; k < 4; k++) acc[tl][j][k] = 0.f;
    for (int c = 0; c < 64; c++) {
      const float4 wv = *(const float4*)&rwTP[c*128 + o0];
      #pragma unroll
      for (int tl = 0; tl < 4; tl++) {
        const float4 xv = *(const float4*)&xs[tl][c][v0];
        OUT16(acc[tl], wv, xv);
      }
    }
    const float4 scr = *(const float4*)&scRP[o0];
    const float4 shr = *(const float4*)&shRP[o0];
    #pragma unroll
    for (int tl = 0; tl < 4; tl++) {
      #pragma unroll
      for (int k = 0; k < 4; k++) {
        int v = v0 + k;
        if (v < 25) {
          union { ushort4 s4; u16 u[4]; } cv;
          cv.s4 = *(const ushort4*)&ch[(tl*25 + v)*128 + o0];
          #pragma unroll
          for (int j = 0; j < 4; j++) {
            float zv = fmaf(bf2f(cv.u[j]), sc2L[o0+j], sh2L[o0+j]);
            float rv = fmaf(acc[tl][j][k], ((const float*)&scr)[j], ((const float*)&shr)[j]);
            out[((size_t)(n*128 + p2L[o0+j])*32 + tp4 + tl)*25 + v] = fmaxf(zv + rv, 0.f);
          }
        }
      }
    }
  }
}

extern "C" void kernel_launch(void* const* d_in, const int* in_sizes, int n_in,
                              void* d_out, int out_size, void* d_ws, size_t ws_size,
                              hipStream_t stream) {
  (void)in_sizes; (void)n_in; (void)out_size;
  if (ws_size < 105200000ull) return;  // clean fail instead of OOB crash
  const float* x     = (const float*)d_in[0];
  const float* Wl    = (const float*)d_in[1];
  const float* fm    = (const float*)d_in[3];
  const float* gg    = (const float*)d_in[4];
  const float* gb    = (const float*)d_in[5];
  const float* dw    = (const float*)d_in[6];
  const float* dbg   = (const float*)d_in[8];
  const float* dbb   = (const float*)d_in[9];
  const float* tgam  = (const float*)d_in[10];
  const float* tbet  = (const float*)d_in[11];
  const float* thin  = (const float*)d_in[12];
  const float* tw    = (const float*)d_in[13];
  const float* tlb   = (const float*)d_in[14];
  const float* thout = (const float*)d_in[15];
  const float* t2g   = (const float*)d_in[16];
  const float* t2b   = (const float*)d_in[17];
  const float* rw    = (const float*)d_in[18];
  const float* rbg   = (const float*)d_in[20];
  const float* rbb   = (const float*)d_in[21];
  float* out = (float*)d_out;
  u16* Zd = (u16*)d_out;            // Z bf16 lives in d_out until k5 overwrites

  u16* A  = (u16*)d_ws;             // [256][64][25][128] bf16 = 104,857,600 B
  u16* Cb = A;                      // C aliases A (A dead after k3)
  float* S = (float*)((char*)d_ws + 104857600);
  float* mskT = S;                  // 1600
  float* WlP  = mskT + 1600;        // 8192
  float* dwTP = WlP + 8192;         // 8192
  float* rwTP = dwTP + 8192;        // 8192
  float* tlTP = rwTP + 8192;        // 16384
  float* scG  = tlTP + 16384;       // 3200
  float* shG  = scG + 3200;         // 3200
  float* scDP = shG + 3200;         // 128
  float* shDP = scDP + 128;
  float* scRP = shDP + 128;
  float* shRP = scRP + 128;
  float* ikPf = shRP + 128;
  float* frP  = ikPf + 128;
  float* ik2Pf= frP + 128;
  float* fr2P = ik2Pf + 128;
  float* Sxa  = fr2P + 128;         // zero region start (15232 floats)
  float* Sxe  = Sxa + 4096;
  float* suma = Sxe + 4096;
  float* sume = suma + 64;
  float* gs1  = sume + 64;
  float* gs2  = gs1 + 3200;
  float* ts1  = gs2 + 3200;
  float* ts2  = ts1 + 128;
  float* zs1  = ts2 + 128;
  float* zs2  = zs1 + 128;
  int* perm1  = (int*)(zs2 + 128);
  int* perm2  = perm1 + 128;

  (void)hipMemsetAsync(Sxa, 0, 15232 * sizeof(float), stream);
  k_prep0<<<1, 128, 0, stream>>>(thin, thout, perm1, perm2, ikPf, frP, ik2Pf, fr2P);
  k_prep1<<<64, 256, 0, stream>>>(fm, Wl, dw, rw, tw, perm1, perm2, mskT, WlP, dwTP, rwTP, tlTP);
  k_mom<<<512, 256, 0, stream>>>(x, Sxa, Sxe, suma, sume);
  k_fin<<<1, 256, 0, stream>>>(dw, dbg, dbb, rw, rbg, rbb, perm1, perm2,
                               Sxa, Sxe, suma, sume, scDP, shDP, scRP, shRP);
  k1<<<dim3(16, 256), 256, 0, stream>>>(x, WlP, mskT, perm1, A);
  k_statsA<<<dim3(2, 128), 256, 0, stream>>>(A, gs1, gs2);
  k_fin2<<<13, 256, 0, stream>>>(gs1, gs2, gg, gb, perm1, scG, shG);
  k2<<<dim3(16, 256), 256, 0, stream>>>(x, dwTP, scG, shG, scDP, shDP, A);
  k_statsP<<<200, 256, 0, stream>>>(A, 409600L, ts1, ts2);
  k3<<<dim3(16, 256), 256, 0, stream>>>(A, ts1, ts2, tgam, tbet, perm1, perm2,
                                        ikPf, frP, tlTP, tlb, Zd);
  k4<<<2048, 256, 0, stream>>>(Zd, ik2Pf, fr2P, Cb);
  k_statsP<<<100, 256, 0, stream>>>(Cb, 204800L, zs1, zs2);
  k5<<<dim3(8, 256), 256, 0, stream>>>(x, Cb, rwTP, scRP, shRP, zs1, zs2, t2g, t2b, perm2, out);
}

// Round 6
// 1383.656 us; speedup vs baseline: 1.3472x; 1.2158x over previous
//
#include <hip/hip_runtime.h>
#include <cstdint>
#include <cstddef>

namespace {
constexpr float EPS_ = 1e-5f;
}

using u16 = unsigned short;

static __device__ __forceinline__ float bf2f(u16 u) {
  union { unsigned int i; float f; } x; x.i = ((unsigned int)u) << 16; return x.f;
}
static __device__ __forceinline__ u16 f2bf(float f) {
  union { float f; unsigned int i; } x; x.f = f;
  unsigned int r = x.i + 0x7fff + ((x.i >> 16) & 1);
  return (u16)(r >> 16);
}

#define OUT16(a, wv, xv) \
  a[0][0]=fmaf(wv.x,xv.x,a[0][0]); a[0][1]=fmaf(wv.x,xv.y,a[0][1]); \
  a[0][2]=fmaf(wv.x,xv.z,a[0][2]); a[0][3]=fmaf(wv.x,xv.w,a[0][3]); \
  a[1][0]=fmaf(wv.y,xv.x,a[1][0]); a[1][1]=fmaf(wv.y,xv.y,a[1][1]); \
  a[1][2]=fmaf(wv.y,xv.z,a[1][2]); a[1][3]=fmaf(wv.y,xv.w,a[1][3]); \
  a[2][0]=fmaf(wv.z,xv.x,a[2][0]); a[2][1]=fmaf(wv.z,xv.y,a[2][1]); \
  a[2][2]=fmaf(wv.z,xv.z,a[2][2]); a[2][3]=fmaf(wv.z,xv.w,a[2][3]); \
  a[3][0]=fmaf(wv.w,xv.x,a[3][0]); a[3][1]=fmaf(wv.w,xv.y,a[3][1]); \
  a[3][2]=fmaf(wv.w,xv.z,a[3][2]); a[3][3]=fmaf(wv.w,xv.w,a[3][3]);

// ---------- prep0: channel permutations sorted by floor(theta) ----------
__global__ __launch_bounds__(128) void k_prep0(
    const float* __restrict__ thin, const float* __restrict__ thout,
    int* __restrict__ perm1, int* __restrict__ perm2,
    float* __restrict__ ikPf, float* __restrict__ frP,
    float* __restrict__ ik2Pf, float* __restrict__ fr2P) {
  __shared__ float ikL[128], ik2L[128];
  const int c = threadIdx.x;
  float t1 = thin[c], t2 = thout[c];
  float f1 = floorf(t1), f2 = floorf(t2);
  ikL[c] = f1; ik2L[c] = f2;
  __syncthreads();
  int r1 = 0, r2 = 0;
  for (int j = 0; j < 128; j++) {
    r1 += (ikL[j] < f1) || (ikL[j] == f1 && j < c);
    r2 += (ik2L[j] < f2) || (ik2L[j] == f2 && j < c);
  }
  perm1[r1] = c; ikPf[r1] = f1; frP[r1] = t1 - f1;
  perm2[r2] = c; ik2Pf[r2] = f2; fr2P[r2] = t2 - f2;
}

// ---------- prep1: mask + permuted weight transposes ----------
__global__ __launch_bounds__(256) void k_prep1(
    const float* __restrict__ fm, const float* __restrict__ Wl,
    const float* __restrict__ dw, const float* __restrict__ rw, const float* __restrict__ tw,
    const int* __restrict__ perm1, const int* __restrict__ perm2,
    float* __restrict__ mskT, float* __restrict__ WlP, float* __restrict__ dwTP,
    float* __restrict__ rwTP, float* __restrict__ tlTP) {
  int i = blockIdx.x * 256 + threadIdx.x;
  if (i < 1600) { int c = i / 25, w = i % 25; mskT[c*25 + w] = tanhf(fm[w*64 + c]) + 1.0f; }
  if (i < 8192) {
    int c = i >> 7, dp = i & 127;
    int d = perm1[dp], o = perm2[dp];
    WlP[i]  = Wl[c*128 + d];
    dwTP[i] = dw[d*64 + c];
    rwTP[i] = rw[o*64 + c];
  }
  if (i < 16384) { int cp = i >> 7, op = i & 127; tlTP[i] = tw[perm2[op]*128 + perm1[cp]]; }
}

// ---------- second moments of x (all t / even t) ----------
__global__ __launch_bounds__(256) void k_mom(const float* __restrict__ x,
    float* __restrict__ Sxa, float* __restrict__ Sxe,
    float* __restrict__ suma, float* __restrict__ sume) {
  __shared__ float xs[64][208];
  const int n = blockIdx.x >> 1, half = blockIdx.x & 1, tid = threadIdx.x;
  const int ci = (tid >> 4) * 4, cj = (tid & 15) * 4;
  float ae[4][4], ao[4][4], se[4], so[4];
  #pragma unroll
  for (int i = 0; i < 4; i++) {
    se[i] = 0.f; so[i] = 0.f;
    #pragma unroll
    for (int j = 0; j < 4; j++) { ae[i][j] = 0.f; ao[i][j] = 0.f; }
  }
  for (int tc = half*32; tc < half*32 + 32; tc += 8) {
    for (int e = tid; e < 3200; e += 256) {
      int c = e / 50, q = e - c*50;
      *(float4*)&xs[c][q*4] = *(const float4*)&x[(size_t)n*102400 + (size_t)c*1600 + tc*25 + q*4];
    }
    __syncthreads();
    for (int s = 0; s < 200; s += 4) {
      float4 ra0 = *(const float4*)&xs[ci+0][s];
      float4 ra1 = *(const float4*)&xs[ci+1][s];
      float4 ra2 = *(const float4*)&xs[ci+2][s];
      float4 ra3 = *(const float4*)&xs[ci+3][s];
      float4 rb0 = *(const float4*)&xs[cj+0][s];
      float4 rb1 = *(const float4*)&xs[cj+1][s];
      float4 rb2 = *(const float4*)&xs[cj+2][s];
      float4 rb3 = *(const float4*)&xs[cj+3][s];
      #pragma unroll
      for (int k = 0; k < 4; k++) {
        const int tpar = (tc + (s + k) / 25) & 1;
        float xi[4], xj[4];
        xi[0] = ((const float*)&ra0)[k]; xi[1] = ((const float*)&ra1)[k];
        xi[2] = ((const float*)&ra2)[k]; xi[3] = ((const float*)&ra3)[k];
        xj[0] = ((const float*)&rb0)[k]; xj[1] = ((const float*)&rb1)[k];
        xj[2] = ((const float*)&rb2)[k]; xj[3] = ((const float*)&rb3)[k];
        if (!tpar) {
          #pragma unroll
          for (int i = 0; i < 4; i++) {
            #pragma unroll
            for (int j = 0; j < 4; j++) ae[i][j] = fmaf(xi[i], xj[j], ae[i][j]);
          }
          if (cj == 0) {
            #pragma unroll
            for (int i = 0; i < 4; i++) se[i] += xi[i];
          }
        } else {
          #pragma unroll
          for (int i = 0; i < 4; i++) {
            #pragma unroll
            for (int j = 0; j < 4; j++) ao[i][j] = fmaf(xi[i], xj[j], ao[i][j]);
          }
          if (cj == 0) {
            #pragma unroll
            for (int i = 0; i < 4; i++) so[i] += xi[i];
          }
        }
      }
    }
    __syncthreads();
  }
  #pragma unroll
  for (int i = 0; i < 4; i++) {
    #pragma unroll
    for (int j = 0; j < 4; j++) {
      atomicAdd(&Sxa[(ci+i)*64 + cj+j], ae[i][j] + ao[i][j]);
      atomicAdd(&Sxe[(ci+i)*64 + cj+j], ae[i][j]);
    }
  }
  if (cj == 0) {
    #pragma unroll
    for (int i = 0; i < 4; i++) {
      atomicAdd(&suma[ci+i], se[i] + so[i]);
      atomicAdd(&sume[ci+i], se[i]);
    }
  }
}

// ---------- analytic bn scale/shift for down (perm1) & res (perm2) ----------
__global__ __launch_bounds__(256) void k_fin(
    const float* __restrict__ dw, const float* __restrict__ dbg, const float* __restrict__ dbb,
    const float* __restrict__ rw, const float* __restrict__ rbg, const float* __restrict__ rbb,
    const int* __restrict__ perm1, const int* __restrict__ perm2,
    const float* __restrict__ Sxa, const float* __restrict__ Sxe,
    const float* __restrict__ suma, const float* __restrict__ sume,
    float* __restrict__ scDP, float* __restrict__ shDP,
    float* __restrict__ scRP, float* __restrict__ shRP) {
  __shared__ float SA[4096], SE[4096], sa[64], seL[64];
  const int tid = threadIdx.x;
  for (int i = tid; i < 4096; i += 256) { SA[i] = Sxa[i]; SE[i] = Sxe[i]; }
  if (tid < 64) { sa[tid] = suma[tid]; seL[tid] = sume[tid]; }
  __syncthreads();
  const bool down = tid < 128;
  const int p = tid & 127;
  const int o = down ? perm1[p] : perm2[p];
  const float* w = down ? dw : rw;
  const float* SS = down ? SA : SE;
  const float* sv = down ? sa : seL;
  const float iS = down ? (1.f/409600.f) : (1.f/204800.f);
  float wr[64];
  #pragma unroll
  for (int c = 0; c < 64; c += 4) {
    float4 t = *(const float4*)&w[o*64 + c];
    wr[c] = t.x; wr[c+1] = t.y; wr[c+2] = t.z; wr[c+3] = t.w;
  }
  float mu = 0.f, q = 0.f;
  for (int c = 0; c < 64; c++) {
    mu = fmaf(wr[c], sv[c], mu);
    float pp = 0.f;
    #pragma unroll 8
    for (int c2 = 0; c2 < 64; c2++) pp = fmaf(SS[c*64 + c2], wr[c2], pp);
    q = fmaf(wr[c], pp, q);
  }
  mu *= iS; q *= iS;
  float var = fmaxf(q - mu*mu, 0.f);
  float g = down ? dbg[o] : rbg[o];
  float b = down ? dbb[o] : rbb[o];
  float sc = g * rsqrtf(var + EPS_);
  if (down) { scDP[p] = sc; shDP[p] = b - mu*sc; }
  else      { scRP[p] = sc; shRP[p] = b - mu*sc; }
}

// ---------- K1: GCN GEMM (mask+shift in, vertex shuffle out) -> A[n][t][v][dp] bf16 ----------
// TB=2 t-slices per block: LDS ~27.6KB -> 5 blocks/CU
__global__ __launch_bounds__(256) void k1(
    const float* __restrict__ x, const float* __restrict__ WlP,
    const float* __restrict__ mskT, const int* __restrict__ perm1,
    u16* __restrict__ A) {
  __shared__ float xm[2][64][28];
  __shared__ u16 ys[6400];
  __shared__ int p1L[128];
  const int tg = blockIdx.x, n = blockIdx.y, tid = threadIdx.x;
  const int t2 = tg * 2;
  if (tid < 128) p1L[tid] = perm1[tid];
  for (int e = tid; e < 384; e += 256) { int q = e / 3; xm[q>>6][q&63][25 + e%3] = 0.f; }
  const float* xb = x + (size_t)n * 102400;
  for (int e = tid; e < 3200; e += 256) {
    int tl = e / 1600, r = e - tl*1600, c = r / 25, w = r - c*25;
    int cm = c; if (cm >= 50) cm -= 50; else if (cm >= 25) cm -= 25;
    int vs = w + cm; if (vs >= 25) vs -= 25;
    xm[tl][c][w] = xb[c*1600 + (t2+tl)*25 + vs] * mskT[c*25 + w];
  }
  __syncthreads();
  const int l = tid & 31, vq = tid >> 5;
  const int d0 = l * 4, v0 = vq * 4;
  if (vq < 7) {
    float acc[2][4][4];
    #pragma unroll
    for (int tl = 0; tl < 2; tl++)
      #pragma unroll
      for (int j = 0; j < 4; j++)
        #pragma unroll
        for (int k = 0; k < 4; k++) acc[tl][j][k] = 0.f;
    for (int c = 0; c < 64; c++) {
      const float4 wv = *(const float4*)&WlP[c*128 + d0];
      #pragma unroll
      for (int tl = 0; tl < 2; tl++) {
        const float4 xv = *(const float4*)&xm[tl][c][v0];
        OUT16(acc[tl], wv, xv);
      }
    }
    #pragma unroll
    for (int tl = 0; tl < 2; tl++) {
      #pragma unroll
      for (int j = 0; j < 4; j++) {
        int d = p1L[d0 + j];
        int dm = d % 25;
        #pragma unroll
        for (int k = 0; k < 4; k++) {
          int w = v0 + k;
          if (w < 25) {
            int v = w + dm; if (v >= 25) v -= 25;
            ys[(tl*25 + v)*128 + d0 + j] = f2bf(acc[tl][j][k]);
          }
        }
      }
    }
  }
  __syncthreads();
  int4* dst = (int4*)(A + (size_t)n*204800 + (size_t)t2*3200);
  const int4* src = (const int4*)ys;
  for (int i = tid; i < 800; i += 256) dst[i] = src[i];
}

// ---------- stats over 3200 features (v,dp) of A ----------
__global__ __launch_bounds__(256) void k_statsA(const u16* __restrict__ A,
    float* __restrict__ gs1, float* __restrict__ gs2) {
  const int foct = blockIdx.x*256 + threadIdx.x;
  if (foct >= 400) return;
  const int rb = blockIdx.y * 128;
  const size_t f0 = (size_t)foct * 8;
  float s1[8], s2[8];
  #pragma unroll
  for (int i = 0; i < 8; i++) { s1[i] = 0.f; s2[i] = 0.f; }
  for (int r = 0; r < 128; r++) {
    union { int4 i4; u16 u[8]; } raw;
    raw.i4 = *(const int4*)(A + (size_t)(rb + r)*3200 + f0);
    #pragma unroll
    for (int i = 0; i < 8; i++) { float v = bf2f(raw.u[i]); s1[i] += v; s2[i] = fmaf(v, v, s2[i]); }
  }
  #pragma unroll
  for (int i = 0; i < 8; i++) { atomicAdd(&gs1[f0+i], s1[i]); atomicAdd(&gs2[f0+i], s2[i]); }
}

// ---------- finalize gcn bn scale/shift per (v,dp) ----------
__global__ __launch_bounds__(256) void k_fin2(
    const float* __restrict__ gs1, const float* __restrict__ gs2,
    const float* __restrict__ gg, const float* __restrict__ gb,
    const int* __restrict__ perm1,
    float* __restrict__ scG, float* __restrict__ shG) {
  int f = blockIdx.x*256 + threadIdx.x;
  if (f >= 3200) return;
  int v = f >> 7, dp = f & 127;
  int d = perm1[dp];
  float m = gs1[f] * (1.f/16384.f);
  float var = fmaxf(gs2[f]*(1.f/16384.f) - m*m, 0.f);
  float r = rsqrtf(var + EPS_);
  float sc = gg[v*128 + d] * r;
  scG[f] = sc; shG[f] = gb[v*128 + d] - m*sc;
}

// ---------- K2: down GEMM + y = relu(bn1d(h)+bn(down)), A in place ----------
__global__ __launch_bounds__(256) void k2(
    const float* __restrict__ x, const float* __restrict__ dwTP,
    const float* __restrict__ scG, const float* __restrict__ shG,
    const float* __restrict__ scDP, const float* __restrict__ shDP,
    u16* __restrict__ A) {
  __shared__ float xs[2][64][28];
  __shared__ u16 ah[6400];
  const int tg = blockIdx.x, n = blockIdx.y, tid = threadIdx.x;
  const int t2 = tg * 2;
  for (int e = tid; e < 384; e += 256) { int q = e / 3; xs[q>>6][q&63][25 + e%3] = 0.f; }
  const float* xb = x + (size_t)n * 102400;
  for (int e = tid; e < 3200; e += 256) {
    int tl = e / 1600, r = e - tl*1600, c = r / 25, v = r - c*25;
    xs[tl][c][v] = xb[c*1600 + (t2+tl)*25 + v];
  }
  u16* Aslab = A + (size_t)n*204800 + (size_t)t2*3200;
  {
    int4* dst = (int4*)ah;
    const int4* src = (const int4*)Aslab;
    for (int i = tid; i < 800; i += 256) dst[i] = src[i];
  }
  __syncthreads();
  const int l = tid & 31, vq = tid >> 5;
  const int d0 = l * 4, v0 = vq * 4;
  if (vq < 7) {
    float acc[2][4][4];
    #pragma unroll
    for (int tl = 0; tl < 2; tl++)
      #pragma unroll
      for (int j = 0; j < 4; j++)
        #pragma unroll
        for (int k = 0; k < 4; k++) acc[tl][j][k] = 0.f;
    for (int c = 0; c < 64; c++) {
      const float4 wv = *(const float4*)&dwTP[c*128 + d0];
      #pragma unroll
      for (int tl = 0; tl < 2; tl++) {
        const float4 xv = *(const float4*)&xs[tl][c][v0];
        OUT16(acc[tl], wv, xv);
      }
    }
    const float4 scd = *(const float4*)&scDP[d0];
    const float4 shd = *(const float4*)&shDP[d0];
    #pragma unroll
    for (int tl = 0; tl < 2; tl++) {
      #pragma unroll
      for (int k = 0; k < 4; k++) {
        int v = v0 + k;
        if (v < 25) {
          union { ushort4 s4; u16 u[4]; } hv, ov;
          hv.s4 = *(const ushort4*)&ah[(tl*25 + v)*128 + d0];
          const float4 sg = *(const float4*)&scG[v*128 + d0];
          const float4 hg = *(const float4*)&shG[v*128 + d0];
          #pragma unroll
          for (int j = 0; j < 4; j++) {
            float hb = fmaf(bf2f(hv.u[j]), ((const float*)&sg)[j], ((const float*)&hg)[j]);
            float dd = fmaf(acc[tl][j][k], ((const float*)&scd)[j], ((const float*)&shd)[j]);
            ov.u[j] = f2bf(fmaxf(hb + dd, 0.f));
          }
          *(ushort4*)(Aslab + (size_t)tl*3200 + v*128 + d0) = ov.s4;
        }
      }
    }
  }
}

// ---------- per-128-channel stats (channel-last rows) ----------
__global__ __launch_bounds__(256) void k_statsP(const u16* __restrict__ P, long nrows,
    float* __restrict__ s1g, float* __restrict__ s2g) {
  const int tid = threadIdx.x;
  const int f0 = (tid & 15) * 8;
  const int rg = tid >> 4;
  long rpb = nrows / gridDim.x;
  long rb = (long)blockIdx.x * rpb;
  float s1[8], s2[8];
  #pragma unroll
  for (int i = 0; i < 8; i++) { s1[i] = 0.f; s2[i] = 0.f; }
  for (long r = rg; r < rpb; r += 16) {
    union { int4 i4; u16 u[8]; } raw;
    raw.i4 = *(const int4*)(P + (rb + r)*128 + f0);
    #pragma unroll
    for (int i = 0; i < 8; i++) { float v = bf2f(raw.u[i]); s1[i] += v; s2[i] = fmaf(v, v, s2[i]); }
  }
  __shared__ float m1[16][128], m2[16][128];
  #pragma unroll
  for (int i = 0; i < 8; i++) { m1[rg][f0+i] = s1[i]; m2[rg][f0+i] = s2[i]; }
  __syncthreads();
  if (tid < 128) {
    float a = 0.f, b = 0.f;
    #pragma unroll
    for (int g = 0; g < 16; g++) { a += m1[g][tid]; b += m2[g][tid]; }
    atomicAdd(&s1g[tid], a); atomicAdd(&s2g[tid], b);
  }
}

// ---------- K3: bn(y)+shift(theta_in,1)+tl GEMM+bias+relu -> Z[n][t][v][op] bf16 (d_out) ----------
// TB=2: LDS ~31KB -> 5 blocks/CU
__global__ __launch_bounds__(256) void k3(
    const u16* __restrict__ Y,
    const float* __restrict__ ts1, const float* __restrict__ ts2,
    const float* __restrict__ tgamma, const float* __restrict__ tbeta,
    const int* __restrict__ perm1, const int* __restrict__ perm2,
    const float* __restrict__ ikPf, const float* __restrict__ frP,
    const float* __restrict__ tlTP, const float* __restrict__ tlb,
    u16* __restrict__ Z) {
  __shared__ float zsl[2][128][28];
  __shared__ float scL[128], shL[128], frL[128], tlbL[128];
  __shared__ int ikL[128];
  const int tg = blockIdx.x, n = blockIdx.y, tid = threadIdx.x;
  const int t2 = tg * 2;
  if (tid < 128) {
    int cp = tid, c = perm1[cp];
    float m = ts1[cp] * (1.f/409600.f);
    float var = fmaxf(ts2[cp]*(1.f/409600.f) - m*m, 0.f);
    float r = rsqrtf(var + EPS_);
    float sc = tgamma[c] * r;
    scL[cp] = sc; shL[cp] = tbeta[c] - m*sc;
    ikL[cp] = (int)ikPf[cp]; frL[cp] = frP[cp];
    tlbL[cp] = tlb[perm2[cp]];
  }
  for (int e = tid; e < 768; e += 256) { int q = e / 3; zsl[q>>7][q&127][25 + e%3] = 0.f; }
  __syncthreads();
  const u16* Yb = Y + (size_t)n * 204800;
  for (int e = tid; e < 6400; e += 256) {
    int cp = e & 127, v = (e >> 7) % 25, tl = e / 3200;
    int t0 = t2 + tl + ikL[cp];
    float fr = frL[cp], sc = scL[cp], sh = shL[cp];
    float a0 = (t0 >= 0 && t0 < 64) ? fmaf(bf2f(Yb[(size_t)t0*3200 + v*128 + cp]), sc, sh) : 0.f;
    int t1 = t0 + 1;
    float a1 = (t1 >= 0 && t1 < 64) ? fmaf(bf2f(Yb[(size_t)t1*3200 + v*128 + cp]), sc, sh) : 0.f;
    zsl[tl][cp][v] = (1.f - fr)*a0 + fr*a1;
  }
  __syncthreads();
  const int l = tid & 31, vq = tid >> 5;
  const int o0 = l * 4, v0 = vq * 4;
  if (vq < 7) {
    float acc[2][4][4];
    #pragma unroll
    for (int j = 0; j < 4; j++) {
      float bb = tlbL[o0 + j];
      #pragma unroll
      for (int tl = 0; tl < 2; tl++)
        #pragma unroll
        for (int k = 0; k < 4; k++) acc[tl][j][k] = bb;
    }
    for (int c = 0; c < 128; c++) {
      const float4 wv = *(const float4*)&tlTP[c*128 + o0];
      #pragma unroll
      for (int tl = 0; tl < 2; tl++) {
        const float4 xv = *(const float4*)&zsl[tl][c][v0];
        OUT16(acc[tl], wv, xv);
      }
    }
    u16* Zb = Z + (size_t)n*204800 + (size_t)t2*3200;
    #pragma unroll
    for (int tl = 0; tl < 2; tl++) {
      #pragma unroll
      for (int k = 0; k < 4; k++) {
        int v = v0 + k;
        if (v < 25) {
          union { ushort4 s4; u16 u[4]; } ov;
          #pragma unroll
          for (int j = 0; j < 4; j++) ov.u[j] = f2bf(fmaxf(acc[tl][j][k], 0.f));
          *(ushort4*)(Zb + (size_t)tl*3200 + v*128 + o0) = ov.s4;
        }
      }
    }
  }
}

// ---------- K4: stride-2 shift(theta_out) Z -> C[n][tp][v][op] bf16 ----------
__global__ __launch_bounds__(256) void k4(const u16* __restrict__ Z,
    const float* __restrict__ ik2Pf, const float* __restrict__ fr2P,
    u16* __restrict__ C) {
  __shared__ int ikL[128];
  __shared__ float frL[128];
  if (threadIdx.x < 128) { ikL[threadIdx.x] = (int)ik2Pf[threadIdx.x]; frL[threadIdx.x] = fr2P[threadIdx.x]; }
  __syncthreads();
  for (size_t idx = (size_t)blockIdx.x*256 + threadIdx.x; idx < 26214400ull; idx += (size_t)gridDim.x*256) {
    int op = (int)(idx & 127);
    int v  = (int)((idx >> 7) % 25);
    int tp = (int)((idx / 3200) & 31);
    int n  = (int)(idx / 102400);
    int t0 = 2*tp + ikL[op];
    float fr = frL[op];
    const u16* base = Z + (size_t)n*204800 + v*128 + op;
    float a0 = (t0 >= 0 && t0 < 64) ? bf2f(base[(size_t)t0*3200]) : 0.f;
    int t1 = t0 + 1;
    float a1 = (t1 >= 0 && t1 < 64) ? bf2f(base[(size_t)t1*3200]) : 0.f;
    C[idx] = f2bf((1.f - fr)*a0 + fr*a1);
  }
}

// ---------- K5: res GEMM + out = relu(bn2(C)+bn(res)) -> NCHW fp32 ----------
__global__ __launch_bounds__(256) void k5(
    const float* __restrict__ x, const u16* __restrict__ C,
    const float* __restrict__ rwTP,
    const float* __restrict__ scRP, const float* __restrict__ shRP,
    const float* __restrict__ zs1, const float* __restrict__ zs2,
    const float* __restrict__ t2g, const float* __restrict__ t2b,
    const int* __restrict__ perm2, float* __restrict__ out) {
  __shared__ float xs[2][64][28];
  __shared__ u16 ch[6400];
  __shared__ float sc2L[128], sh2L[128];
  __shared__ int p2L[128];
  const int tpg = blockIdx.x, n = blockIdx.y, tid = threadIdx.x;
  const int tp2 = tpg * 2;
  if (tid < 128) {
    int op = tid, o = perm2[op];
    float m = zs1[op] * (1.f/204800.f);
    float var = fmaxf(zs2[op]*(1.f/204800.f) - m*m, 0.f);
    float r = rsqrtf(var + EPS_);
    float sc = t2g[o] * r;
    sc2L[op] = sc; sh2L[op] = t2b[o] - m*sc;
    p2L[op] = o;
  }
  for (int e = tid; e < 384; e += 256) { int q = e / 3; xs[q>>6][q&63][25 + e%3] = 0.f; }
  const float* xb = x + (size_t)n * 102400;
  for (int e = tid; e < 3200; e += 256) {
    int tl = e / 1600, r = e - tl*1600, c = r / 25, v = r - c*25;
    xs[tl][c][v] = xb[c*1600 + 2*(tp2+tl)*25 + v];
  }
  {
    int4* dst = (int4*)ch;
    const int4* src = (const int4*)(C + (size_t)n*102400 + (size_t)tp2*3200);
    for (int i = tid; i < 800; i += 256) dst[i] = src[i];
  }
  __syncthreads();
  const int l = tid & 31, vq = tid >> 5;
  const int o0 = l * 4, v0 = vq * 4;
  if (vq < 7) {
    float acc[2][4][4];
    #pragma unroll
    for (int tl = 0; tl < 2; tl++)
      #pragma unroll
      for (int j = 0; j < 4; j++)
        #pragma unroll
        for (int k = 0; k < 4; k++) acc[tl][j][k] = 0.f;
    for (int c = 0; c < 64; c++) {
      const float4 wv = *(const float4*)&rwTP[c*128 + o0];
      #pragma unroll
      for (int tl = 0; tl < 2; tl++) {
        const float4 xv = *(const float4*)&xs[tl][c][v0];
        OUT16(acc[tl], wv, xv);
      }
    }
    const float4 scr = *(const float4*)&scRP[o0];
    const float4 shr = *(const float4*)&shRP[o0];
    #pragma unroll
    for (int tl = 0; tl < 2; tl++) {
      #pragma unroll
      for (int k = 0; k < 4; k++) {
        int v = v0 + k;
        if (v < 25) {
          union { ushort4 s4; u16 u[4]; } cv;
          cv.s4 = *(const ushort4*)&ch[(tl*25 + v)*128 + o0];
          #pragma unroll
          for (int j = 0; j < 4; j++) {
            float zv = fmaf(bf2f(cv.u[j]), sc2L[o0+j], sh2L[o0+j]);
            float rv = fmaf(acc[tl][j][k], ((const float*)&scr)[j], ((const float*)&shr)[j]);
            out[((size_t)(n*128 + p2L[o0+j])*32 + tp2 + tl)*25 + v] = fmaxf(zv + rv, 0.f);
          }
        }
      }
    }
  }
}

extern "C" void kernel_launch(void* const* d_in, const int* in_sizes, int n_in,
                              void* d_out, int out_size, void* d_ws, size_t ws_size,
                              hipStream_t stream) {
  (void)in_sizes; (void)n_in; (void)out_size;
  if (ws_size < 105200000ull) return;  // clean fail instead of OOB crash
  const float* x     = (const float*)d_in[0];
  const float* Wl    = (const float*)d_in[1];
  const float* fm    = (const float*)d_in[3];
  const float* gg    = (const float*)d_in[4];
  const float* gb    = (const float*)d_in[5];
  const float* dw    = (const float*)d_in[6];
  const float* dbg   = (const float*)d_in[8];
  const float* dbb   = (const float*)d_in[9];
  const float* tgam  = (const float*)d_in[10];
  const float* tbet  = (const float*)d_in[11];
  const float* thin  = (const float*)d_in[12];
  const float* tw    = (const float*)d_in[13];
  const float* tlb   = (const float*)d_in[14];
  const float* thout = (const float*)d_in[15];
  const float* t2g   = (const float*)d_in[16];
  const float* t2b   = (const float*)d_in[17];
  const float* rw    = (const float*)d_in[18];
  const float* rbg   = (const float*)d_in[20];
  const float* rbb   = (const float*)d_in[21];
  float* out = (float*)d_out;
  u16* Zd = (u16*)d_out;            // Z bf16 lives in d_out until k5 overwrites

  u16* A  = (u16*)d_ws;             // [256][64][25][128] bf16 = 104,857,600 B
  u16* Cb = A;                      // C aliases A (A dead after k3)
  float* S = (float*)((char*)d_ws + 104857600);
  float* mskT = S;                  // 1600
  float* WlP  = mskT + 1600;        // 8192
  float* dwTP = WlP + 8192;         // 8192
  float* rwTP = dwTP + 8192;        // 8192
  float* tlTP = rwTP + 8192;        // 16384
  float* scG  = tlTP + 16384;       // 3200
  float* shG  = scG + 3200;         // 3200
  float* scDP = shG + 3200;         // 128
  float* shDP = scDP + 128;
  float* scRP = shDP + 128;
  float* shRP = scRP + 128;
  float* ikPf = shRP + 128;
  float* frP  = ikPf + 128;
  float* ik2Pf= frP + 128;
  float* fr2P = ik2Pf + 128;
  float* Sxa  = fr2P + 128;         // zero region start (15232 floats)
  float* Sxe  = Sxa + 4096;
  float* suma = Sxe + 4096;
  float* sume = suma + 64;
  float* gs1  = sume + 64;
  float* gs2  = gs1 + 3200;
  float* ts1  = gs2 + 3200;
  float* ts2  = ts1 + 128;
  float* zs1  = ts2 + 128;
  float* zs2  = zs1 + 128;
  int* perm1  = (int*)(zs2 + 128);
  int* perm2  = perm1 + 128;

  (void)hipMemsetAsync(Sxa, 0, 15232 * sizeof(float), stream);
  k_prep0<<<1, 128, 0, stream>>>(thin, thout, perm1, perm2, ikPf, frP, ik2Pf, fr2P);
  k_prep1<<<64, 256, 0, stream>>>(fm, Wl, dw, rw, tw, perm1, perm2, mskT, WlP, dwTP, rwTP, tlTP);
  k_mom<<<512, 256, 0, stream>>>(x, Sxa, Sxe, suma, sume);
  k_fin<<<1, 256, 0, stream>>>(dw, dbg, dbb, rw, rbg, rbb, perm1, perm2,
                               Sxa, Sxe, suma, sume, scDP, shDP, scRP, shRP);
  k1<<<dim3(32, 256), 256, 0, stream>>>(x, WlP, mskT, perm1, A);
  k_statsA<<<dim3(2, 128), 256, 0, stream>>>(A, gs1, gs2);
  k_fin2<<<13, 256, 0, stream>>>(gs1, gs2, gg, gb, perm1, scG, shG);
  k2<<<dim3(32, 256), 256, 0, stream>>>(x, dwTP, scG, shG, scDP, shDP, A);
  k_statsP<<<200, 256, 0, stream>>>(A, 409600L, ts1, ts2);
  k3<<<dim3(32, 256), 256, 0, stream>>>(A, ts1, ts2, tgam, tbet, perm1, perm2,
                                        ikPf, frP, tlTP, tlb, Zd);
  k4<<<2048, 256, 0, stream>>>(Zd, ik2Pf, fr2P, Cb);
  k_statsP<<<100, 256, 0, stream>>>(Cb, 204800L, zs1, zs2);
  k5<<<dim3(16, 256), 256, 0, stream>>>(x, Cb, rwTP, scRP, shRP, zs1, zs2, t2g, t2b, perm2, out);
}

// Round 7
// 1331.425 us; speedup vs baseline: 1.4000x; 1.0392x over previous
//
#include <hip/hip_runtime.h>
#include <cstdint>
#include <cstddef>

namespace {
constexpr float EPS_ = 1e-5f;
}

using u16 = unsigned short;

static __device__ __forceinline__ float bf2f(u16 u) {
  union { unsigned int i; float f; } x; x.i = ((unsigned int)u) << 16; return x.f;
}
static __device__ __forceinline__ u16 f2bf(float f) {
  union { float f; unsigned int i; } x; x.f = f;
  unsigned int r = x.i + 0x7fff + ((x.i >> 16) & 1);
  return (u16)(r >> 16);
}

#define OUT16(a, wv, xv) \
  a[0][0]=fmaf(wv.x,xv.x,a[0][0]); a[0][1]=fmaf(wv.x,xv.y,a[0][1]); \
  a[0][2]=fmaf(wv.x,xv.z,a[0][2]); a[0][3]=fmaf(wv.x,xv.w,a[0][3]); \
  a[1][0]=fmaf(wv.y,xv.x,a[1][0]); a[1][1]=fmaf(wv.y,xv.y,a[1][1]); \
  a[1][2]=fmaf(wv.y,xv.z,a[1][2]); a[1][3]=fmaf(wv.y,xv.w,a[1][3]); \
  a[2][0]=fmaf(wv.z,xv.x,a[2][0]); a[2][1]=fmaf(wv.z,xv.y,a[2][1]); \
  a[2][2]=fmaf(wv.z,xv.z,a[2][2]); a[2][3]=fmaf(wv.z,xv.w,a[2][3]); \
  a[3][0]=fmaf(wv.w,xv.x,a[3][0]); a[3][1]=fmaf(wv.w,xv.y,a[3][1]); \
  a[3][2]=fmaf(wv.w,xv.z,a[3][2]); a[3][3]=fmaf(wv.w,xv.w,a[3][3]);

// ---------- prep0: channel permutations sorted by floor(theta) ----------
__global__ __launch_bounds__(128) void k_prep0(
    const float* __restrict__ thin, const float* __restrict__ thout,
    int* __restrict__ perm1, int* __restrict__ perm2,
    float* __restrict__ ikPf, float* __restrict__ frP,
    float* __restrict__ ik2Pf, float* __restrict__ fr2P) {
  __shared__ float ikL[128], ik2L[128];
  const int c = threadIdx.x;
  float t1 = thin[c], t2 = thout[c];
  float f1 = floorf(t1), f2 = floorf(t2);
  ikL[c] = f1; ik2L[c] = f2;
  __syncthreads();
  int r1 = 0, r2 = 0;
  for (int j = 0; j < 128; j++) {
    r1 += (ikL[j] < f1) || (ikL[j] == f1 && j < c);
    r2 += (ik2L[j] < f2) || (ik2L[j] == f2 && j < c);
  }
  perm1[r1] = c; ikPf[r1] = f1; frP[r1] = t1 - f1;
  perm2[r2] = c; ik2Pf[r2] = f2; fr2P[r2] = t2 - f2;
}

// ---------- prep1: mask + permuted weight transposes ----------
__global__ __launch_bounds__(256) void k_prep1(
    const float* __restrict__ fm, const float* __restrict__ Wl,
    const float* __restrict__ dw, const float* __restrict__ rw, const float* __restrict__ tw,
    const int* __restrict__ perm1, const int* __restrict__ perm2,
    float* __restrict__ mskT, float* __restrict__ WlP, float* __restrict__ dwTP,
    float* __restrict__ rwTP, float* __restrict__ tlTP) {
  int i = blockIdx.x * 256 + threadIdx.x;
  if (i < 1600) { int c = i / 25, w = i % 25; mskT[c*25 + w] = tanhf(fm[w*64 + c]) + 1.0f; }
  if (i < 8192) {
    int c = i >> 7, dp = i & 127;
    int d = perm1[dp], o = perm2[dp];
    WlP[i]  = Wl[c*128 + d];
    dwTP[i] = dw[d*64 + c];
    rwTP[i] = rw[o*64 + c];
  }
  if (i < 16384) { int cp = i >> 7, op = i & 127; tlTP[i] = tw[perm2[op]*128 + perm1[cp]]; }
}

// ---------- second moments of x (all t / even t) ----------
// Transposed LDS layout xs[sample][channel] (stride 68 -> 2-way read aliasing, free).
// grid = (4 quarters) x 256 n; each block: 16 t-slices in 4 staged chunks of 4 t (100 samples).
__global__ __launch_bounds__(256) void k_mom(const float* __restrict__ x,
    float* __restrict__ Sxa, float* __restrict__ Sxe,
    float* __restrict__ suma, float* __restrict__ sume) {
  __shared__ float xs[100][68];
  const int n = blockIdx.x >> 2, quarter = blockIdx.x & 3, tid = threadIdx.x;
  const int ci = (tid >> 4) * 4, cj = (tid & 15) * 4;
  float ae[4][4], ao[4][4], se[4], so[4];
  #pragma unroll
  for (int i = 0; i < 4; i++) {
    se[i] = 0.f; so[i] = 0.f;
    #pragma unroll
    for (int j = 0; j < 4; j++) { ae[i][j] = 0.f; ao[i][j] = 0.f; }
  }
  const float* xb = x + (size_t)n * 102400;
  for (int it = 0; it < 4; it++) {
    const int toff = quarter*16 + it*4;          // multiple of 4 -> even parity base
    // stage 4 t-slices (100 samples) transposed: xs[s][c]
    for (int e = tid; e < 1600; e += 256) {
      int c = e / 25, q = e - c*25;              // q: 25 float4 = 100 floats
      float4 vq4 = *(const float4*)&xb[(size_t)c*1600 + toff*25 + q*4];
      xs[q*4+0][c] = vq4.x; xs[q*4+1][c] = vq4.y;
      xs[q*4+2][c] = vq4.z; xs[q*4+3][c] = vq4.w;
    }
    __syncthreads();
    #pragma unroll
    for (int tl = 0; tl < 4; tl++) {
      #pragma unroll 5
      for (int vv = 0; vv < 25; vv++) {
        const int s = tl*25 + vv;
        const float4 ra = *(const float4*)&xs[s][ci];
        const float4 rb = *(const float4*)&xs[s][cj];
        if ((tl & 1) == 0) {
          OUT16(ae, ra, rb);
          if (cj == 0) { se[0] += ra.x; se[1] += ra.y; se[2] += ra.z; se[3] += ra.w; }
        } else {
          OUT16(ao, ra, rb);
          if (cj == 0) { so[0] += ra.x; so[1] += ra.y; so[2] += ra.z; so[3] += ra.w; }
        }
      }
    }
    __syncthreads();
  }
  #pragma unroll
  for (int i = 0; i < 4; i++) {
    #pragma unroll
    for (int j = 0; j < 4; j++) {
      atomicAdd(&Sxa[(ci+i)*64 + cj+j], ae[i][j] + ao[i][j]);
      atomicAdd(&Sxe[(ci+i)*64 + cj+j], ae[i][j]);
    }
  }
  if (cj == 0) {
    #pragma unroll
    for (int i = 0; i < 4; i++) {
      atomicAdd(&suma[ci+i], se[i] + so[i]);
      atomicAdd(&sume[ci+i], se[i]);
    }
  }
}

// ---------- analytic bn scale/shift for down (perm1) & res (perm2) ----------
__global__ __launch_bounds__(256) void k_fin(
    const float* __restrict__ dw, const float* __restrict__ dbg, const float* __restrict__ dbb,
    const float* __restrict__ rw, const float* __restrict__ rbg, const float* __restrict__ rbb,
    const int* __restrict__ perm1, const int* __restrict__ perm2,
    const float* __restrict__ Sxa, const float* __restrict__ Sxe,
    const float* __restrict__ suma, const float* __restrict__ sume,
    float* __restrict__ scDP, float* __restrict__ shDP,
    float* __restrict__ scRP, float* __restrict__ shRP) {
  __shared__ float SA[4096], SE[4096], sa[64], seL[64];
  const int tid = threadIdx.x;
  for (int i = tid; i < 4096; i += 256) { SA[i] = Sxa[i]; SE[i] = Sxe[i]; }
  if (tid < 64) { sa[tid] = suma[tid]; seL[tid] = sume[tid]; }
  __syncthreads();
  const bool down = tid < 128;
  const int p = tid & 127;
  const int o = down ? perm1[p] : perm2[p];
  const float* w = down ? dw : rw;
  const float* SS = down ? SA : SE;
  const float* sv = down ? sa : seL;
  const float iS = down ? (1.f/409600.f) : (1.f/204800.f);
  float wr[64];
  #pragma unroll
  for (int c = 0; c < 64; c += 4) {
    float4 t = *(const float4*)&w[o*64 + c];
    wr[c] = t.x; wr[c+1] = t.y; wr[c+2] = t.z; wr[c+3] = t.w;
  }
  float mu = 0.f, q = 0.f;
  for (int c = 0; c < 64; c++) {
    mu = fmaf(wr[c], sv[c], mu);
    float pp = 0.f;
    #pragma unroll 8
    for (int c2 = 0; c2 < 64; c2++) pp = fmaf(SS[c*64 + c2], wr[c2], pp);
    q = fmaf(wr[c], pp, q);
  }
  mu *= iS; q *= iS;
  float var = fmaxf(q - mu*mu, 0.f);
  float g = down ? dbg[o] : rbg[o];
  float b = down ? dbb[o] : rbb[o];
  float sc = g * rsqrtf(var + EPS_);
  if (down) { scDP[p] = sc; shDP[p] = b - mu*sc; }
  else      { scRP[p] = sc; shRP[p] = b - mu*sc; }
}

// ---------- K1: GCN GEMM (mask+shift in, vertex shuffle out) -> A[n][t][v][dp] bf16 ----------
__global__ __launch_bounds__(256) void k1(
    const float* __restrict__ x, const float* __restrict__ WlP,
    const float* __restrict__ mskT, const int* __restrict__ perm1,
    u16* __restrict__ A) {
  __shared__ float xm[2][64][28];
  __shared__ u16 ys[6400];
  __shared__ int p1L[128];
  const int tg = blockIdx.x, n = blockIdx.y, tid = threadIdx.x;
  const int t2 = tg * 2;
  if (tid < 128) p1L[tid] = perm1[tid];
  for (int e = tid; e < 384; e += 256) { int q = e / 3; xm[q>>6][q&63][25 + e%3] = 0.f; }
  const float* xb = x + (size_t)n * 102400;
  for (int e = tid; e < 3200; e += 256) {
    int tl = e / 1600, r = e - tl*1600, c = r / 25, w = r - c*25;
    int cm = c; if (cm >= 50) cm -= 50; else if (cm >= 25) cm -= 25;
    int vs = w + cm; if (vs >= 25) vs -= 25;
    xm[tl][c][w] = xb[c*1600 + (t2+tl)*25 + vs] * mskT[c*25 + w];
  }
  __syncthreads();
  const int l = tid & 31, vq = tid >> 5;
  const int d0 = l * 4, v0 = vq * 4;
  if (vq < 7) {
    float acc[2][4][4];
    #pragma unroll
    for (int tl = 0; tl < 2; tl++)
      #pragma unroll
      for (int j = 0; j < 4; j++)
        #pragma unroll
        for (int k = 0; k < 4; k++) acc[tl][j][k] = 0.f;
    for (int c = 0; c < 64; c++) {
      const float4 wv = *(const float4*)&WlP[c*128 + d0];
      #pragma unroll
      for (int tl = 0; tl < 2; tl++) {
        const float4 xv = *(const float4*)&xm[tl][c][v0];
        OUT16(acc[tl], wv, xv);
      }
    }
    #pragma unroll
    for (int tl = 0; tl < 2; tl++) {
      #pragma unroll
      for (int j = 0; j < 4; j++) {
        int d = p1L[d0 + j];
        int dm = d % 25;
        #pragma unroll
        for (int k = 0; k < 4; k++) {
          int w = v0 + k;
          if (w < 25) {
            int v = w + dm; if (v >= 25) v -= 25;
            ys[(tl*25 + v)*128 + d0 + j] = f2bf(acc[tl][j][k]);
          }
        }
      }
    }
  }
  __syncthreads();
  int4* dst = (int4*)(A + (size_t)n*204800 + (size_t)t2*3200);
  const int4* src = (const int4*)ys;
  for (int i = tid; i < 800; i += 256) dst[i] = src[i];
}

// ---------- stats over 3200 features (v,dp) of A ----------
__global__ __launch_bounds__(256) void k_statsA(const u16* __restrict__ A,
    float* __restrict__ gs1, float* __restrict__ gs2) {
  const int foct = blockIdx.x*256 + threadIdx.x;
  if (foct >= 400) return;
  const int rb = blockIdx.y * 128;
  const size_t f0 = (size_t)foct * 8;
  float s1[8], s2[8];
  #pragma unroll
  for (int i = 0; i < 8; i++) { s1[i] = 0.f; s2[i] = 0.f; }
  for (int r = 0; r < 128; r++) {
    union { int4 i4; u16 u[8]; } raw;
    raw.i4 = *(const int4*)(A + (size_t)(rb + r)*3200 + f0);
    #pragma unroll
    for (int i = 0; i < 8; i++) { float v = bf2f(raw.u[i]); s1[i] += v; s2[i] = fmaf(v, v, s2[i]); }
  }
  #pragma unroll
  for (int i = 0; i < 8; i++) { atomicAdd(&gs1[f0+i], s1[i]); atomicAdd(&gs2[f0+i], s2[i]); }
}

// ---------- finalize gcn bn scale/shift per (v,dp) ----------
__global__ __launch_bounds__(256) void k_fin2(
    const float* __restrict__ gs1, const float* __restrict__ gs2,
    const float* __restrict__ gg, const float* __restrict__ gb,
    const int* __restrict__ perm1,
    float* __restrict__ scG, float* __restrict__ shG) {
  int f = blockIdx.x*256 + threadIdx.x;
  if (f >= 3200) return;
  int v = f >> 7, dp = f & 127;
  int d = perm1[dp];
  float m = gs1[f] * (1.f/16384.f);
  float var = fmaxf(gs2[f]*(1.f/16384.f) - m*m, 0.f);
  float r = rsqrtf(var + EPS_);
  float sc = gg[v*128 + d] * r;
  scG[f] = sc; shG[f] = gb[v*128 + d] - m*sc;
}

// ---------- K2: down GEMM + y = relu(bn1d(h)+bn(down)), A in place ----------
__global__ __launch_bounds__(256) void k2(
    const float* __restrict__ x, const float* __restrict__ dwTP,
    const float* __restrict__ scG, const float* __restrict__ shG,
    const float* __restrict__ scDP, const float* __restrict__ shDP,
    u16* __restrict__ A) {
  __shared__ float xs[2][64][28];
  __shared__ u16 ah[6400];
  const int tg = blockIdx.x, n = blockIdx.y, tid = threadIdx.x;
  const int t2 = tg * 2;
  for (int e = tid; e < 384; e += 256) { int q = e / 3; xs[q>>6][q&63][25 + e%3] = 0.f; }
  const float* xb = x + (size_t)n * 102400;
  for (int e = tid; e < 3200; e += 256) {
    int tl = e / 1600, r = e - tl*1600, c = r / 25, v = r - c*25;
    xs[tl][c][v] = xb[c*1600 + (t2+tl)*25 + v];
  }
  u16* Aslab = A + (size_t)n*204800 + (size_t)t2*3200;
  {
    int4* dst = (int4*)ah;
    const int4* src = (const int4*)Aslab;
    for (int i = tid; i < 800; i += 256) dst[i] = src[i];
  }
  __syncthreads();
  const int l = tid & 31, vq = tid >> 5;
  const int d0 = l * 4, v0 = vq * 4;
  if (vq < 7) {
    float acc[2][4][4];
    #pragma unroll
    for (int tl = 0; tl < 2; tl++)
      #pragma unroll
      for (int j = 0; j < 4; j++)
        #pragma unroll
        for (int k = 0; k < 4; k++) acc[tl][j][k] = 0.f;
    for (int c = 0; c < 64; c++) {
      const float4 wv = *(const float4*)&dwTP[c*128 + d0];
      #pragma unroll
      for (int tl = 0; tl < 2; tl++) {
        const float4 xv = *(const float4*)&xs[tl][c][v0];
        OUT16(acc[tl], wv, xv);
      }
    }
    const float4 scd = *(const float4*)&scDP[d0];
    const float4 shd = *(const float4*)&shDP[d0];
    #pragma unroll
    for (int tl = 0; tl < 2; tl++) {
      #pragma unroll
      for (int k = 0; k < 4; k++) {
        int v = v0 + k;
        if (v < 25) {
          union { ushort4 s4; u16 u[4]; } hv, ov;
          hv.s4 = *(const ushort4*)&ah[(tl*25 + v)*128 + d0];
          const float4 sg = *(const float4*)&scG[v*128 + d0];
          const float4 hg = *(const float4*)&shG[v*128 + d0];
          #pragma unroll
          for (int j = 0; j < 4; j++) {
            float hb = fmaf(bf2f(hv.u[j]), ((const float*)&sg)[j], ((const float*)&hg)[j]);
            float dd = fmaf(acc[tl][j][k], ((const float*)&scd)[j], ((const float*)&shd)[j]);
            ov.u[j] = f2bf(fmaxf(hb + dd, 0.f));
          }
          *(ushort4*)(Aslab + (size_t)tl*3200 + v*128 + d0) = ov.s4;
        }
      }
    }
  }
}

// ---------- per-128-channel stats (channel-last rows) ----------
__global__ __launch_bounds__(256) void k_statsP(const u16* __restrict__ P, long nrows,
    float* __restrict__ s1g, float* __restrict__ s2g) {
  const int tid = threadIdx.x;
  const int f0 = (tid & 15) * 8;
  const int rg = tid >> 4;
  long rpb = nrows / gridDim.x;
  long rb = (long)blockIdx.x * rpb;
  float s1[8], s2[8];
  #pragma unroll
  for (int i = 0; i < 8; i++) { s1[i] = 0.f; s2[i] = 0.f; }
  for (long r = rg; r < rpb; r += 16) {
    union { int4 i4; u16 u[8]; } raw;
    raw.i4 = *(const int4*)(P + (rb + r)*128 + f0);
    #pragma unroll
    for (int i = 0; i < 8; i++) { float v = bf2f(raw.u[i]); s1[i] += v; s2[i] = fmaf(v, v, s2[i]); }
  }
  __shared__ float m1[16][128], m2[16][128];
  #pragma unroll
  for (int i = 0; i < 8; i++) { m1[rg][f0+i] = s1[i]; m2[rg][f0+i] = s2[i]; }
  __syncthreads();
  if (tid < 128) {
    float a = 0.f, b = 0.f;
    #pragma unroll
    for (int g = 0; g < 16; g++) { a += m1[g][tid]; b += m2[g][tid]; }
    atomicAdd(&s1g[tid], a); atomicAdd(&s2g[tid], b);
  }
}

// ---------- K3: bn(y)+shift(theta_in,1)+tl GEMM+bias+relu -> Z[n][t][v][op] bf16 (d_out) ----------
__global__ __launch_bounds__(256) void k3(
    const u16* __restrict__ Y,
    const float* __restrict__ ts1, const float* __restrict__ ts2,
    const float* __restrict__ tgamma, const float* __restrict__ tbeta,
    const int* __restrict__ perm1, const int* __restrict__ perm2,
    const float* __restrict__ ikPf, const float* __restrict__ frP,
    const float* __restrict__ tlTP, const float* __restrict__ tlb,
    u16* __restrict__ Z) {
  __shared__ float zsl[2][128][28];
  __shared__ float scL[128], shL[128], frL[128], tlbL[128];
  __shared__ int ikL[128];
  const int tg = blockIdx.x, n = blockIdx.y, tid = threadIdx.x;
  const int t2 = tg * 2;
  if (tid < 128) {
    int cp = tid, c = perm1[cp];
    float m = ts1[cp] * (1.f/409600.f);
    float var = fmaxf(ts2[cp]*(1.f/409600.f) - m*m, 0.f);
    float r = rsqrtf(var + EPS_);
    float sc = tgamma[c] * r;
    scL[cp] = sc; shL[cp] = tbeta[c] - m*sc;
    ikL[cp] = (int)ikPf[cp]; frL[cp] = frP[cp];
    tlbL[cp] = tlb[perm2[cp]];
  }
  for (int e = tid; e < 768; e += 256) { int q = e / 3; zsl[q>>7][q&127][25 + e%3] = 0.f; }
  __syncthreads();
  const u16* Yb = Y + (size_t)n * 204800;
  for (int e = tid; e < 6400; e += 256) {
    int cp = e & 127, v = (e >> 7) % 25, tl = e / 3200;
    int t0 = t2 + tl + ikL[cp];
    float fr = frL[cp], sc = scL[cp], sh = shL[cp];
    float a0 = (t0 >= 0 && t0 < 64) ? fmaf(bf2f(Yb[(size_t)t0*3200 + v*128 + cp]), sc, sh) : 0.f;
    int t1 = t0 + 1;
    float a1 = (t1 >= 0 && t1 < 64) ? fmaf(bf2f(Yb[(size_t)t1*3200 + v*128 + cp]), sc, sh) : 0.f;
    zsl[tl][cp][v] = (1.f - fr)*a0 + fr*a1;
  }
  __syncthreads();
  const int l = tid & 31, vq = tid >> 5;
  const int o0 = l * 4, v0 = vq * 4;
  if (vq < 7) {
    float acc[2][4][4];
    #pragma unroll
    for (int j = 0; j < 4; j++) {
      float bb = tlbL[o0 + j];
      #pragma unroll
      for (int tl = 0; tl < 2; tl++)
        #pragma unroll
        for (int k = 0; k < 4; k++) acc[tl][j][k] = bb;
    }
    for (int c = 0; c < 128; c++) {
      const float4 wv = *(const float4*)&tlTP[c*128 + o0];
      #pragma unroll
      for (int tl = 0; tl < 2; tl++) {
        const float4 xv = *(const float4*)&zsl[tl][c][v0];
        OUT16(acc[tl], wv, xv);
      }
    }
    u16* Zb = Z + (size_t)n*204800 + (size_t)t2*3200;
    #pragma unroll
    for (int tl = 0; tl < 2; tl++) {
      #pragma unroll
      for (int k = 0; k < 4; k++) {
        int v = v0 + k;
        if (v < 25) {
          union { ushort4 s4; u16 u[4]; } ov;
          #pragma unroll
          for (int j = 0; j < 4; j++) ov.u[j] = f2bf(fmaxf(acc[tl][j][k], 0.f));
          *(ushort4*)(Zb + (size_t)tl*3200 + v*128 + o0) = ov.s4;
        }
      }
    }
  }
}

// ---------- K4: stride-2 shift(theta_out) Z -> C[n][tp][v][op] bf16 ----------
__global__ __launch_bounds__(256) void k4(const u16* __restrict__ Z,
    const float* __restrict__ ik2Pf, const float* __restrict__ fr2P,
    u16* __restrict__ C) {
  __shared__ int ikL[128];
  __shared__ float frL[128];
  if (threadIdx.x < 128) { ikL[threadIdx.x] = (int)ik2Pf[threadIdx.x]; frL[threadIdx.x] = fr2P[threadIdx.x]; }
  __syncthreads();
  for (size_t idx = (size_t)blockIdx.x*256 + threadIdx.x; idx < 26214400ull; idx += (size_t)gridDim.x*256) {
    int op = (int)(idx & 127);
    int v  = (int)((idx >> 7) % 25);
    int tp = (int)((idx / 3200) & 31);
    int n  = (int)(idx / 102400);
    int t0 = 2*tp + ikL[op];
    float fr = frL[op];
    const u16* base = Z + (size_t)n*204800 + v*128 + op;
    float a0 = (t0 >= 0 && t0 < 64) ? bf2f(base[(size_t)t0*3200]) : 0.f;
    int t1 = t0 + 1;
    float a1 = (t1 >= 0 && t1 < 64) ? bf2f(base[(size_t)t1*3200]) : 0.f;
    C[idx] = f2bf((1.f - fr)*a0 + fr*a1);
  }
}

// ---------- K5: res GEMM + out = relu(bn2(C)+bn(res)) -> NCHW fp32 ----------
__global__ __launch_bounds__(256) void k5(
    const float* __restrict__ x, const u16* __restrict__ C,
    const float* __restrict__ rwTP,
    const float* __restrict__ scRP, const float* __restrict__ shRP,
    const float* __restrict__ zs1, const float* __restrict__ zs2,
    const float* __restrict__ t2g, const float* __restrict__ t2b,
    const int* __restrict__ perm2, float* __restrict__ out) {
  __shared__ float xs[2][64][28];
  __shared__ u16 ch[6400];
  __shared__ float sc2L[128], sh2L[128];
  __shared__ int p2L[128];
  const int tpg = blockIdx.x, n = blockIdx.y, tid = threadIdx.x;
  const int tp2 = tpg * 2;
  if (tid < 128) {
    int op = tid, o = perm2[op];
    float m = zs1[op] * (1.f/204800.f);
    float var = fmaxf(zs2[op]*(1.f/204800.f) - m*m, 0.f);
    float r = rsqrtf(var + EPS_);
    float sc = t2g[o] * r;
    sc2L[op] = sc; sh2L[op] = t2b[o] - m*sc;
    p2L[op] = o;
  }
  for (int e = tid; e < 384; e += 256) { int q = e / 3; xs[q>>6][q&63][25 + e%3] = 0.f; }
  const float* xb = x + (size_t)n * 102400;
  for (int e = tid; e < 3200; e += 256) {
    int tl = e / 1600, r = e - tl*1600, c = r / 25, v = r - c*25;
    xs[tl][c][v] = xb[c*1600 + 2*(tp2+tl)*25 + v];
  }
  {
    int4* dst = (int4*)ch;
    const int4* src = (const int4*)(C + (size_t)n*102400 + (size_t)tp2*3200);
    for (int i = tid; i < 800; i += 256) dst[i] = src[i];
  }
  __syncthreads();
  const int l = tid & 31, vq = tid >> 5;
  const int o0 = l * 4, v0 = vq * 4;
  if (vq < 7) {
    float acc[2][4][4];
    #pragma unroll
    for (int tl = 0; tl < 2; tl++)
      #pragma unroll
      for (int j = 0; j < 4; j++)
        #pragma unroll
        for (int k = 0; k < 4; k++) acc[tl][j][k] = 0.f;
    for (int c = 0; c < 64; c++) {
      const float4 wv = *(const float4*)&rwTP[c*128 + o0];
      #pragma unroll
      for (int tl = 0; tl < 2; tl++) {
        const float4 xv = *(const float4*)&xs[tl][c][v0];
        OUT16(acc[tl], wv, xv);
      }
    }
    const float4 scr = *(const float4*)&scRP[o0];
    const float4 shr = *(const float4*)&shRP[o0];
    #pragma unroll
    for (int tl = 0; tl < 2; tl++) {
      #pragma unroll
      for (int k = 0; k < 4; k++) {
        int v = v0 + k;
        if (v < 25) {
          union { ushort4 s4; u16 u[4]; } cv;
          cv.s4 = *(const ushort4*)&ch[(tl*25 + v)*128 + o0];
          #pragma unroll
          for (int j = 0; j < 4; j++) {
            float zv = fmaf(bf2f(cv.u[j]), sc2L[o0+j], sh2L[o0+j]);
            float rv = fmaf(acc[tl][j][k], ((const float*)&scr)[j], ((const float*)&shr)[j]);
            out[((size_t)(n*128 + p2L[o0+j])*32 + tp2 + tl)*25 + v] = fmaxf(zv + rv, 0.f);
          }
        }
      }
    }
  }
}

extern "C" void kernel_launch(void* const* d_in, const int* in_sizes, int n_in,
                              void* d_out, int out_size, void* d_ws, size_t ws_size,
                              hipStream_t stream) {
  (void)in_sizes; (void)n_in; (void)out_size;
  if (ws_size < 105200000ull) return;  // clean fail instead of OOB crash
  const float* x     = (const float*)d_in[0];
  const float* Wl    = (const float*)d_in[1];
  const float* fm    = (const float*)d_in[3];
  const float* gg    = (const float*)d_in[4];
  const float* gb    = (const float*)d_in[5];
  const float* dw    = (const float*)d_in[6];
  const float* dbg   = (const float*)d_in[8];
  const float* dbb   = (const float*)d_in[9];
  const float* tgam  = (const float*)d_in[10];
  const float* tbet  = (const float*)d_in[11];
  const float* thin  = (const float*)d_in[12];
  const float* tw    = (const float*)d_in[13];
  const float* tlb   = (const float*)d_in[14];
  const float* thout = (const float*)d_in[15];
  const float* t2g   = (const float*)d_in[16];
  const float* t2b   = (const float*)d_in[17];
  const float* rw    = (const float*)d_in[18];
  const float* rbg   = (const float*)d_in[20];
  const float* rbb   = (const float*)d_in[21];
  float* out = (float*)d_out;
  u16* Zd = (u16*)d_out;            // Z bf16 lives in d_out until k5 overwrites

  u16* A  = (u16*)d_ws;             // [256][64][25][128] bf16 = 104,857,600 B
  u16* Cb = A;                      // C aliases A (A dead after k3)
  float* S = (float*)((char*)d_ws + 104857600);
  float* mskT = S;                  // 1600
  float* WlP  = mskT + 1600;        // 8192
  float* dwTP = WlP + 8192;         // 8192
  float* rwTP = dwTP + 8192;        // 8192
  float* tlTP = rwTP + 8192;        // 16384
  float* scG  = tlTP + 16384;       // 3200
  float* shG  = scG + 3200;         // 3200
  float* scDP = shG + 3200;         // 128
  float* shDP = scDP + 128;
  float* scRP = shDP + 128;
  float* shRP = scRP + 128;
  float* ikPf = shRP + 128;
  float* frP  = ikPf + 128;
  float* ik2Pf= frP + 128;
  float* fr2P = ik2Pf + 128;
  float* Sxa  = fr2P + 128;         // zero region start (15232 floats)
  float* Sxe  = Sxa + 4096;
  float* suma = Sxe + 4096;
  float* sume = suma + 64;
  float* gs1  = sume + 64;
  float* gs2  = gs1 + 3200;
  float* ts1  = gs2 + 3200;
  float* ts2  = ts1 + 128;
  float* zs1  = ts2 + 128;
  float* zs2  = zs1 + 128;
  int* perm1  = (int*)(zs2 + 128);
  int* perm2  = perm1 + 128;

  (void)hipMemsetAsync(Sxa, 0, 15232 * sizeof(float), stream);
  k_prep0<<<1, 128, 0, stream>>>(thin, thout, perm1, perm2, ikPf, frP, ik2Pf, fr2P);
  k_prep1<<<64, 256, 0, stream>>>(fm, Wl, dw, rw, tw, perm1, perm2, mskT, WlP, dwTP, rwTP, tlTP);
  k_mom<<<1024, 256, 0, stream>>>(x, Sxa, Sxe, suma, sume);
  k_fin<<<1, 256, 0, stream>>>(dw, dbg, dbb, rw, rbg, rbb, perm1, perm2,
                               Sxa, Sxe, suma, sume, scDP, shDP, scRP, shRP);
  k1<<<dim3(32, 256), 256, 0, stream>>>(x, WlP, mskT, perm1, A);
  k_statsA<<<dim3(2, 128), 256, 0, stream>>>(A, gs1, gs2);
  k_fin2<<<13, 256, 0, stream>>>(gs1, gs2, gg, gb, perm1, scG, shG);
  k2<<<dim3(32, 256), 256, 0, stream>>>(x, dwTP, scG, shG, scDP, shDP, A);
  k_statsP<<<200, 256, 0, stream>>>(A, 409600L, ts1, ts2);
  k3<<<dim3(32, 256), 256, 0, stream>>>(A, ts1, ts2, tgam, tbet, perm1, perm2,
                                        ikPf, frP, tlTP, tlb, Zd);
  k4<<<2048, 256, 0, stream>>>(Zd, ik2Pf, fr2P, Cb);
  k_statsP<<<100, 256, 0, stream>>>(Cb, 204800L, zs1, zs2);
  k5<<<dim3(16, 256), 256, 0, stream>>>(x, Cb, rwTP, scRP, shRP, zs1, zs2, t2g, t2b, perm2, out);
}

// Round 8
// 1301.664 us; speedup vs baseline: 1.4320x; 1.0229x over previous
//
#include <hip/hip_runtime.h>
#include <cstdint>
#include <cstddef>

namespace {
constexpr float EPS_ = 1e-5f;
}

using u16 = unsigned short;
typedef __attribute__((ext_vector_type(8))) short bf16x8;
typedef __attribute__((ext_vector_type(4))) float f32x4;

static __device__ __forceinline__ float bf2f(u16 u) {
  union { unsigned int i; float f; } x; x.i = ((unsigned int)u) << 16; return x.f;
}
static __device__ __forceinline__ u16 f2bf(float f) {
  union { float f; unsigned int i; } x; x.f = f;
  unsigned int r = x.i + 0x7fff + ((x.i >> 16) & 1);
  return (u16)(r >> 16);
}

#define OUT16(a, wv, xv) \
  a[0][0]=fmaf(wv.x,xv.x,a[0][0]); a[0][1]=fmaf(wv.x,xv.y,a[0][1]); \
  a[0][2]=fmaf(wv.x,xv.z,a[0][2]); a[0][3]=fmaf(wv.x,xv.w,a[0][3]); \
  a[1][0]=fmaf(wv.y,xv.x,a[1][0]); a[1][1]=fmaf(wv.y,xv.y,a[1][1]); \
  a[1][2]=fmaf(wv.y,xv.z,a[1][2]); a[1][3]=fmaf(wv.y,xv.w,a[1][3]); \
  a[2][0]=fmaf(wv.z,xv.x,a[2][0]); a[2][1]=fmaf(wv.z,xv.y,a[2][1]); \
  a[2][2]=fmaf(wv.z,xv.z,a[2][2]); a[2][3]=fmaf(wv.z,xv.w,a[2][3]); \
  a[3][0]=fmaf(wv.w,xv.x,a[3][0]); a[3][1]=fmaf(wv.w,xv.y,a[3][1]); \
  a[3][2]=fmaf(wv.w,xv.z,a[3][2]); a[3][3]=fmaf(wv.w,xv.w,a[3][3]);

// ---------- prep0: channel permutations sorted by floor(theta) ----------
__global__ __launch_bounds__(128) void k_prep0(
    const float* __restrict__ thin, const float* __restrict__ thout,
    int* __restrict__ perm1, int* __restrict__ perm2,
    float* __restrict__ ikPf, float* __restrict__ frP,
    float* __restrict__ ik2Pf, float* __restrict__ fr2P) {
  __shared__ float ikL[128], ik2L[128];
  const int c = threadIdx.x;
  float t1 = thin[c], t2 = thout[c];
  float f1 = floorf(t1), f2 = floorf(t2);
  ikL[c] = f1; ik2L[c] = f2;
  __syncthreads();
  int r1 = 0, r2 = 0;
  for (int j = 0; j < 128; j++) {
    r1 += (ikL[j] < f1) || (ikL[j] == f1 && j < c);
    r2 += (ik2L[j] < f2) || (ik2L[j] == f2 && j < c);
  }
  perm1[r1] = c; ikPf[r1] = f1; frP[r1] = t1 - f1;
  perm2[r2] = c; ik2Pf[r2] = f2; fr2P[r2] = t2 - f2;
}

// ---------- prep1: mask + permuted weight transposes (tlBP: bf16, op-major for MFMA B-frag) ----------
__global__ __launch_bounds__(256) void k_prep1(
    const float* __restrict__ fm, const float* __restrict__ Wl,
    const float* __restrict__ dw, const float* __restrict__ rw, const float* __restrict__ tw,
    const int* __restrict__ perm1, const int* __restrict__ perm2,
    float* __restrict__ mskT, float* __restrict__ WlP, float* __restrict__ dwTP,
    float* __restrict__ rwTP, u16* __restrict__ tlBP) {
  int i = blockIdx.x * 256 + threadIdx.x;
  if (i < 1600) { int c = i / 25, w = i % 25; mskT[c*25 + w] = tanhf(fm[w*64 + c]) + 1.0f; }
  if (i < 8192) {
    int c = i >> 7, dp = i & 127;
    int d = perm1[dp], o = perm2[dp];
    WlP[i]  = Wl[c*128 + d];
    dwTP[i] = dw[d*64 + c];
    rwTP[i] = rw[o*64 + c];
  }
  if (i < 16384) { int op = i >> 7, cp = i & 127; tlBP[i] = f2bf(tw[perm2[op]*128 + perm1[cp]]); }
}

// ---------- second moments of x (all t / even t) ----------
__global__ __launch_bounds__(256) void k_mom(const float* __restrict__ x,
    float* __restrict__ Sxa, float* __restrict__ Sxe,
    float* __restrict__ suma, float* __restrict__ sume) {
  __shared__ float xs[100][68];
  const int n = blockIdx.x >> 2, quarter = blockIdx.x & 3, tid = threadIdx.x;
  const int ci = (tid >> 4) * 4, cj = (tid & 15) * 4;
  float ae[4][4], ao[4][4], se[4], so[4];
  #pragma unroll
  for (int i = 0; i < 4; i++) {
    se[i] = 0.f; so[i] = 0.f;
    #pragma unroll
    for (int j = 0; j < 4; j++) { ae[i][j] = 0.f; ao[i][j] = 0.f; }
  }
  const float* xb = x + (size_t)n * 102400;
  for (int it = 0; it < 4; it++) {
    const int toff = quarter*16 + it*4;
    for (int e = tid; e < 1600; e += 256) {
      int c = e / 25, q = e - c*25;
      float4 vq4 = *(const float4*)&xb[(size_t)c*1600 + toff*25 + q*4];
      xs[q*4+0][c] = vq4.x; xs[q*4+1][c] = vq4.y;
      xs[q*4+2][c] = vq4.z; xs[q*4+3][c] = vq4.w;
    }
    __syncthreads();
    #pragma unroll
    for (int tl = 0; tl < 4; tl++) {
      #pragma unroll 5
      for (int vv = 0; vv < 25; vv++) {
        const int s = tl*25 + vv;
        const float4 ra = *(const float4*)&xs[s][ci];
        const float4 rb = *(const float4*)&xs[s][cj];
        if ((tl & 1) == 0) {
          OUT16(ae, ra, rb);
          if (cj == 0) { se[0] += ra.x; se[1] += ra.y; se[2] += ra.z; se[3] += ra.w; }
        } else {
          OUT16(ao, ra, rb);
          if (cj == 0) { so[0] += ra.x; so[1] += ra.y; so[2] += ra.z; so[3] += ra.w; }
        }
      }
    }
    __syncthreads();
  }
  #pragma unroll
  for (int i = 0; i < 4; i++) {
    #pragma unroll
    for (int j = 0; j < 4; j++) {
      atomicAdd(&Sxa[(ci+i)*64 + cj+j], ae[i][j] + ao[i][j]);
      atomicAdd(&Sxe[(ci+i)*64 + cj+j], ae[i][j]);
    }
  }
  if (cj == 0) {
    #pragma unroll
    for (int i = 0; i < 4; i++) {
      atomicAdd(&suma[ci+i], se[i] + so[i]);
      atomicAdd(&sume[ci+i], se[i]);
    }
  }
}

// ---------- analytic bn scale/shift for down (perm1) & res (perm2) ----------
__global__ __launch_bounds__(256) void k_fin(
    const float* __restrict__ dw, const float* __restrict__ dbg, const float* __restrict__ dbb,
    const float* __restrict__ rw, const float* __restrict__ rbg, const float* __restrict__ rbb,
    const int* __restrict__ perm1, const int* __restrict__ perm2,
    const float* __restrict__ Sxa, const float* __restrict__ Sxe,
    const float* __restrict__ suma, const float* __restrict__ sume,
    float* __restrict__ scDP, float* __restrict__ shDP,
    float* __restrict__ scRP, float* __restrict__ shRP) {
  __shared__ float SA[4096], SE[4096], sa[64], seL[64];
  const int tid = threadIdx.x;
  for (int i = tid; i < 4096; i += 256) { SA[i] = Sxa[i]; SE[i] = Sxe[i]; }
  if (tid < 64) { sa[tid] = suma[tid]; seL[tid] = sume[tid]; }
  __syncthreads();
  const bool down = tid < 128;
  const int p = tid & 127;
  const int o = down ? perm1[p] : perm2[p];
  const float* w = down ? dw : rw;
  const float* SS = down ? SA : SE;
  const float* sv = down ? sa : seL;
  const float iS = down ? (1.f/409600.f) : (1.f/204800.f);
  float wr[64];
  #pragma unroll
  for (int c = 0; c < 64; c += 4) {
    float4 t = *(const float4*)&w[o*64 + c];
    wr[c] = t.x; wr[c+1] = t.y; wr[c+2] = t.z; wr[c+3] = t.w;
  }
  float mu = 0.f, q = 0.f;
  for (int c = 0; c < 64; c++) {
    mu = fmaf(wr[c], sv[c], mu);
    float pp = 0.f;
    #pragma unroll 8
    for (int c2 = 0; c2 < 64; c2++) pp = fmaf(SS[c*64 + c2], wr[c2], pp);
    q = fmaf(wr[c], pp, q);
  }
  mu *= iS; q *= iS;
  float var = fmaxf(q - mu*mu, 0.f);
  float g = down ? dbg[o] : rbg[o];
  float b = down ? dbb[o] : rbb[o];
  float sc = g * rsqrtf(var + EPS_);
  if (down) { scDP[p] = sc; shDP[p] = b - mu*sc; }
  else      { scRP[p] = sc; shRP[p] = b - mu*sc; }
}

// ---------- K1: GCN GEMM (mask+shift in, vertex shuffle out) -> A[n][t][v][dp] bf16 ----------
__global__ __launch_bounds__(256) void k1(
    const float* __restrict__ x, const float* __restrict__ WlP,
    const float* __restrict__ mskT, const int* __restrict__ perm1,
    u16* __restrict__ A) {
  __shared__ float xm[2][64][28];
  __shared__ u16 ys[6400];
  __shared__ int p1L[128];
  const int tg = blockIdx.x, n = blockIdx.y, tid = threadIdx.x;
  const int t2 = tg * 2;
  if (tid < 128) p1L[tid] = perm1[tid];
  for (int e = tid; e < 384; e += 256) { int q = e / 3; xm[q>>6][q&63][25 + e%3] = 0.f; }
  const float* xb = x + (size_t)n * 102400;
  for (int e = tid; e < 3200; e += 256) {
    int tl = e / 1600, r = e - tl*1600, c = r / 25, w = r - c*25;
    int cm = c; if (cm >= 50) cm -= 50; else if (cm >= 25) cm -= 25;
    int vs = w + cm; if (vs >= 25) vs -= 25;
    xm[tl][c][w] = xb[c*1600 + (t2+tl)*25 + vs] * mskT[c*25 + w];
  }
  __syncthreads();
  const int l = tid & 31, vq = tid >> 5;
  const int d0 = l * 4, v0 = vq * 4;
  if (vq < 7) {
    float acc[2][4][4];
    #pragma unroll
    for (int tl = 0; tl < 2; tl++)
      #pragma unroll
      for (int j = 0; j < 4; j++)
        #pragma unroll
        for (int k = 0; k < 4; k++) acc[tl][j][k] = 0.f;
    for (int c = 0; c < 64; c++) {
      const float4 wv = *(const float4*)&WlP[c*128 + d0];
      #pragma unroll
      for (int tl = 0; tl < 2; tl++) {
        const float4 xv = *(const float4*)&xm[tl][c][v0];
        OUT16(acc[tl], wv, xv);
      }
    }
    #pragma unroll
    for (int tl = 0; tl < 2; tl++) {
      #pragma unroll
      for (int j = 0; j < 4; j++) {
        int d = p1L[d0 + j];
        int dm = d % 25;
        #pragma unroll
        for (int k = 0; k < 4; k++) {
          int w = v0 + k;
          if (w < 25) {
            int v = w + dm; if (v >= 25) v -= 25;
            ys[(tl*25 + v)*128 + d0 + j] = f2bf(acc[tl][j][k]);
          }
        }
      }
    }
  }
  __syncthreads();
  int4* dst = (int4*)(A + (size_t)n*204800 + (size_t)t2*3200);
  const int4* src = (const int4*)ys;
  for (int i = tid; i < 800; i += 256) dst[i] = src[i];
}

// ---------- stats over 3200 features (v,dp) of A ----------
__global__ __launch_bounds__(256) void k_statsA(const u16* __restrict__ A,
    float* __restrict__ gs1, float* __restrict__ gs2) {
  const int foct = blockIdx.x*256 + threadIdx.x;
  if (foct >= 400) return;
  const int rb = blockIdx.y * 128;
  const size_t f0 = (size_t)foct * 8;
  float s1[8], s2[8];
  #pragma unroll
  for (int i = 0; i < 8; i++) { s1[i] = 0.f; s2[i] = 0.f; }
  for (int r = 0; r < 128; r++) {
    union { int4 i4; u16 u[8]; } raw;
    raw.i4 = *(const int4*)(A + (size_t)(rb + r)*3200 + f0);
    #pragma unroll
    for (int i = 0; i < 8; i++) { float v = bf2f(raw.u[i]); s1[i] += v; s2[i] = fmaf(v, v, s2[i]); }
  }
  #pragma unroll
  for (int i = 0; i < 8; i++) { atomicAdd(&gs1[f0+i], s1[i]); atomicAdd(&gs2[f0+i], s2[i]); }
}

// ---------- finalize gcn bn scale/shift per (v,dp) ----------
__global__ __launch_bounds__(256) void k_fin2(
    const float* __restrict__ gs1, const float* __restrict__ gs2,
    const float* __restrict__ gg, const float* __restrict__ gb,
    const int* __restrict__ perm1,
    float* __restrict__ scG, float* __restrict__ shG) {
  int f = blockIdx.x*256 + threadIdx.x;
  if (f >= 3200) return;
  int v = f >> 7, dp = f & 127;
  int d = perm1[dp];
  float m = gs1[f] * (1.f/16384.f);
  float var = fmaxf(gs2[f]*(1.f/16384.f) - m*m, 0.f);
  float r = rsqrtf(var + EPS_);
  float sc = gg[v*128 + d] * r;
  scG[f] = sc; shG[f] = gb[v*128 + d] - m*sc;
}

// ---------- K2: down GEMM + y = relu(bn1d(h)+bn(down)), A in place ----------
__global__ __launch_bounds__(256) void k2(
    const float* __restrict__ x, const float* __restrict__ dwTP,
    const float* __restrict__ scG, const float* __restrict__ shG,
    const float* __restrict__ scDP, const float* __restrict__ shDP,
    u16* __restrict__ A) {
  __shared__ float xs[2][64][28];
  __shared__ u16 ah[6400];
  const int tg = blockIdx.x, n = blockIdx.y, tid = threadIdx.x;
  const int t2 = tg * 2;
  for (int e = tid; e < 384; e += 256) { int q = e / 3; xs[q>>6][q&63][25 + e%3] = 0.f; }
  const float* xb = x + (size_t)n * 102400;
  for (int e = tid; e < 3200; e += 256) {
    int tl = e / 1600, r = e - tl*1600, c = r / 25, v = r - c*25;
    xs[tl][c][v] = xb[c*1600 + (t2+tl)*25 + v];
  }
  u16* Aslab = A + (size_t)n*204800 + (size_t)t2*3200;
  {
    int4* dst = (int4*)ah;
    const int4* src = (const int4*)Aslab;
    for (int i = tid; i < 800; i += 256) dst[i] = src[i];
  }
  __syncthreads();
  const int l = tid & 31, vq = tid >> 5;
  const int d0 = l * 4, v0 = vq * 4;
  if (vq < 7) {
    float acc[2][4][4];
    #pragma unroll
    for (int tl = 0; tl < 2; tl++)
      #pragma unroll
      for (int j = 0; j < 4; j++)
        #pragma unroll
        for (int k = 0; k < 4; k++) acc[tl][j][k] = 0.f;
    for (int c = 0; c < 64; c++) {
      const float4 wv = *(const float4*)&dwTP[c*128 + d0];
      #pragma unroll
      for (int tl = 0; tl < 2; tl++) {
        const float4 xv = *(const float4*)&xs[tl][c][v0];
        OUT16(acc[tl], wv, xv);
      }
    }
    const float4 scd = *(const float4*)&scDP[d0];
    const float4 shd = *(const float4*)&shDP[d0];
    #pragma unroll
    for (int tl = 0; tl < 2; tl++) {
      #pragma unroll
      for (int k = 0; k < 4; k++) {
        int v = v0 + k;
        if (v < 25) {
          union { ushort4 s4; u16 u[4]; } hv, ov;
          hv.s4 = *(const ushort4*)&ah[(tl*25 + v)*128 + d0];
          const float4 sg = *(const float4*)&scG[v*128 + d0];
          const float4 hg = *(const float4*)&shG[v*128 + d0];
          #pragma unroll
          for (int j = 0; j < 4; j++) {
            float hb = fmaf(bf2f(hv.u[j]), ((const float*)&sg)[j], ((const float*)&hg)[j]);
            float dd = fmaf(acc[tl][j][k], ((const float*)&scd)[j], ((const float*)&shd)[j]);
            ov.u[j] = f2bf(fmaxf(hb + dd, 0.f));
          }
          *(ushort4*)(Aslab + (size_t)tl*3200 + v*128 + d0) = ov.s4;
        }
      }
    }
  }
}

// ---------- per-128-channel stats (channel-last rows) ----------
__global__ __launch_bounds__(256) void k_statsP(const u16* __restrict__ P, long nrows,
    float* __restrict__ s1g, float* __restrict__ s2g) {
  const int tid = threadIdx.x;
  const int f0 = (tid & 15) * 8;
  const int rg = tid >> 4;
  long rpb = nrows / gridDim.x;
  long rb = (long)blockIdx.x * rpb;
  float s1[8], s2[8];
  #pragma unroll
  for (int i = 0; i < 8; i++) { s1[i] = 0.f; s2[i] = 0.f; }
  for (long r = rg; r < rpb; r += 16) {
    union { int4 i4; u16 u[8]; } raw;
    raw.i4 = *(const int4*)(P + (rb + r)*128 + f0);
    #pragma unroll
    for (int i = 0; i < 8; i++) { float v = bf2f(raw.u[i]); s1[i] += v; s2[i] = fmaf(v, v, s2[i]); }
  }
  __shared__ float m1[16][128], m2[16][128];
  #pragma unroll
  for (int i = 0; i < 8; i++) { m1[rg][f0+i] = s1[i]; m2[rg][f0+i] = s2[i]; }
  __syncthreads();
  if (tid < 128) {
    float a = 0.f, b = 0.f;
    #pragma unroll
    for (int g = 0; g < 16; g++) { a += m1[g][tid]; b += m2[g][tid]; }
    atomicAdd(&s1g[tid], a); atomicAdd(&s2g[tid], b);
  }
}

// ---------- K3 (MFMA): bn(y)+shift(theta_in,1)+tl GEMM+bias+relu -> Z[n][t][v][op] bf16 (d_out) ----------
// A-tile zslT[64][136] bf16 (stride 272B => conflict-free b128 reads); B-frags from global tlBP (L1/L2-hot).
// 4 waves x (8 n-tiles x 4 k-steps) mfma_f32_16x16x32_bf16. Rows 50..63 garbage, never written.
__global__ __launch_bounds__(256) void k3(
    const u16* __restrict__ Y,
    const float* __restrict__ ts1, const float* __restrict__ ts2,
    const float* __restrict__ tgamma, const float* __restrict__ tbeta,
    const int* __restrict__ perm1, const int* __restrict__ perm2,
    const float* __restrict__ ikPf, const float* __restrict__ frP,
    const u16* __restrict__ tlBP, const float* __restrict__ tlb,
    u16* __restrict__ Z) {
  __shared__ u16 zslT[64][136];
  __shared__ u16 ys[50][136];
  __shared__ float scL[128], shL[128], frL[128], tlbL[128];
  __shared__ int ikL[128];
  const int tg = blockIdx.x, n = blockIdx.y, tid = threadIdx.x;
  const int t2 = tg * 2;
  if (tid < 128) {
    int cp = tid, c = perm1[cp];
    float m = ts1[cp] * (1.f/409600.f);
    float var = fmaxf(ts2[cp]*(1.f/409600.f) - m*m, 0.f);
    float r = rsqrtf(var + EPS_);
    float sc = tgamma[c] * r;
    scL[cp] = sc; shL[cp] = tbeta[c] - m*sc;
    ikL[cp] = (int)ikPf[cp]; frL[cp] = frP[cp];
    tlbL[cp] = tlb[perm2[cp]];
  }
  __syncthreads();
  const u16* Yb = Y + (size_t)n * 204800;
  for (int e = tid; e < 6400; e += 256) {
    int cp = e & 127, v = (e >> 7) % 25, tl = e / 3200;
    int t0 = t2 + tl + ikL[cp];
    float fr = frL[cp], sc = scL[cp], sh = shL[cp];
    float a0 = (t0 >= 0 && t0 < 64) ? fmaf(bf2f(Yb[(size_t)t0*3200 + v*128 + cp]), sc, sh) : 0.f;
    int t1 = t0 + 1;
    float a1 = (t1 >= 0 && t1 < 64) ? fmaf(bf2f(Yb[(size_t)t1*3200 + v*128 + cp]), sc, sh) : 0.f;
    zslT[tl*25 + v][cp] = f2bf((1.f - fr)*a0 + fr*a1);
  }
  __syncthreads();
  const int w = tid >> 6, l = tid & 63;
  const int lc = l & 15, kg = l >> 4;      // lc: A-row / B-col / D-col; kg: k-group
  f32x4 acc[8];
  #pragma unroll
  for (int nt = 0; nt < 8; nt++) {
    float bb = tlbL[nt*16 + lc];
    acc[nt][0] = bb; acc[nt][1] = bb; acc[nt][2] = bb; acc[nt][3] = bb;
  }
  #pragma unroll
  for (int ks = 0; ks < 4; ks++) {
    const bf16x8 a = *(const bf16x8*)&zslT[w*16 + lc][ks*32 + kg*8];
    #pragma unroll
    for (int nt = 0; nt < 8; nt++) {
      const bf16x8 b = *(const bf16x8*)&tlBP[(size_t)(nt*16 + lc)*128 + ks*32 + kg*8];
      acc[nt] = __builtin_amdgcn_mfma_f32_16x16x32_bf16(a, b, acc[nt], 0, 0, 0);
    }
  }
  #pragma unroll
  for (int nt = 0; nt < 8; nt++) {
    const int op = nt*16 + lc;
    #pragma unroll
    for (int r = 0; r < 4; r++) {
      const int s = w*16 + kg*4 + r;
      if (s < 50) ys[s][op] = f2bf(fmaxf(acc[nt][r], 0.f));
    }
  }
  __syncthreads();
  u16* Zb = Z + (size_t)n*204800 + (size_t)t2*3200;
  for (int i = tid; i < 800; i += 256) {
    int s = i >> 4, ch = i & 15;
    *(int4*)(Zb + s*128 + ch*8) = *(const int4*)&ys[s][ch*8];
  }
}

// ---------- K4: stride-2 shift(theta_out) Z -> C[n][tp][v][op] bf16 ----------
__global__ __launch_bounds__(256) void k4(const u16* __restrict__ Z,
    const float* __restrict__ ik2Pf, const float* __restrict__ fr2P,
    u16* __restrict__ C) {
  __shared__ int ikL[128];
  __shared__ float frL[128];
  if (threadIdx.x < 128) { ikL[threadIdx.x] = (int)ik2Pf[threadIdx.x]; frL[threadIdx.x] = fr2P[threadIdx.x]; }
  __syncthreads();
  for (size_t idx = (size_t)blockIdx.x*256 + threadIdx.x; idx < 26214400ull; idx += (size_t)gridDim.x*256) {
    int op = (int)(idx & 127);
    int v  = (int)((idx >> 7) % 25);
    int tp = (int)((idx / 3200) & 31);
    int n  = (int)(idx / 102400);
    int t0 = 2*tp + ikL[op];
    float fr = frL[op];
    const u16* base = Z + (size_t)n*204800 + v*128 + op;
    float a0 = (t0 >= 0 && t0 < 64) ? bf2f(base[(size_t)t0*3200]) : 0.f;
    int t1 = t0 + 1;
    float a1 = (t1 >= 0 && t1 < 64) ? bf2f(base[(size_t)t1*3200]) : 0.f;
    C[idx] = f2bf((1.f - fr)*a0 + fr*a1);
  }
}

// ---------- K5: res GEMM + out = relu(bn2(C)+bn(res)) -> NCHW fp32 ----------
__global__ __launch_bounds__(256) void k5(
    const float* __restrict__ x, const u16* __restrict__ C,
    const float* __restrict__ rwTP,
    const float* __restrict__ scRP, const float* __restrict__ shRP,
    const float* __restrict__ zs1, const float* __restrict__ zs2,
    const float* __restrict__ t2g, const float* __restrict__ t2b,
    const int* __restrict__ perm2, float* __restrict__ out) {
  __shared__ float xs[2][64][28];
  __shared__ u16 ch[6400];
  __shared__ float sc2L[128], sh2L[128];
  __shared__ int p2L[128];
  const int tpg = blockIdx.x, n = blockIdx.y, tid = threadIdx.x;
  const int tp2 = tpg * 2;
  if (tid < 128) {
    int op = tid, o = perm2[op];
    float m = zs1[op] * (1.f/204800.f);
    float var = fmaxf(zs2[op]*(1.f/204800.f) - m*m, 0.f);
    float r = rsqrtf(var + EPS_);
    float sc = t2g[o] * r;
    sc2L[op] = sc; sh2L[op] = t2b[o] - m*sc;
    p2L[op] = o;
  }
  for (int e = tid; e < 384; e += 256) { int q = e / 3; xs[q>>6][q&63][25 + e%3] = 0.f; }
  const float* xb = x + (size_t)n * 102400;
  for (int e = tid; e < 3200; e += 256) {
    int tl = e / 1600, r = e - tl*1600, c = r / 25, v = r - c*25;
    xs[tl][c][v] = xb[c*1600 + 2*(tp2+tl)*25 + v];
  }
  {
    int4* dst = (int4*)ch;
    const int4* src = (const int4*)(C + (size_t)n*102400 + (size_t)tp2*3200);
    for (int i = tid; i < 800; i += 256) dst[i] = src[i];
  }
  __syncthreads();
  const int l = tid & 31, vq = tid >> 5;
  const int o0 = l * 4, v0 = vq * 4;
  if (vq < 7) {
    float acc[2][4][4];
    #pragma unroll
    for (int tl = 0; tl < 2; tl++)
      #pragma unroll
      for (int j = 0; j < 4; j++)
        #pragma unroll
        for (int k = 0; k < 4; k++) acc[tl][j][k] = 0.f;
    for (int c = 0; c < 64; c++) {
      const float4 wv = *(const float4*)&rwTP[c*128 + o0];
      #pragma unroll
      for (int tl = 0; tl < 2; tl++) {
        const float4 xv = *(const float4*)&xs[tl][c][v0];
        OUT16(acc[tl], wv, xv);
      }
    }
    const float4 scr = *(const float4*)&scRP[o0];
    const float4 shr = *(const float4*)&shRP[o0];
    #pragma unroll
    for (int tl = 0; tl < 2; tl++) {
      #pragma unroll
      for (int k = 0; k < 4; k++) {
        int v = v0 + k;
        if (v < 25) {
          union { ushort4 s4; u16 u[4]; } cv;
          cv.s4 = *(const ushort4*)&ch[(tl*25 + v)*128 + o0];
          #pragma unroll
          for (int j = 0; j < 4; j++) {
            float zv = fmaf(bf2f(cv.u[j]), sc2L[o0+j], sh2L[o0+j]);
            float rv = fmaf(acc[tl][j][k], ((const float*)&scr)[j], ((const float*)&shr)[j]);
            out[((size_t)(n*128 + p2L[o0+j])*32 + tp2 + tl)*25 + v] = fmaxf(zv + rv, 0.f);
          }
        }
      }
    }
  }
}

extern "C" void kernel_launch(void* const* d_in, const int* in_sizes, int n_in,
                              void* d_out, int out_size, void* d_ws, size_t ws_size,
                              hipStream_t stream) {
  (void)in_sizes; (void)n_in; (void)out_size;
  if (ws_size < 105200000ull) return;  // clean fail instead of OOB crash
  const float* x     = (const float*)d_in[0];
  const float* Wl    = (const float*)d_in[1];
  const float* fm    = (const float*)d_in[3];
  const float* gg    = (const float*)d_in[4];
  const float* gb    = (const float*)d_in[5];
  const float* dw    = (const float*)d_in[6];
  const float* dbg   = (const float*)d_in[8];
  const float* dbb   = (const float*)d_in[9];
  const float* tgam  = (const float*)d_in[10];
  const float* tbet  = (const float*)d_in[11];
  const float* thin  = (const float*)d_in[12];
  const float* tw    = (const float*)d_in[13];
  const float* tlb   = (const float*)d_in[14];
  const float* thout = (const float*)d_in[15];
  const float* t2g   = (const float*)d_in[16];
  const float* t2b   = (const float*)d_in[17];
  const float* rw    = (const float*)d_in[18];
  const float* rbg   = (const float*)d_in[20];
  const float* rbb   = (const float*)d_in[21];
  float* out = (float*)d_out;
  u16* Zd = (u16*)d_out;            // Z bf16 lives in d_out until k5 overwrites

  u16* A  = (u16*)d_ws;             // [256][64][25][128] bf16 = 104,857,600 B
  u16* Cb = A;                      // C aliases A (A dead after k3)
  float* S = (float*)((char*)d_ws + 104857600);
  float* mskT = S;                  // 1600
  float* WlP  = mskT + 1600;        // 8192
  float* dwTP = WlP + 8192;         // 8192
  float* rwTP = dwTP + 8192;        // 8192
  u16*  tlBP  = (u16*)(rwTP + 8192);// 16384 u16 (occupies half of old 16384-float slot)
  float* scG  = rwTP + 8192 + 16384;// 3200
  float* shG  = scG + 3200;         // 3200
  float* scDP = shG + 3200;         // 128
  float* shDP = scDP + 128;
  float* scRP = shDP + 128;
  float* shRP = scRP + 128;
  float* ikPf = shRP + 128;
  float* frP  = ikPf + 128;
  float* ik2Pf= frP + 128;
  float* fr2P = ik2Pf + 128;
  float* Sxa  = fr2P + 128;         // zero region start (15232 floats)
  float* Sxe  = Sxa + 4096;
  float* suma = Sxe + 4096;
  float* sume = suma + 64;
  float* gs1  = sume + 64;
  float* gs2  = gs1 + 3200;
  float* ts1  = gs2 + 3200;
  float* ts2  = ts1 + 128;
  float* zs1  = ts2 + 128;
  float* zs2  = zs1 + 128;
  int* perm1  = (int*)(zs2 + 128);
  int* perm2  = perm1 + 128;

  (void)hipMemsetAsync(Sxa, 0, 15232 * sizeof(float), stream);
  k_prep0<<<1, 128, 0, stream>>>(thin, thout, perm1, perm2, ikPf, frP, ik2Pf, fr2P);
  k_prep1<<<64, 256, 0, stream>>>(fm, Wl, dw, rw, tw, perm1, perm2, mskT, WlP, dwTP, rwTP, tlBP);
  k_mom<<<1024, 256, 0, stream>>>(x, Sxa, Sxe, suma, sume);
  k_fin<<<1, 256, 0, stream>>>(dw, dbg, dbb, rw, rbg, rbb, perm1, perm2,
                               Sxa, Sxe, suma, sume, scDP, shDP, scRP, shRP);
  k1<<<dim3(32, 256), 256, 0, stream>>>(x, WlP, mskT, perm1, A);
  k_statsA<<<dim3(2, 128), 256, 0, stream>>>(A, gs1, gs2);
  k_fin2<<<13, 256, 0, stream>>>(gs1, gs2, gg, gb, perm1, scG, shG);
  k2<<<dim3(32, 256), 256, 0, stream>>>(x, dwTP, scG, shG, scDP, shDP, A);
  k_statsP<<<200, 256, 0, stream>>>(A, 409600L, ts1, ts2);
  k3<<<dim3(32, 256), 256, 0, stream>>>(A, ts1, ts2, tgam, tbet, perm1, perm2,
                                        ikPf, frP, tlBP, tlb, Zd);
  k4<<<2048, 256, 0, stream>>>(Zd, ik2Pf, fr2P, Cb);
  k_statsP<<<100, 256, 0, stream>>>(Cb, 204800L, zs1, zs2);
  k5<<<dim3(16, 256), 256, 0, stream>>>(x, Cb, rwTP, scRP, shRP, zs1, zs2, t2g, t2b, perm2, out);
}

// Round 9
// 1203.141 us; speedup vs baseline: 1.5493x; 1.0819x over previous
//
#include <hip/hip_runtime.h>
#include <cstdint>
#include <cstddef>

namespace {
constexpr float EPS_ = 1e-5f;
}

using u16 = unsigned short;
typedef __attribute__((ext_vector_type(8))) short bf16x8;
typedef __attribute__((ext_vector_type(4))) float f32x4;

static __device__ __forceinline__ float bf2f(u16 u) {
  union { unsigned int i; float f; } x; x.i = ((unsigned int)u) << 16; return x.f;
}
static __device__ __forceinline__ u16 f2bf(float f) {
  union { float f; unsigned int i; } x; x.f = f;
  unsigned int r = x.i + 0x7fff + ((x.i >> 16) & 1);
  return (u16)(r >> 16);
}

#define OUT16(a, wv, xv) \
  a[0][0]=fmaf(wv.x,xv.x,a[0][0]); a[0][1]=fmaf(wv.x,xv.y,a[0][1]); \
  a[0][2]=fmaf(wv.x,xv.z,a[0][2]); a[0][3]=fmaf(wv.x,xv.w,a[0][3]); \
  a[1][0]=fmaf(wv.y,xv.x,a[1][0]); a[1][1]=fmaf(wv.y,xv.y,a[1][1]); \
  a[1][2]=fmaf(wv.y,xv.z,a[1][2]); a[1][3]=fmaf(wv.y,xv.w,a[1][3]); \
  a[2][0]=fmaf(wv.z,xv.x,a[2][0]); a[2][1]=fmaf(wv.z,xv.y,a[2][1]); \
  a[2][2]=fmaf(wv.z,xv.z,a[2][2]); a[2][3]=fmaf(wv.z,xv.w,a[2][3]); \
  a[3][0]=fmaf(wv.w,xv.x,a[3][0]); a[3][1]=fmaf(wv.w,xv.y,a[3][1]); \
  a[3][2]=fmaf(wv.w,xv.z,a[3][2]); a[3][3]=fmaf(wv.w,xv.w,a[3][3]);

// ---------- prep0: channel permutations sorted by floor(theta) ----------
__global__ __launch_bounds__(128) void k_prep0(
    const float* __restrict__ thin, const float* __restrict__ thout,
    int* __restrict__ perm1, int* __restrict__ perm2,
    float* __restrict__ ikPf, float* __restrict__ frP,
    float* __restrict__ ik2Pf, float* __restrict__ fr2P) {
  __shared__ float ikL[128], ik2L[128];
  const int c = threadIdx.x;
  float t1 = thin[c], t2 = thout[c];
  float f1 = floorf(t1), f2 = floorf(t2);
  ikL[c] = f1; ik2L[c] = f2;
  __syncthreads();
  int r1 = 0, r2 = 0;
  for (int j = 0; j < 128; j++) {
    r1 += (ikL[j] < f1) || (ikL[j] == f1 && j < c);
    r2 += (ik2L[j] < f2) || (ik2L[j] == f2 && j < c);
  }
  perm1[r1] = c; ikPf[r1] = f1; frP[r1] = t1 - f1;
  perm2[r2] = c; ik2Pf[r2] = f2; fr2P[r2] = t2 - f2;
}

// ---------- prep1: mask + permuted weight tables (bf16 op-major for MFMA B) ----------
__global__ __launch_bounds__(256) void k_prep1(
    const float* __restrict__ fm, const float* __restrict__ Wl,
    const float* __restrict__ dw, const float* __restrict__ rw, const float* __restrict__ tw,
    const int* __restrict__ perm1, const int* __restrict__ perm2,
    float* __restrict__ mskT, u16* __restrict__ WlB, u16* __restrict__ dwB,
    float* __restrict__ rwTP, u16* __restrict__ tlBP) {
  int i = blockIdx.x * 256 + threadIdx.x;
  if (i < 1600) { int c = i / 25, w = i % 25; mskT[c*25 + w] = tanhf(fm[w*64 + c]) + 1.0f; }
  if (i < 8192) {
    int dp = i >> 6, c = i & 63;
    int d = perm1[dp];
    WlB[i] = f2bf(Wl[c*128 + d]);
    dwB[i] = f2bf(dw[d*64 + c]);
    int c2 = i >> 7, op2 = i & 127;
    rwTP[i] = rw[perm2[op2]*64 + c2];
  }
  if (i < 16384) { int op = i >> 7, cp = i & 127; tlBP[i] = f2bf(tw[perm2[op]*128 + perm1[cp]]); }
}

// ---------- second moments of x: per-block partials, NO global atomics ----------
// reg double-buffer staging; xs[sample][channel] transposed layout.
__global__ __launch_bounds__(256) void k_mom(const float* __restrict__ x,
    float* __restrict__ part) {
  __shared__ float xs[100][68];
  const int n = blockIdx.x >> 2, quarter = blockIdx.x & 3, tid = threadIdx.x;
  const int ci = (tid >> 4) * 4, cj = (tid & 15) * 4;
  float ae[4][4], ao[4][4], se[4], so[4];
  #pragma unroll
  for (int i = 0; i < 4; i++) {
    se[i] = 0.f; so[i] = 0.f;
    #pragma unroll
    for (int j = 0; j < 4; j++) { ae[i][j] = 0.f; ao[i][j] = 0.f; }
  }
  const float* xb = x + (size_t)n * 102400;
  float4 pf[7];
  #pragma unroll
  for (int k = 0; k < 7; k++) {
    int e = tid + k*256;
    if (e < 1600) { int c = e/25, q = e - c*25;
      pf[k] = *(const float4*)&xb[(size_t)c*1600 + (quarter*16)*25 + q*4]; }
  }
  for (int it = 0; it < 4; it++) {
    #pragma unroll
    for (int k = 0; k < 7; k++) {
      int e = tid + k*256;
      if (e < 1600) {
        int c = e/25, q = e - c*25;
        xs[q*4+0][c] = pf[k].x; xs[q*4+1][c] = pf[k].y;
        xs[q*4+2][c] = pf[k].z; xs[q*4+3][c] = pf[k].w;
      }
    }
    __syncthreads();
    if (it < 3) {
      const int toff = quarter*16 + (it+1)*4;
      #pragma unroll
      for (int k = 0; k < 7; k++) {
        int e = tid + k*256;
        if (e < 1600) { int c = e/25, q = e - c*25;
          pf[k] = *(const float4*)&xb[(size_t)c*1600 + toff*25 + q*4]; }
      }
    }
    #pragma unroll
    for (int tl = 0; tl < 4; tl++) {
      #pragma unroll 5
      for (int vv = 0; vv < 25; vv++) {
        const int s = tl*25 + vv;
        const float4 ra = *(const float4*)&xs[s][ci];
        const float4 rb = *(const float4*)&xs[s][cj];
        if ((tl & 1) == 0) {
          OUT16(ae, ra, rb);
          if (cj == 0) { se[0] += ra.x; se[1] += ra.y; se[2] += ra.z; se[3] += ra.w; }
        } else {
          OUT16(ao, ra, rb);
          if (cj == 0) { so[0] += ra.x; so[1] += ra.y; so[2] += ra.z; so[3] += ra.w; }
        }
      }
    }
    __syncthreads();
  }
  float* pb = part + (size_t)blockIdx.x * 8320;
  #pragma unroll
  for (int i = 0; i < 4; i++) {
    #pragma unroll
    for (int j = 0; j < 4; j++) {
      pb[tid*16 + i*4 + j]        = ae[i][j] + ao[i][j];   // Sxa partial
      pb[4096 + tid*16 + i*4 + j] = ae[i][j];              // Sxe partial
    }
  }
  if (cj == 0) {
    #pragma unroll
    for (int i = 0; i < 4; i++) {
      pb[8192 + (tid>>4)*4 + i] = se[i] + so[i];
      pb[8256 + (tid>>4)*4 + i] = se[i];
    }
  }
}

// ---------- reduce k_mom partials ----------
__global__ __launch_bounds__(256) void k_red(const float* __restrict__ part,
    float* __restrict__ Sxa, float* __restrict__ Sxe,
    float* __restrict__ suma, float* __restrict__ sume) {
  const int f = blockIdx.x*256 + threadIdx.x;
  if (f >= 8320) return;
  const int b0 = blockIdx.y * 64;
  float s = 0.f;
  for (int b = b0; b < b0 + 64; b++) s += part[(size_t)b*8320 + f];
  if (f < 8192) {
    const int half = f >> 12;
    const int q = f & 4095;
    const int t0 = q >> 4, idx = q & 15;
    const int ci = (t0 >> 4)*4 + (idx >> 2);
    const int cj = (t0 & 15)*4 + (idx & 3);
    atomicAdd(half ? &Sxe[ci*64 + cj] : &Sxa[ci*64 + cj], s);
  } else if (f < 8256) {
    atomicAdd(&suma[f - 8192], s);
  } else {
    atomicAdd(&sume[f - 8256], s);
  }
}

// ---------- analytic bn scale/shift for down (perm1) & res (perm2) ----------
__global__ __launch_bounds__(256) void k_fin(
    const float* __restrict__ dw, const float* __restrict__ dbg, const float* __restrict__ dbb,
    const float* __restrict__ rw, const float* __restrict__ rbg, const float* __restrict__ rbb,
    const int* __restrict__ perm1, const int* __restrict__ perm2,
    const float* __restrict__ Sxa, const float* __restrict__ Sxe,
    const float* __restrict__ suma, const float* __restrict__ sume,
    float* __restrict__ scDP, float* __restrict__ shDP,
    float* __restrict__ scRP, float* __restrict__ shRP) {
  __shared__ float SA[4096], SE[4096], sa[64], seL[64];
  const int tid = threadIdx.x;
  for (int i = tid; i < 4096; i += 256) { SA[i] = Sxa[i]; SE[i] = Sxe[i]; }
  if (tid < 64) { sa[tid] = suma[tid]; seL[tid] = sume[tid]; }
  __syncthreads();
  const bool down = tid < 128;
  const int p = tid & 127;
  const int o = down ? perm1[p] : perm2[p];
  const float* w = down ? dw : rw;
  const float* SS = down ? SA : SE;
  const float* sv = down ? sa : seL;
  const float iS = down ? (1.f/409600.f) : (1.f/204800.f);
  float wr[64];
  #pragma unroll
  for (int c = 0; c < 64; c += 4) {
    float4 t = *(const float4*)&w[o*64 + c];
    wr[c] = t.x; wr[c+1] = t.y; wr[c+2] = t.z; wr[c+3] = t.w;
  }
  float mu = 0.f, q = 0.f;
  for (int c = 0; c < 64; c++) {
    mu = fmaf(wr[c], sv[c], mu);
    float pp = 0.f;
    #pragma unroll 8
    for (int c2 = 0; c2 < 64; c2++) pp = fmaf(SS[c*64 + c2], wr[c2], pp);
    q = fmaf(wr[c], pp, q);
  }
  mu *= iS; q *= iS;
  float var = fmaxf(q - mu*mu, 0.f);
  float g = down ? dbg[o] : rbg[o];
  float b = down ? dbb[o] : rbb[o];
  float sc = g * rsqrtf(var + EPS_);
  if (down) { scDP[p] = sc; shDP[p] = b - mu*sc; }
  else      { scRP[p] = sc; shRP[p] = b - mu*sc; }
}

// ---------- K1 (MFMA): GCN GEMM (mask+shift in, vertex shuffle out) -> A[n][t][v][dp] bf16 ----------
__global__ __launch_bounds__(256) void k1(
    const float* __restrict__ x, const u16* __restrict__ WlB,
    const float* __restrict__ mskT, const int* __restrict__ perm1,
    u16* __restrict__ A) {
  __shared__ __align__(16) u16 xmT[64][72];
  __shared__ __align__(16) u16 ys[50][136];
  __shared__ int dmL[128];
  const int tg = blockIdx.x, n = blockIdx.y, tid = threadIdx.x;
  const int t2 = tg * 2;
  if (tid < 128) dmL[tid] = perm1[tid] % 25;
  const float* xb = x + (size_t)n * 102400;
  for (int e = tid; e < 3200; e += 256) {
    int tl = e / 1600, r = e - tl*1600, c = r / 25, w_ = r - c*25;
    int cm = c; if (cm >= 50) cm -= 50; else if (cm >= 25) cm -= 25;
    int vs = w_ + cm; if (vs >= 25) vs -= 25;
    xmT[tl*25 + w_][c] = f2bf(xb[(size_t)c*1600 + (t2+tl)*25 + vs] * mskT[c*25 + w_]);
  }
  __syncthreads();
  const int w = tid >> 6, l = tid & 63;
  const int lc = l & 15, kg = l >> 4;
  f32x4 acc[8];
  #pragma unroll
  for (int nt = 0; nt < 8; nt++) { acc[nt][0]=0.f; acc[nt][1]=0.f; acc[nt][2]=0.f; acc[nt][3]=0.f; }
  #pragma unroll
  for (int ks = 0; ks < 2; ks++) {
    const bf16x8 a = *(const bf16x8*)&xmT[w*16 + lc][ks*32 + kg*8];
    #pragma unroll
    for (int nt = 0; nt < 8; nt++) {
      const bf16x8 b = *(const bf16x8*)&WlB[(size_t)(nt*16 + lc)*64 + ks*32 + kg*8];
      acc[nt] = __builtin_amdgcn_mfma_f32_16x16x32_bf16(a, b, acc[nt], 0, 0, 0);
    }
  }
  #pragma unroll
  for (int nt = 0; nt < 8; nt++) {
    const int dp = nt*16 + lc;
    const int dm = dmL[dp];
    #pragma unroll
    for (int r = 0; r < 4; r++) {
      const int s = w*16 + kg*4 + r;
      if (s < 50) {
        int tl = 0, wv = s; if (wv >= 25) { tl = 1; wv -= 25; }
        int v = wv + dm; if (v >= 25) v -= 25;
        ys[tl*25 + v][dp] = f2bf(acc[nt][r]);
      }
    }
  }
  __syncthreads();
  u16* Aslab = A + (size_t)n*204800 + (size_t)t2*3200;
  for (int i = tid; i < 800; i += 256) {
    int s = i >> 4, ch = i & 15;
    *(int4*)(Aslab + s*128 + ch*8) = *(const int4*)&ys[s][ch*8];
  }
}

// ---------- stats over 3200 features (v,dp) of A ----------
__global__ __launch_bounds__(256) void k_statsA(const u16* __restrict__ A,
    float* __restrict__ gs1, float* __restrict__ gs2) {
  const int foct = blockIdx.x*256 + threadIdx.x;
  if (foct >= 400) return;
  const int rb = blockIdx.y * 512;
  const size_t f0 = (size_t)foct * 8;
  float s1[8], s2[8];
  #pragma unroll
  for (int i = 0; i < 8; i++) { s1[i] = 0.f; s2[i] = 0.f; }
  for (int r = 0; r < 512; r++) {
    union { int4 i4; u16 u[8]; } raw;
    raw.i4 = *(const int4*)(A + (size_t)(rb + r)*3200 + f0);
    #pragma unroll
    for (int i = 0; i < 8; i++) { float v = bf2f(raw.u[i]); s1[i] += v; s2[i] = fmaf(v, v, s2[i]); }
  }
  #pragma unroll
  for (int i = 0; i < 8; i++) { atomicAdd(&gs1[f0+i], s1[i]); atomicAdd(&gs2[f0+i], s2[i]); }
}

// ---------- finalize gcn bn scale/shift per (v,dp) ----------
__global__ __launch_bounds__(256) void k_fin2(
    const float* __restrict__ gs1, const float* __restrict__ gs2,
    const float* __restrict__ gg, const float* __restrict__ gb,
    const int* __restrict__ perm1,
    float* __restrict__ scG, float* __restrict__ shG) {
  int f = blockIdx.x*256 + threadIdx.x;
  if (f >= 3200) return;
  int v = f >> 7, dp = f & 127;
  int d = perm1[dp];
  float m = gs1[f] * (1.f/16384.f);
  float var = fmaxf(gs2[f]*(1.f/16384.f) - m*m, 0.f);
  float r = rsqrtf(var + EPS_);
  float sc = gg[v*128 + d] * r;
  scG[f] = sc; shG[f] = gb[v*128 + d] - m*sc;
}

// ---------- K2 (MFMA): down GEMM + y = relu(bn1d(h)+bn(down)), A in place ----------
__global__ __launch_bounds__(256) void k2(
    const float* __restrict__ x, const u16* __restrict__ dwB,
    const float* __restrict__ scG, const float* __restrict__ shG,
    const float* __restrict__ scDP, const float* __restrict__ shDP,
    u16* __restrict__ A) {
  __shared__ __align__(16) u16 xsT[64][72];
  __shared__ __align__(16) u16 ah[6400];
  __shared__ __align__(16) u16 ys[50][136];
  const int tg = blockIdx.x, n = blockIdx.y, tid = threadIdx.x;
  const int t2 = tg * 2;
  const float* xb = x + (size_t)n * 102400;
  u16* Aslab = A + (size_t)n*204800 + (size_t)t2*3200;
  {
    int4* dst = (int4*)ah;
    const int4* src = (const int4*)Aslab;
    for (int i = tid; i < 800; i += 256) dst[i] = src[i];
  }
  for (int e = tid; e < 3200; e += 256) {
    int tl = e / 1600, r = e - tl*1600, c = r / 25, v = r - c*25;
    xsT[tl*25 + v][c] = f2bf(xb[(size_t)c*1600 + (t2+tl)*25 + v]);
  }
  __syncthreads();
  const int w = tid >> 6, l = tid & 63;
  const int lc = l & 15, kg = l >> 4;
  f32x4 acc[8];
  #pragma unroll
  for (int nt = 0; nt < 8; nt++) { acc[nt][0]=0.f; acc[nt][1]=0.f; acc[nt][2]=0.f; acc[nt][3]=0.f; }
  #pragma unroll
  for (int ks = 0; ks < 2; ks++) {
    const bf16x8 a = *(const bf16x8*)&xsT[w*16 + lc][ks*32 + kg*8];
    #pragma unroll
    for (int nt = 0; nt < 8; nt++) {
      const bf16x8 b = *(const bf16x8*)&dwB[(size_t)(nt*16 + lc)*64 + ks*32 + kg*8];
      acc[nt] = __builtin_amdgcn_mfma_f32_16x16x32_bf16(a, b, acc[nt], 0, 0, 0);
    }
  }
  #pragma unroll
  for (int nt = 0; nt < 8; nt++) {
    const int dp = nt*16 + lc;
    const float sD = scDP[dp], hD = shDP[dp];
    #pragma unroll
    for (int r = 0; r < 4; r++) {
      const int s = w*16 + kg*4 + r;
      if (s < 50) {
        int v = s; if (v >= 25) v -= 25;
        int f = v*128 + dp;
        float hb = fmaf(bf2f(ah[s*128 + dp]), scG[f], shG[f]);
        float dd = fmaf(acc[nt][r], sD, hD);
        ys[s][dp] = f2bf(fmaxf(hb + dd, 0.f));
      }
    }
  }
  __syncthreads();
  for (int i = tid; i < 800; i += 256) {
    int s = i >> 4, ch = i & 15;
    *(int4*)(Aslab + s*128 + ch*8) = *(const int4*)&ys[s][ch*8];
  }
}

// ---------- per-128-channel stats (channel-last rows) ----------
__global__ __launch_bounds__(256) void k_statsP(const u16* __restrict__ P, long nrows,
    float* __restrict__ s1g, float* __restrict__ s2g) {
  const int tid = threadIdx.x;
  const int f0 = (tid & 15) * 8;
  const int rg = tid >> 4;
  long rpb = nrows / gridDim.x;
  long rb = (long)blockIdx.x * rpb;
  float s1[8], s2[8];
  #pragma unroll
  for (int i = 0; i < 8; i++) { s1[i] = 0.f; s2[i] = 0.f; }
  for (long r = rg; r < rpb; r += 16) {
    union { int4 i4; u16 u[8]; } raw;
    raw.i4 = *(const int4*)(P + (rb + r)*128 + f0);
    #pragma unroll
    for (int i = 0; i < 8; i++) { float v = bf2f(raw.u[i]); s1[i] += v; s2[i] = fmaf(v, v, s2[i]); }
  }
  __shared__ float m1[16][128], m2[16][128];
  #pragma unroll
  for (int i = 0; i < 8; i++) { m1[rg][f0+i] = s1[i]; m2[rg][f0+i] = s2[i]; }
  __syncthreads();
  if (tid < 128) {
    float a = 0.f, b = 0.f;
    #pragma unroll
    for (int g = 0; g < 16; g++) { a += m1[g][tid]; b += m2[g][tid]; }
    atomicAdd(&s1g[tid], a); atomicAdd(&s2g[tid], b);
  }
}

// ---------- K3 (MFMA): bn(y)+shift(theta_in,1)+tl GEMM+bias+relu -> Z bf16 (d_out) ----------
__global__ __launch_bounds__(256) void k3(
    const u16* __restrict__ Y,
    const float* __restrict__ ts1, const float* __restrict__ ts2,
    const float* __restrict__ tgamma, const float* __restrict__ tbeta,
    const int* __restrict__ perm1, const int* __restrict__ perm2,
    const float* __restrict__ ikPf, const float* __restrict__ frP,
    const u16* __restrict__ tlBP, const float* __restrict__ tlb,
    u16* __restrict__ Z) {
  __shared__ __align__(16) u16 zslT[64][136];
  __shared__ __align__(16) u16 ys[50][136];
  __shared__ float scL[128], shL[128], frL[128], tlbL[128];
  __shared__ int ikL[128];
  const int tg = blockIdx.x, n = blockIdx.y, tid = threadIdx.x;
  const int t2 = tg * 2;
  if (tid < 128) {
    int cp = tid, c = perm1[cp];
    float m = ts1[cp] * (1.f/409600.f);
    float var = fmaxf(ts2[cp]*(1.f/409600.f) - m*m, 0.f);
    float r = rsqrtf(var + EPS_);
    float sc = tgamma[c] * r;
    scL[cp] = sc; shL[cp] = tbeta[c] - m*sc;
    ikL[cp] = (int)ikPf[cp]; frL[cp] = frP[cp];
    tlbL[cp] = tlb[perm2[cp]];
  }
  __syncthreads();
  const u16* Yb = Y + (size_t)n * 204800;
  for (int e = tid; e < 6400; e += 256) {
    int cp = e & 127, v = (e >> 7) % 25, tl = e / 3200;
    int t0 = t2 + tl + ikL[cp];
    float fr = frL[cp], sc = scL[cp], sh = shL[cp];
    float a0 = (t0 >= 0 && t0 < 64) ? fmaf(bf2f(Yb[(size_t)t0*3200 + v*128 + cp]), sc, sh) : 0.f;
    int t1 = t0 + 1;
    float a1 = (t1 >= 0 && t1 < 64) ? fmaf(bf2f(Yb[(size_t)t1*3200 + v*128 + cp]), sc, sh) : 0.f;
    zslT[tl*25 + v][cp] = f2bf((1.f - fr)*a0 + fr*a1);
  }
  __syncthreads();
  const int w = tid >> 6, l = tid & 63;
  const int lc = l & 15, kg = l >> 4;
  f32x4 acc[8];
  #pragma unroll
  for (int nt = 0; nt < 8; nt++) {
    float bb = tlbL[nt*16 + lc];
    acc[nt][0] = bb; acc[nt][1] = bb; acc[nt][2] = bb; acc[nt][3] = bb;
  }
  #pragma unroll
  for (int ks = 0; ks < 4; ks++) {
    const bf16x8 a = *(const bf16x8*)&zslT[w*16 + lc][ks*32 + kg*8];
    #pragma unroll
    for (int nt = 0; nt < 8; nt++) {
      const bf16x8 b = *(const bf16x8*)&tlBP[(size_t)(nt*16 + lc)*128 + ks*32 + kg*8];
      acc[nt] = __builtin_amdgcn_mfma_f32_16x16x32_bf16(a, b, acc[nt], 0, 0, 0);
    }
  }
  #pragma unroll
  for (int nt = 0; nt < 8; nt++) {
    const int op = nt*16 + lc;
    #pragma unroll
    for (int r = 0; r < 4; r++) {
      const int s = w*16 + kg*4 + r;
      if (s < 50) ys[s][op] = f2bf(fmaxf(acc[nt][r], 0.f));
    }
  }
  __syncthreads();
  u16* Zb = Z + (size_t)n*204800 + (size_t)t2*3200;
  for (int i = tid; i < 800; i += 256) {
    int s = i >> 4, ch = i & 15;
    *(int4*)(Zb + s*128 + ch*8) = *(const int4*)&ys[s][ch*8];
  }
}

// ---------- K4: stride-2 shift(theta_out) Z -> C[n][tp][v][op] bf16 ----------
__global__ __launch_bounds__(256) void k4(const u16* __restrict__ Z,
    const float* __restrict__ ik2Pf, const float* __restrict__ fr2P,
    u16* __restrict__ C) {
  __shared__ int ikL[128];
  __shared__ float frL[128];
  if (threadIdx.x < 128) { ikL[threadIdx.x] = (int)ik2Pf[threadIdx.x]; frL[threadIdx.x] = fr2P[threadIdx.x]; }
  __syncthreads();
  for (size_t idx = (size_t)blockIdx.x*256 + threadIdx.x; idx < 26214400ull; idx += (size_t)gridDim.x*256) {
    int op = (int)(idx & 127);
    int v  = (int)((idx >> 7) % 25);
    int tp = (int)((idx / 3200) & 31);
    int n  = (int)(idx / 102400);
    int t0 = 2*tp + ikL[op];
    float fr = frL[op];
    const u16* base = Z + (size_t)n*204800 + v*128 + op;
    float a0 = (t0 >= 0 && t0 < 64) ? bf2f(base[(size_t)t0*3200]) : 0.f;
    int t1 = t0 + 1;
    float a1 = (t1 >= 0 && t1 < 64) ? bf2f(base[(size_t)t1*3200]) : 0.f;
    C[idx] = f2bf((1.f - fr)*a0 + fr*a1);
  }
}

// ---------- K5: res GEMM + out = relu(bn2(C)+bn(res)) -> NCHW fp32 ----------
__global__ __launch_bounds__(256) void k5(
    const float* __restrict__ x, const u16* __restrict__ C,
    const float* __restrict__ rwTP,
    const float* __restrict__ scRP, const float* __restrict__ shRP,
    const float* __restrict__ zs1, const float* __restrict__ zs2,
    const float* __restrict__ t2g, const float* __restrict__ t2b,
    const int* __restrict__ perm2, float* __restrict__ out) {
  __shared__ float xs[2][64][28];
  __shared__ u16 ch[6400];
  __shared__ float sc2L[128], sh2L[128];
  __shared__ int p2L[128];
  const int tpg = blockIdx.x, n = blockIdx.y, tid = threadIdx.x;
  const int tp2 = tpg * 2;
  if (tid < 128) {
    int op = tid, o = perm2[op];
    float m = zs1[op] * (1.f/204800.f);
    float var = fmaxf(zs2[op]*(1.f/204800.f) - m*m, 0.f);
    float r = rsqrtf(var + EPS_);
    float sc = t2g[o] * r;
    sc2L[op] = sc; sh2L[op] = t2b[o] - m*sc;
    p2L[op] = o;
  }
  for (int e = tid; e < 384; e += 256) { int q = e / 3; xs[q>>6][q&63][25 + e%3] = 0.f; }
  const float* xb = x + (size_t)n * 102400;
  for (int e = tid; e < 3200; e += 256) {
    int tl = e / 1600, r = e - tl*1600, c = r / 25, v = r - c*25;
    xs[tl][c][v] = xb[(size_t)c*1600 + 2*(tp2+tl)*25 + v];
  }
  {
    int4* dst = (int4*)ch;
    const int4* src = (const int4*)(C + (size_t)n*102400 + (size_t)tp2*3200);
    for (int i = tid; i < 800; i += 256) dst[i] = src[i];
  }
  __syncthreads();
  const int l = tid & 31, vq = tid >> 5;
  const int o0 = l * 4, v0 = vq * 4;
  if (vq < 7) {
    float acc[2][4][4];
    #pragma unroll
    for (int tl = 0; tl < 2; tl++)
      #pragma unroll
      for (int j = 0; j < 4; j++)
        #pragma unroll
        for (int k = 0; k < 4; k++) acc[tl][j][k] = 0.f;
    for (int c = 0; c < 64; c++) {
      const float4 wv = *(const float4*)&rwTP[c*128 + o0];
      #pragma unroll
      for (int tl = 0; tl < 2; tl++) {
        const float4 xv = *(const float4*)&xs[tl][c][v0];
        OUT16(acc[tl], wv, xv);
      }
    }
    const float4 scr = *(const float4*)&scRP[o0];
    const float4 shr = *(const float4*)&shRP[o0];
    #pragma unroll
    for (int tl = 0; tl < 2; tl++) {
      #pragma unroll
      for (int k = 0; k < 4; k++) {
        int v = v0 + k;
        if (v < 25) {
          union { ushort4 s4; u16 u[4]; } cv;
          cv.s4 = *(const ushort4*)&ch[(tl*25 + v)*128 + o0];
          #pragma unroll
          for (int j = 0; j < 4; j++) {
            float zv = fmaf(bf2f(cv.u[j]), sc2L[o0+j], sh2L[o0+j]);
            float rv = fmaf(acc[tl][j][k], ((const float*)&scr)[j], ((const float*)&shr)[j]);
            out[((size_t)(n*128 + p2L[o0+j])*32 + tp2 + tl)*25 + v] = fmaxf(zv + rv, 0.f);
          }
        }
      }
    }
  }
}

extern "C" void kernel_launch(void* const* d_in, const int* in_sizes, int n_in,
                              void* d_out, int out_size, void* d_ws, size_t ws_size,
                              hipStream_t stream) {
  (void)in_sizes; (void)n_in; (void)out_size;
  if (ws_size < 105200000ull) return;  // clean fail instead of OOB crash
  const float* x     = (const float*)d_in[0];
  const float* Wl    = (const float*)d_in[1];
  const float* fm    = (const float*)d_in[3];
  const float* gg    = (const float*)d_in[4];
  const float* gb    = (const float*)d_in[5];
  const float* dw    = (const float*)d_in[6];
  const float* dbg   = (const float*)d_in[8];
  const float* dbb   = (const float*)d_in[9];
  const float* tgam  = (const float*)d_in[10];
  const float* tbet  = (const float*)d_in[11];
  const float* thin  = (const float*)d_in[12];
  const float* tw    = (const float*)d_in[13];
  const float* tlb   = (const float*)d_in[14];
  const float* thout = (const float*)d_in[15];
  const float* t2g   = (const float*)d_in[16];
  const float* t2b   = (const float*)d_in[17];
  const float* rw    = (const float*)d_in[18];
  const float* rbg   = (const float*)d_in[20];
  const float* rbb   = (const float*)d_in[21];
  float* out = (float*)d_out;
  u16* Zd = (u16*)d_out;            // Z bf16 lives in d_out until k5 overwrites

  u16* A  = (u16*)d_ws;             // [256][64][25][128] bf16 = 104,857,600 B
  u16* Cb = A;                      // C aliases A (A dead after k3)
  float* part = (float*)d_ws;       // k_mom partials (34 MB) — dead before k1 writes A
  float* mskT = (float*)((char*)d_ws + 104857600);   // 1600 f
  u16*  WlB   = (u16*)(mskT + 1600);                 // 8192 u16
  u16*  dwB   = WlB + 8192;                          // 8192 u16
  float* rwTP = (float*)(dwB + 8192);                // 8192 f
  u16*  tlBP  = (u16*)(rwTP + 8192);                 // 16384 u16
  float* scG  = (float*)(tlBP + 16384);              // 3200
  float* shG  = scG + 3200;         // 3200
  float* scDP = shG + 3200;         // 128
  float* shDP = scDP + 128;
  float* scRP = shDP + 128;
  float* shRP = scRP + 128;
  float* ikPf = shRP + 128;
  float* frP  = ikPf + 128;
  float* ik2Pf= frP + 128;
  float* fr2P = ik2Pf + 128;
  float* Sxa  = fr2P + 128;         // zero region start (15232 floats)
  float* Sxe  = Sxa + 4096;
  float* suma = Sxe + 4096;
  float* sume = suma + 64;
  float* gs1  = sume + 64;
  float* gs2  = gs1 + 3200;
  float* ts1  = gs2 + 3200;
  float* ts2  = ts1 + 128;
  float* zs1  = ts2 + 128;
  float* zs2  = zs1 + 128;
  int* perm1  = (int*)(zs2 + 128);
  int* perm2  = perm1 + 128;

  (void)hipMemsetAsync(Sxa, 0, 15232 * sizeof(float), stream);
  k_prep0<<<1, 128, 0, stream>>>(thin, thout, perm1, perm2, ikPf, frP, ik2Pf, fr2P);
  k_prep1<<<64, 256, 0, stream>>>(fm, Wl, dw, rw, tw, perm1, perm2, mskT, WlB, dwB, rwTP, tlBP);
  k_mom<<<1024, 256, 0, stream>>>(x, part);
  k_red<<<dim3(33, 16), 256, 0, stream>>>(part, Sxa, Sxe, suma, sume);
  k_fin<<<1, 256, 0, stream>>>(dw, dbg, dbb, rw, rbg, rbb, perm1, perm2,
                               Sxa, Sxe, suma, sume, scDP, shDP, scRP, shRP);
  k1<<<dim3(32, 256), 256, 0, stream>>>(x, WlB, mskT, perm1, A);
  k_statsA<<<dim3(2, 32), 256, 0, stream>>>(A, gs1, gs2);
  k_fin2<<<13, 256, 0, stream>>>(gs1, gs2, gg, gb, perm1, scG, shG);
  k2<<<dim3(32, 256), 256, 0, stream>>>(x, dwB, scG, shG, scDP, shDP, A);
  k_statsP<<<200, 256, 0, stream>>>(A, 409600L, ts1, ts2);
  k3<<<dim3(32, 256), 256, 0, stream>>>(A, ts1, ts2, tgam, tbet, perm1, perm2,
                                        ikPf, frP, tlBP, tlb, Zd);
  k4<<<2048, 256, 0, stream>>>(Zd, ik2Pf, fr2P, Cb);
  k_statsP<<<100, 256, 0, stream>>>(Cb, 204800L, zs1, zs2);
  k5<<<dim3(16, 256), 256, 0, stream>>>(x, Cb, rwTP, scRP, shRP, zs1, zs2, t2g, t2b, perm2, out);
}

// Round 10
// 984.253 us; speedup vs baseline: 1.8938x; 1.2224x over previous
//
#include <hip/hip_runtime.h>
#include <cstdint>
#include <cstddef>

namespace {
constexpr float EPS_ = 1e-5f;
}

using u16 = unsigned short;
typedef __attribute__((ext_vector_type(8))) short bf16x8;
typedef __attribute__((ext_vector_type(4))) float f32x4;

static __device__ __forceinline__ float bf2f(u16 u) {
  union { unsigned int i; float f; } x; x.i = ((unsigned int)u) << 16; return x.f;
}
static __device__ __forceinline__ u16 f2bf(float f) {
  union { float f; unsigned int i; } x; x.f = f;
  unsigned int r = x.i + 0x7fff + ((x.i >> 16) & 1);
  return (u16)(r >> 16);
}

#define OUT16(a, wv, xv) \
  a[0][0]=fmaf(wv.x,xv.x,a[0][0]); a[0][1]=fmaf(wv.x,xv.y,a[0][1]); \
  a[0][2]=fmaf(wv.x,xv.z,a[0][2]); a[0][3]=fmaf(wv.x,xv.w,a[0][3]); \
  a[1][0]=fmaf(wv.y,xv.x,a[1][0]); a[1][1]=fmaf(wv.y,xv.y,a[1][1]); \
  a[1][2]=fmaf(wv.y,xv.z,a[1][2]); a[1][3]=fmaf(wv.y,xv.w,a[1][3]); \
  a[2][0]=fmaf(wv.z,xv.x,a[2][0]); a[2][1]=fmaf(wv.z,xv.y,a[2][1]); \
  a[2][2]=fmaf(wv.z,xv.z,a[2][2]); a[2][3]=fmaf(wv.z,xv.w,a[2][3]); \
  a[3][0]=fmaf(wv.w,xv.x,a[3][0]); a[3][1]=fmaf(wv.w,xv.y,a[3][1]); \
  a[3][2]=fmaf(wv.w,xv.z,a[3][2]); a[3][3]=fmaf(wv.w,xv.w,a[3][3]);

// ---------- prep0: channel permutations sorted by floor(theta) ----------
__global__ __launch_bounds__(128) void k_prep0(
    const float* __restrict__ thin, const float* __restrict__ thout,
    int* __restrict__ perm1, int* __restrict__ perm2,
    float* __restrict__ ikPf, float* __restrict__ frP,
    float* __restrict__ ik2Pf, float* __restrict__ fr2P) {
  __shared__ float ikL[128], ik2L[128];
  const int c = threadIdx.x;
  float t1 = thin[c], t2 = thout[c];
  float f1 = floorf(t1), f2 = floorf(t2);
  ikL[c] = f1; ik2L[c] = f2;
  __syncthreads();
  int r1 = 0, r2 = 0;
  for (int j = 0; j < 128; j++) {
    r1 += (ikL[j] < f1) || (ikL[j] == f1 && j < c);
    r2 += (ik2L[j] < f2) || (ik2L[j] == f2 && j < c);
  }
  perm1[r1] = c; ikPf[r1] = f1; frP[r1] = t1 - f1;
  perm2[r2] = c; ik2Pf[r2] = f2; fr2P[r2] = t2 - f2;
}

// ---------- prep1: mask + permuted weight tables (bf16 op-major for MFMA B) ----------
__global__ __launch_bounds__(256) void k_prep1(
    const float* __restrict__ fm, const float* __restrict__ Wl,
    const float* __restrict__ dw, const float* __restrict__ rw, const float* __restrict__ tw,
    const int* __restrict__ perm1, const int* __restrict__ perm2,
    float* __restrict__ mskT, u16* __restrict__ WlB, u16* __restrict__ dwB,
    float* __restrict__ rwTP, u16* __restrict__ tlBP) {
  int i = blockIdx.x * 256 + threadIdx.x;
  if (i < 1600) { int c = i / 25, w = i % 25; mskT[c*25 + w] = tanhf(fm[w*64 + c]) + 1.0f; }
  if (i < 8192) {
    int dp = i >> 6, c = i & 63;
    int d = perm1[dp];
    WlB[i] = f2bf(Wl[c*128 + d]);
    dwB[i] = f2bf(dw[d*64 + c]);
    int c2 = i >> 7, op2 = i & 127;
    rwTP[i] = rw[perm2[op2]*64 + c2];
  }
  if (i < 16384) { int op = i >> 7, cp = i & 127; tlBP[i] = f2bf(tw[perm2[op]*128 + perm1[cp]]); }
}

// ---------- second moments of x: per-block partials, NO global atomics ----------
__global__ __launch_bounds__(256) void k_mom(const float* __restrict__ x,
    float* __restrict__ part) {
  __shared__ float xs[100][68];
  const int n = blockIdx.x >> 2, quarter = blockIdx.x & 3, tid = threadIdx.x;
  const int ci = (tid >> 4) * 4, cj = (tid & 15) * 4;
  float ae[4][4], ao[4][4], se[4], so[4];
  #pragma unroll
  for (int i = 0; i < 4; i++) {
    se[i] = 0.f; so[i] = 0.f;
    #pragma unroll
    for (int j = 0; j < 4; j++) { ae[i][j] = 0.f; ao[i][j] = 0.f; }
  }
  const float* xb = x + (size_t)n * 102400;
  float4 pf[7];
  #pragma unroll
  for (int k = 0; k < 7; k++) {
    int e = tid + k*256;
    if (e < 1600) { int c = e/25, q = e - c*25;
      pf[k] = *(const float4*)&xb[(size_t)c*1600 + (quarter*16)*25 + q*4]; }
  }
  for (int it = 0; it < 4; it++) {
    #pragma unroll
    for (int k = 0; k < 7; k++) {
      int e = tid + k*256;
      if (e < 1600) {
        int c = e/25, q = e - c*25;
        xs[q*4+0][c] = pf[k].x; xs[q*4+1][c] = pf[k].y;
        xs[q*4+2][c] = pf[k].z; xs[q*4+3][c] = pf[k].w;
      }
    }
    __syncthreads();
    if (it < 3) {
      const int toff = quarter*16 + (it+1)*4;
      #pragma unroll
      for (int k = 0; k < 7; k++) {
        int e = tid + k*256;
        if (e < 1600) { int c = e/25, q = e - c*25;
          pf[k] = *(const float4*)&xb[(size_t)c*1600 + toff*25 + q*4]; }
      }
    }
    #pragma unroll
    for (int tl = 0; tl < 4; tl++) {
      #pragma unroll 5
      for (int vv = 0; vv < 25; vv++) {
        const int s = tl*25 + vv;
        const float4 ra = *(const float4*)&xs[s][ci];
        const float4 rb = *(const float4*)&xs[s][cj];
        if ((tl & 1) == 0) {
          OUT16(ae, ra, rb);
          if (cj == 0) { se[0] += ra.x; se[1] += ra.y; se[2] += ra.z; se[3] += ra.w; }
        } else {
          OUT16(ao, ra, rb);
          if (cj == 0) { so[0] += ra.x; so[1] += ra.y; so[2] += ra.z; so[3] += ra.w; }
        }
      }
    }
    __syncthreads();
  }
  float* pb = part + (size_t)blockIdx.x * 8320;
  #pragma unroll
  for (int i = 0; i < 4; i++) {
    #pragma unroll
    for (int j = 0; j < 4; j++) {
      pb[tid*16 + i*4 + j]        = ae[i][j] + ao[i][j];   // Sxa partial
      pb[4096 + tid*16 + i*4 + j] = ae[i][j];              // Sxe partial
    }
  }
  if (cj == 0) {
    #pragma unroll
    for (int i = 0; i < 4; i++) {
      pb[8192 + (tid>>4)*4 + i] = se[i] + so[i];
      pb[8256 + (tid>>4)*4 + i] = se[i];
    }
  }
}

// ---------- reduce k_mom partials ----------
__global__ __launch_bounds__(256) void k_red(const float* __restrict__ part,
    float* __restrict__ Sxa, float* __restrict__ Sxe,
    float* __restrict__ suma, float* __restrict__ sume) {
  const int f = blockIdx.x*256 + threadIdx.x;
  if (f >= 8320) return;
  const int b0 = blockIdx.y * 64;
  float s = 0.f;
  for (int b = b0; b < b0 + 64; b++) s += part[(size_t)b*8320 + f];
  if (f < 8192) {
    const int half = f >> 12;
    const int q = f & 4095;
    const int t0 = q >> 4, idx = q & 15;
    const int ci = (t0 >> 4)*4 + (idx >> 2);
    const int cj = (t0 & 15)*4 + (idx & 3);
    atomicAdd(half ? &Sxe[ci*64 + cj] : &Sxa[ci*64 + cj], s);
  } else if (f < 8256) {
    atomicAdd(&suma[f - 8192], s);
  } else {
    atomicAdd(&sume[f - 8256], s);
  }
}

// ---------- analytic bn scale/shift for down (perm1) & res (perm2) ----------
__global__ __launch_bounds__(256) void k_fin(
    const float* __restrict__ dw, const float* __restrict__ dbg, const float* __restrict__ dbb,
    const float* __restrict__ rw, const float* __restrict__ rbg, const float* __restrict__ rbb,
    const int* __restrict__ perm1, const int* __restrict__ perm2,
    const float* __restrict__ Sxa, const float* __restrict__ Sxe,
    const float* __restrict__ suma, const float* __restrict__ sume,
    float* __restrict__ scDP, float* __restrict__ shDP,
    float* __restrict__ scRP, float* __restrict__ shRP) {
  __shared__ float SA[4096], SE[4096], sa[64], seL[64];
  const int tid = threadIdx.x;
  for (int i = tid; i < 4096; i += 256) { SA[i] = Sxa[i]; SE[i] = Sxe[i]; }
  if (tid < 64) { sa[tid] = suma[tid]; seL[tid] = sume[tid]; }
  __syncthreads();
  const bool down = tid < 128;
  const int p = tid & 127;
  const int o = down ? perm1[p] : perm2[p];
  const float* w = down ? dw : rw;
  const float* SS = down ? SA : SE;
  const float* sv = down ? sa : seL;
  const float iS = down ? (1.f/409600.f) : (1.f/204800.f);
  float wr[64];
  #pragma unroll
  for (int c = 0; c < 64; c += 4) {
    float4 t = *(const float4*)&w[o*64 + c];
    wr[c] = t.x; wr[c+1] = t.y; wr[c+2] = t.z; wr[c+3] = t.w;
  }
  float mu = 0.f, q = 0.f;
  for (int c = 0; c < 64; c++) {
    mu = fmaf(wr[c], sv[c], mu);
    float pp = 0.f;
    #pragma unroll 8
    for (int c2 = 0; c2 < 64; c2++) pp = fmaf(SS[c*64 + c2], wr[c2], pp);
    q = fmaf(wr[c], pp, q);
  }
  mu *= iS; q *= iS;
  float var = fmaxf(q - mu*mu, 0.f);
  float g = down ? dbg[o] : rbg[o];
  float b = down ? dbb[o] : rbb[o];
  float sc = g * rsqrtf(var + EPS_);
  if (down) { scDP[p] = sc; shDP[p] = b - mu*sc; }
  else      { scRP[p] = sc; shRP[p] = b - mu*sc; }
}

// ---------- K1 (MFMA): GCN GEMM (mask+shift in, vertex shuffle out) -> A[n][t][v][dp] bf16 ----------
__global__ __launch_bounds__(256) void k1(
    const float* __restrict__ x, const u16* __restrict__ WlB,
    const float* __restrict__ mskT, const int* __restrict__ perm1,
    u16* __restrict__ A) {
  __shared__ __align__(16) u16 xmT[64][72];
  __shared__ __align__(16) u16 ys[50][136];
  __shared__ int dmL[128];
  const int tg = blockIdx.x, n = blockIdx.y, tid = threadIdx.x;
  const int t2 = tg * 2;
  if (tid < 128) dmL[tid] = perm1[tid] % 25;
  const float* xb = x + (size_t)n * 102400;
  for (int e = tid; e < 3200; e += 256) {
    int tl = e / 1600, r = e - tl*1600, c = r / 25, w_ = r - c*25;
    int cm = c; if (cm >= 50) cm -= 50; else if (cm >= 25) cm -= 25;
    int vs = w_ + cm; if (vs >= 25) vs -= 25;
    xmT[tl*25 + w_][c] = f2bf(xb[(size_t)c*1600 + (t2+tl)*25 + vs] * mskT[c*25 + w_]);
  }
  __syncthreads();
  const int w = tid >> 6, l = tid & 63;
  const int lc = l & 15, kg = l >> 4;
  f32x4 acc[8];
  #pragma unroll
  for (int nt = 0; nt < 8; nt++) { acc[nt][0]=0.f; acc[nt][1]=0.f; acc[nt][2]=0.f; acc[nt][3]=0.f; }
  #pragma unroll
  for (int ks = 0; ks < 2; ks++) {
    const bf16x8 a = *(const bf16x8*)&xmT[w*16 + lc][ks*32 + kg*8];
    #pragma unroll
    for (int nt = 0; nt < 8; nt++) {
      const bf16x8 b = *(const bf16x8*)&WlB[(size_t)(nt*16 + lc)*64 + ks*32 + kg*8];
      acc[nt] = __builtin_amdgcn_mfma_f32_16x16x32_bf16(a, b, acc[nt], 0, 0, 0);
    }
  }
  #pragma unroll
  for (int nt = 0; nt < 8; nt++) {
    const int dp = nt*16 + lc;
    const int dm = dmL[dp];
    #pragma unroll
    for (int r = 0; r < 4; r++) {
      const int s = w*16 + kg*4 + r;
      if (s < 50) {
        int tl = 0, wv = s; if (wv >= 25) { tl = 1; wv -= 25; }
        int v = wv + dm; if (v >= 25) v -= 25;
        ys[tl*25 + v][dp] = f2bf(acc[nt][r]);
      }
    }
  }
  __syncthreads();
  u16* Aslab = A + (size_t)n*204800 + (size_t)t2*3200;
  for (int i = tid; i < 800; i += 256) {
    int s = i >> 4, ch = i & 15;
    *(int4*)(Aslab + s*128 + ch*8) = *(const int4*)&ys[s][ch*8];
  }
}

// ---------- stats over 3200 features (v,dp) of A ----------
__global__ __launch_bounds__(256) void k_statsA(const u16* __restrict__ A,
    float* __restrict__ gs1, float* __restrict__ gs2) {
  const int foct = blockIdx.x*256 + threadIdx.x;
  if (foct >= 400) return;
  const int rb = blockIdx.y * 128;
  const size_t f0 = (size_t)foct * 8;
  float s1[8], s2[8];
  #pragma unroll
  for (int i = 0; i < 8; i++) { s1[i] = 0.f; s2[i] = 0.f; }
  for (int r = 0; r < 128; r++) {
    union { int4 i4; u16 u[8]; } raw;
    raw.i4 = *(const int4*)(A + (size_t)(rb + r)*3200 + f0);
    #pragma unroll
    for (int i = 0; i < 8; i++) { float v = bf2f(raw.u[i]); s1[i] += v; s2[i] = fmaf(v, v, s2[i]); }
  }
  #pragma unroll
  for (int i = 0; i < 8; i++) { atomicAdd(&gs1[f0+i], s1[i]); atomicAdd(&gs2[f0+i], s2[i]); }
}

// ---------- finalize gcn bn scale/shift per (v,dp) ----------
__global__ __launch_bounds__(256) void k_fin2(
    const float* __restrict__ gs1, const float* __restrict__ gs2,
    const float* __restrict__ gg, const float* __restrict__ gb,
    const int* __restrict__ perm1,
    float* __restrict__ scG, float* __restrict__ shG) {
  int f = blockIdx.x*256 + threadIdx.x;
  if (f >= 3200) return;
  int v = f >> 7, dp = f & 127;
  int d = perm1[dp];
  float m = gs1[f] * (1.f/16384.f);
  float var = fmaxf(gs2[f]*(1.f/16384.f) - m*m, 0.f);
  float r = rsqrtf(var + EPS_);
  float sc = gg[v*128 + d] * r;
  scG[f] = sc; shG[f] = gb[v*128 + d] - m*sc;
}

// ---------- K2 (MFMA): down GEMM + y = relu(bn1d(h)+bn(down)), A in place ----------
__global__ __launch_bounds__(256) void k2(
    const float* __restrict__ x, const u16* __restrict__ dwB,
    const float* __restrict__ scG, const float* __restrict__ shG,
    const float* __restrict__ scDP, const float* __restrict__ shDP,
    u16* __restrict__ A) {
  __shared__ __align__(16) u16 xsT[64][72];
  __shared__ __align__(16) u16 ah[6400];
  __shared__ __align__(16) u16 ys[50][136];
  const int tg = blockIdx.x, n = blockIdx.y, tid = threadIdx.x;
  const int t2 = tg * 2;
  const float* xb = x + (size_t)n * 102400;
  u16* Aslab = A + (size_t)n*204800 + (size_t)t2*3200;
  {
    int4* dst = (int4*)ah;
    const int4* src = (const int4*)Aslab;
    for (int i = tid; i < 800; i += 256) dst[i] = src[i];
  }
  for (int e = tid; e < 3200; e += 256) {
    int tl = e / 1600, r = e - tl*1600, c = r / 25, v = r - c*25;
    xsT[tl*25 + v][c] = f2bf(xb[(size_t)c*1600 + (t2+tl)*25 + v]);
  }
  __syncthreads();
  const int w = tid >> 6, l = tid & 63;
  const int lc = l & 15, kg = l >> 4;
  f32x4 acc[8];
  #pragma unroll
  for (int nt = 0; nt < 8; nt++) { acc[nt][0]=0.f; acc[nt][1]=0.f; acc[nt][2]=0.f; acc[nt][3]=0.f; }
  #pragma unroll
  for (int ks = 0; ks < 2; ks++) {
    const bf16x8 a = *(const bf16x8*)&xsT[w*16 + lc][ks*32 + kg*8];
    #pragma unroll
    for (int nt = 0; nt < 8; nt++) {
      const bf16x8 b = *(const bf16x8*)&dwB[(size_t)(nt*16 + lc)*64 + ks*32 + kg*8];
      acc[nt] = __builtin_amdgcn_mfma_f32_16x16x32_bf16(a, b, acc[nt], 0, 0, 0);
    }
  }
  #pragma unroll
  for (int nt = 0; nt < 8; nt++) {
    const int dp = nt*16 + lc;
    const float sD = scDP[dp], hD = shDP[dp];
    #pragma unroll
    for (int r = 0; r < 4; r++) {
      const int s = w*16 + kg*4 + r;
      if (s < 50) {
        int v = s; if (v >= 25) v -= 25;
        int f = v*128 + dp;
        float hb = fmaf(bf2f(ah[s*128 + dp]), scG[f], shG[f]);
        float dd = fmaf(acc[nt][r], sD, hD);
        ys[s][dp] = f2bf(fmaxf(hb + dd, 0.f));
      }
    }
  }
  __syncthreads();
  for (int i = tid; i < 800; i += 256) {
    int s = i >> 4, ch = i & 15;
    *(int4*)(Aslab + s*128 + ch*8) = *(const int4*)&ys[s][ch*8];
  }
}

// ---------- per-128-channel stats (channel-last rows) ----------
__global__ __launch_bounds__(256) void k_statsP(const u16* __restrict__ P, long nrows,
    float* __restrict__ s1g, float* __restrict__ s2g) {
  const int tid = threadIdx.x;
  const int f0 = (tid & 15) * 8;
  const int rg = tid >> 4;
  long rpb = nrows / gridDim.x;
  long rb = (long)blockIdx.x * rpb;
  float s1[8], s2[8];
  #pragma unroll
  for (int i = 0; i < 8; i++) { s1[i] = 0.f; s2[i] = 0.f; }
  for (long r = rg; r < rpb; r += 16) {
    union { int4 i4; u16 u[8]; } raw;
    raw.i4 = *(const int4*)(P + (rb + r)*128 + f0);
    #pragma unroll
    for (int i = 0; i < 8; i++) { float v = bf2f(raw.u[i]); s1[i] += v; s2[i] = fmaf(v, v, s2[i]); }
  }
  __shared__ float m1[16][128], m2[16][128];
  #pragma unroll
  for (int i = 0; i < 8; i++) { m1[rg][f0+i] = s1[i]; m2[rg][f0+i] = s2[i]; }
  __syncthreads();
  if (tid < 128) {
    float a = 0.f, b = 0.f;
    #pragma unroll
    for (int g = 0; g < 16; g++) { a += m1[g][tid]; b += m2[g][tid]; }
    atomicAdd(&s1g[tid], a); atomicAdd(&s2g[tid], b);
  }
}

// ---------- K3 (MFMA, TB=4): bn(y)+shift(theta_in,1)+tl GEMM+bias+relu -> Z bf16 (d_out) ----------
// Single-load staging (5 taps per (v,cp) feed 4 outputs). smem reused: zslT -> A-frags in regs -> ys.
__global__ __launch_bounds__(256) void k3(
    const u16* __restrict__ Y,
    const float* __restrict__ ts1, const float* __restrict__ ts2,
    const float* __restrict__ tgamma, const float* __restrict__ tbeta,
    const int* __restrict__ perm1, const int* __restrict__ perm2,
    const float* __restrict__ ikPf, const float* __restrict__ frP,
    const u16* __restrict__ tlBP, const float* __restrict__ tlb,
    u16* __restrict__ Z) {
  __shared__ __align__(16) u16 smem[128*136];   // zslT rows 0..99 staged; 100..127 garbage; reused as ys
  __shared__ float scL[128], shL[128], frL[128], tlbL[128];
  __shared__ int ikL[128];
  const int tg = blockIdx.x, n = blockIdx.y, tid = threadIdx.x;
  const int t4 = tg * 4;
  if (tid < 128) {
    int cp = tid, c = perm1[cp];
    float m = ts1[cp] * (1.f/409600.f);
    float var = fmaxf(ts2[cp]*(1.f/409600.f) - m*m, 0.f);
    float r = rsqrtf(var + EPS_);
    float sc = tgamma[c] * r;
    scL[cp] = sc; shL[cp] = tbeta[c] - m*sc;
    ikL[cp] = (int)ikPf[cp]; frL[cp] = frP[cp];
    tlbL[cp] = tlb[perm2[cp]];
  }
  __syncthreads();
  const u16* Yb = Y + (size_t)n * 204800;
  for (int e = tid; e < 3200; e += 256) {
    int cp = e & 127, v = e >> 7;
    int ik = ikL[cp];
    float fr = frL[cp], sc = scL[cp], sh = shL[cp];
    const u16* base = Yb + v*128 + cp;
    float y[5];
    #pragma unroll
    for (int j = 0; j < 5; j++) {
      int t = t4 + ik + j;
      y[j] = (t >= 0 && t < 64) ? fmaf(bf2f(base[(size_t)t*3200]), sc, sh) : 0.f;
    }
    #pragma unroll
    for (int tl = 0; tl < 4; tl++)
      smem[(tl*25 + v)*136 + cp] = f2bf((1.f - fr)*y[tl] + fr*y[tl+1]);
  }
  __syncthreads();
  const int w = tid >> 6, l = tid & 63;
  const int lc = l & 15, kg = l >> 4;
  // pull A-fragments (tiles w and w+4) into registers, then smem is free for ys
  bf16x8 a[2][4];
  #pragma unroll
  for (int mi = 0; mi < 2; mi++) {
    const int row = (w + mi*4)*16 + lc;
    #pragma unroll
    for (int ks = 0; ks < 4; ks++)
      a[mi][ks] = *(const bf16x8*)&smem[row*136 + ks*32 + kg*8];
  }
  __syncthreads();
  #pragma unroll
  for (int nt = 0; nt < 8; nt++) {
    const int op = nt*16 + lc;
    bf16x8 b[4];
    #pragma unroll
    for (int ks = 0; ks < 4; ks++)
      b[ks] = *(const bf16x8*)&tlBP[(size_t)op*128 + ks*32 + kg*8];
    const float bb = tlbL[op];
    #pragma unroll
    for (int mi = 0; mi < 2; mi++) {
      f32x4 acc; acc[0]=bb; acc[1]=bb; acc[2]=bb; acc[3]=bb;
      #pragma unroll
      for (int ks = 0; ks < 4; ks++)
        acc = __builtin_amdgcn_mfma_f32_16x16x32_bf16(a[mi][ks], b[ks], acc, 0, 0, 0);
      #pragma unroll
      for (int r = 0; r < 4; r++) {
        const int s = (w + mi*4)*16 + kg*4 + r;
        if (s < 100) smem[s*136 + op] = f2bf(fmaxf(acc[r], 0.f));
      }
    }
  }
  __syncthreads();
  u16* Zb = Z + (size_t)n*204800 + (size_t)t4*3200;
  for (int i = tid; i < 1600; i += 256) {
    int s = i >> 4, ch = i & 15;
    *(int4*)(Zb + s*128 + ch*8) = *(const int4*)&smem[s*136 + ch*8];
  }
}

// ---------- K4: stride-2 shift(theta_out) Z -> C[n][tp][v][op] bf16 ----------
__global__ __launch_bounds__(256) void k4(const u16* __restrict__ Z,
    const float* __restrict__ ik2Pf, const float* __restrict__ fr2P,
    u16* __restrict__ C) {
  __shared__ int ikL[128];
  __shared__ float frL[128];
  if (threadIdx.x < 128) { ikL[threadIdx.x] = (int)ik2Pf[threadIdx.x]; frL[threadIdx.x] = fr2P[threadIdx.x]; }
  __syncthreads();
  for (size_t idx = (size_t)blockIdx.x*256 + threadIdx.x; idx < 26214400ull; idx += (size_t)gridDim.x*256) {
    int op = (int)(idx & 127);
    int v  = (int)((idx >> 7) % 25);
    int tp = (int)((idx / 3200) & 31);
    int n  = (int)(idx / 102400);
    int t0 = 2*tp + ikL[op];
    float fr = frL[op];
    const u16* base = Z + (size_t)n*204800 + v*128 + op;
    float a0 = (t0 >= 0 && t0 < 64) ? bf2f(base[(size_t)t0*3200]) : 0.f;
    int t1 = t0 + 1;
    float a1 = (t1 >= 0 && t1 < 64) ? bf2f(base[(size_t)t1*3200]) : 0.f;
    C[idx] = f2bf((1.f - fr)*a0 + fr*a1);
  }
}

// ---------- K5: res GEMM + out = relu(bn2(C)+bn(res)) -> NCHW fp32 ----------
__global__ __launch_bounds__(256) void k5(
    const float* __restrict__ x, const u16* __restrict__ C,
    const float* __restrict__ rwTP,
    const float* __restrict__ scRP, const float* __restrict__ shRP,
    const float* __restrict__ zs1, const float* __restrict__ zs2,
    const float* __restrict__ t2g, const float* __restrict__ t2b,
    const int* __restrict__ perm2, float* __restrict__ out) {
  __shared__ float xs[2][64][28];
  __shared__ u16 ch[6400];
  __shared__ float sc2L[128], sh2L[128];
  __shared__ int p2L[128];
  const int tpg = blockIdx.x, n = blockIdx.y, tid = threadIdx.x;
  const int tp2 = tpg * 2;
  if (tid < 128) {
    int op = tid, o = perm2[op];
    float m = zs1[op] * (1.f/204800.f);
    float var = fmaxf(zs2[op]*(1.f/204800.f) - m*m, 0.f);
    float r = rsqrtf(var + EPS_);
    float sc = t2g[o] * r;
    sc2L[op] = sc; sh2L[op] = t2b[o] - m*sc;
    p2L[op] = o;
  }
  for (int e = tid; e < 384; e += 256) { int q = e / 3; xs[q>>6][q&63][25 + e%3] = 0.f; }
  const float* xb = x + (size_t)n * 102400;
  for (int e = tid; e < 3200; e += 256) {
    int tl = e / 1600, r = e - tl*1600, c = r / 25, v = r - c*25;
    xs[tl][c][v] = xb[(size_t)c*1600 + 2*(tp2+tl)*25 + v];
  }
  {
    int4* dst = (int4*)ch;
    const int4* src = (const int4*)(C + (size_t)n*102400 + (size_t)tp2*3200);
    for (int i = tid; i < 800; i += 256) dst[i] = src[i];
  }
  __syncthreads();
  const int l = tid & 31, vq = tid >> 5;
  const int o0 = l * 4, v0 = vq * 4;
  if (vq < 7) {
    float acc[2][4][4];
    #pragma unroll
    for (int tl = 0; tl < 2; tl++)
      #pragma unroll
      for (int j = 0; j < 4; j++)
        #pragma unroll
        for (int k = 0; k < 4; k++) acc[tl][j][k] = 0.f;
    for (int c = 0; c < 64; c++) {
      const float4 wv = *(const float4*)&rwTP[c*128 + o0];
      #pragma unroll
      for (int tl = 0; tl < 2; tl++) {
        const float4 xv = *(const float4*)&xs[tl][c][v0];
        OUT16(acc[tl], wv, xv);
      }
    }
    const float4 scr = *(const float4*)&scRP[o0];
    const float4 shr = *(const float4*)&shRP[o0];
    #pragma unroll
    for (int tl = 0; tl < 2; tl++) {
      #pragma unroll
      for (int k = 0; k < 4; k++) {
        int v = v0 + k;
        if (v < 25) {
          union { ushort4 s4; u16 u[4]; } cv;
          cv.s4 = *(const ushort4*)&ch[(tl*25 + v)*128 + o0];
          #pragma unroll
          for (int j = 0; j < 4; j++) {
            float zv = fmaf(bf2f(cv.u[j]), sc2L[o0+j], sh2L[o0+j]);
            float rv = fmaf(acc[tl][j][k], ((const float*)&scr)[j], ((const float*)&shr)[j]);
            out[((size_t)(n*128 + p2L[o0+j])*32 + tp2 + tl)*25 + v] = fmaxf(zv + rv, 0.f);
          }
        }
      }
    }
  }
}

extern "C" void kernel_launch(void* const* d_in, const int* in_sizes, int n_in,
                              void* d_out, int out_size, void* d_ws, size_t ws_size,
                              hipStream_t stream) {
  (void)in_sizes; (void)n_in; (void)out_size;
  if (ws_size < 105200000ull) return;  // clean fail instead of OOB crash
  const float* x     = (const float*)d_in[0];
  const float* Wl    = (const float*)d_in[1];
  const float* fm    = (const float*)d_in[3];
  const float* gg    = (const float*)d_in[4];
  const float* gb    = (const float*)d_in[5];
  const float* dw    = (const float*)d_in[6];
  const float* dbg   = (const float*)d_in[8];
  const float* dbb   = (const float*)d_in[9];
  const float* tgam  = (const float*)d_in[10];
  const float* tbet  = (const float*)d_in[11];
  const float* thin  = (const float*)d_in[12];
  const float* tw    = (const float*)d_in[13];
  const float* tlb   = (const float*)d_in[14];
  const float* thout = (const float*)d_in[15];
  const float* t2g   = (const float*)d_in[16];
  const float* t2b   = (const float*)d_in[17];
  const float* rw    = (const float*)d_in[18];
  const float* rbg   = (const float*)d_in[20];
  const float* rbb   = (const float*)d_in[21];
  float* out = (float*)d_out;
  u16* Zd = (u16*)d_out;            // Z bf16 lives in d_out until k5 overwrites

  u16* A  = (u16*)d_ws;             // [256][64][25][128] bf16 = 104,857,600 B
  u16* Cb = A;                      // C aliases A (A dead after k3)
  float* part = (float*)d_ws;       // k_mom partials (34 MB) — dead before k1 writes A
  float* mskT = (float*)((char*)d_ws + 104857600);   // 1600 f
  u16*  WlB   = (u16*)(mskT + 1600);                 // 8192 u16
  u16*  dwB   = WlB + 8192;                          // 8192 u16
  float* rwTP = (float*)(dwB + 8192);                // 8192 f
  u16*  tlBP  = (u16*)(rwTP + 8192);                 // 16384 u16
  float* scG  = (float*)(tlBP + 16384);              // 3200
  float* shG  = scG + 3200;         // 3200
  float* scDP = shG + 3200;         // 128
  float* shDP = scDP + 128;
  float* scRP = shDP + 128;
  float* shRP = scRP + 128;
  float* ikPf = shRP + 128;
  float* frP  = ikPf + 128;
  float* ik2Pf= frP + 128;
  float* fr2P = ik2Pf + 128;
  float* Sxa  = fr2P + 128;         // zero region start (15232 floats)
  float* Sxe  = Sxa + 4096;
  float* suma = Sxe + 4096;
  float* sume = suma + 64;
  float* gs1  = sume + 64;
  float* gs2  = gs1 + 3200;
  float* ts1  = gs2 + 3200;
  float* ts2  = ts1 + 128;
  float* zs1  = ts2 + 128;
  float* zs2  = zs1 + 128;
  int* perm1  = (int*)(zs2 + 128);
  int* perm2  = perm1 + 128;

  (void)hipMemsetAsync(Sxa, 0, 15232 * sizeof(float), stream);
  k_prep0<<<1, 128, 0, stream>>>(thin, thout, perm1, perm2, ikPf, frP, ik2Pf, fr2P);
  k_prep1<<<64, 256, 0, stream>>>(fm, Wl, dw, rw, tw, perm1, perm2, mskT, WlB, dwB, rwTP, tlBP);
  k_mom<<<1024, 256, 0, stream>>>(x, part);
  k_red<<<dim3(33, 16), 256, 0, stream>>>(part, Sxa, Sxe, suma, sume);
  k_fin<<<1, 256, 0, stream>>>(dw, dbg, dbb, rw, rbg, rbb, perm1, perm2,
                               Sxa, Sxe, suma, sume, scDP, shDP, scRP, shRP);
  k1<<<dim3(32, 256), 256, 0, stream>>>(x, WlB, mskT, perm1, A);
  k_statsA<<<dim3(2, 128), 256, 0, stream>>>(A, gs1, gs2);
  k_fin2<<<13, 256, 0, stream>>>(gs1, gs2, gg, gb, perm1, scG, shG);
  k2<<<dim3(32, 256), 256, 0, stream>>>(x, dwB, scG, shG, scDP, shDP, A);
  k_statsP<<<400, 256, 0, stream>>>(A, 409600L, ts1, ts2);
  k3<<<dim3(16, 256), 256, 0, stream>>>(A, ts1, ts2, tgam, tbet, perm1, perm2,
                                        ikPf, frP, tlBP, tlb, Zd);
  k4<<<2048, 256, 0, stream>>>(Zd, ik2Pf, fr2P, Cb);
  k_statsP<<<400, 256, 0, stream>>>(Cb, 204800L, zs1, zs2);
  k5<<<dim3(16, 256), 256, 0, stream>>>(x, Cb, rwTP, scRP, shRP, zs1, zs2, t2g, t2b, perm2, out);
}

// Round 11
// 930.287 us; speedup vs baseline: 2.0037x; 1.0580x over previous
//
#include <hip/hip_runtime.h>
#include <cstdint>
#include <cstddef>

namespace {
constexpr float EPS_ = 1e-5f;
}

using u16 = unsigned short;
typedef __attribute__((ext_vector_type(8))) short bf16x8;
typedef __attribute__((ext_vector_type(4))) float f32x4;

static __device__ __forceinline__ float bf2f(u16 u) {
  union { unsigned int i; float f; } x; x.i = ((unsigned int)u) << 16; return x.f;
}
static __device__ __forceinline__ u16 f2bf(float f) {
  union { float f; unsigned int i; } x; x.f = f;
  unsigned int r = x.i + 0x7fff + ((x.i >> 16) & 1);
  return (u16)(r >> 16);
}

#define OUT16(a, wv, xv) \
  a[0][0]=fmaf(wv.x,xv.x,a[0][0]); a[0][1]=fmaf(wv.x,xv.y,a[0][1]); \
  a[0][2]=fmaf(wv.x,xv.z,a[0][2]); a[0][3]=fmaf(wv.x,xv.w,a[0][3]); \
  a[1][0]=fmaf(wv.y,xv.x,a[1][0]); a[1][1]=fmaf(wv.y,xv.y,a[1][1]); \
  a[1][2]=fmaf(wv.y,xv.z,a[1][2]); a[1][3]=fmaf(wv.y,xv.w,a[1][3]); \
  a[2][0]=fmaf(wv.z,xv.x,a[2][0]); a[2][1]=fmaf(wv.z,xv.y,a[2][1]); \
  a[2][2]=fmaf(wv.z,xv.z,a[2][2]); a[2][3]=fmaf(wv.z,xv.w,a[2][3]); \
  a[3][0]=fmaf(wv.w,xv.x,a[3][0]); a[3][1]=fmaf(wv.w,xv.y,a[3][1]); \
  a[3][2]=fmaf(wv.w,xv.z,a[3][2]); a[3][3]=fmaf(wv.w,xv.w,a[3][3]);

// ---------- prep0: channel permutations sorted by floor(theta) ----------
__global__ __launch_bounds__(128) void k_prep0(
    const float* __restrict__ thin, const float* __restrict__ thout,
    int* __restrict__ perm1, int* __restrict__ perm2,
    float* __restrict__ ikPf, float* __restrict__ frP,
    float* __restrict__ ik2Pf, float* __restrict__ fr2P) {
  __shared__ float ikL[128], ik2L[128];
  const int c = threadIdx.x;
  float t1 = thin[c], t2 = thout[c];
  float f1 = floorf(t1), f2 = floorf(t2);
  ikL[c] = f1; ik2L[c] = f2;
  __syncthreads();
  int r1 = 0, r2 = 0;
  for (int j = 0; j < 128; j++) {
    r1 += (ikL[j] < f1) || (ikL[j] == f1 && j < c);
    r2 += (ik2L[j] < f2) || (ik2L[j] == f2 && j < c);
  }
  perm1[r1] = c; ikPf[r1] = f1; frP[r1] = t1 - f1;
  perm2[r2] = c; ik2Pf[r2] = f2; fr2P[r2] = t2 - f2;
}

// ---------- prep1: mask + permuted weight tables (bf16 op-major for MFMA B) ----------
__global__ __launch_bounds__(256) void k_prep1(
    const float* __restrict__ fm, const float* __restrict__ Wl,
    const float* __restrict__ dw, const float* __restrict__ rw, const float* __restrict__ tw,
    const int* __restrict__ perm1, const int* __restrict__ perm2,
    float* __restrict__ mskT, u16* __restrict__ WlB, u16* __restrict__ dwB,
    u16* __restrict__ rwB, u16* __restrict__ tlBP) {
  int i = blockIdx.x * 256 + threadIdx.x;
  if (i < 1600) { int c = i / 25, w = i % 25; mskT[c*25 + w] = tanhf(fm[w*64 + c]) + 1.0f; }
  if (i < 8192) {
    int dp = i >> 6, c = i & 63;
    WlB[i] = f2bf(Wl[c*128 + perm1[dp]]);
    dwB[i] = f2bf(dw[perm1[dp]*64 + c]);
    rwB[i] = f2bf(rw[perm2[dp]*64 + c]);
  }
  if (i < 16384) { int op = i >> 7, cp = i & 127; tlBP[i] = f2bf(tw[perm2[op]*128 + perm1[cp]]); }
}

// ---------- second moments of x: per-block partials, NO global atomics ----------
__global__ __launch_bounds__(256) void k_mom(const float* __restrict__ x,
    float* __restrict__ part) {
  __shared__ float xs[100][68];
  const int n = blockIdx.x >> 2, quarter = blockIdx.x & 3, tid = threadIdx.x;
  const int ci = (tid >> 4) * 4, cj = (tid & 15) * 4;
  float ae[4][4], ao[4][4], se[4], so[4];
  #pragma unroll
  for (int i = 0; i < 4; i++) {
    se[i] = 0.f; so[i] = 0.f;
    #pragma unroll
    for (int j = 0; j < 4; j++) { ae[i][j] = 0.f; ao[i][j] = 0.f; }
  }
  const float* xb = x + (size_t)n * 102400;
  float4 pf[7];
  #pragma unroll
  for (int k = 0; k < 7; k++) {
    int e = tid + k*256;
    if (e < 1600) { int c = e/25, q = e - c*25;
      pf[k] = *(const float4*)&xb[(size_t)c*1600 + (quarter*16)*25 + q*4]; }
  }
  for (int it = 0; it < 4; it++) {
    #pragma unroll
    for (int k = 0; k < 7; k++) {
      int e = tid + k*256;
      if (e < 1600) {
        int c = e/25, q = e - c*25;
        xs[q*4+0][c] = pf[k].x; xs[q*4+1][c] = pf[k].y;
        xs[q*4+2][c] = pf[k].z; xs[q*4+3][c] = pf[k].w;
      }
    }
    __syncthreads();
    if (it < 3) {
      const int toff = quarter*16 + (it+1)*4;
      #pragma unroll
      for (int k = 0; k < 7; k++) {
        int e = tid + k*256;
        if (e < 1600) { int c = e/25, q = e - c*25;
          pf[k] = *(const float4*)&xb[(size_t)c*1600 + toff*25 + q*4]; }
      }
    }
    #pragma unroll
    for (int tl = 0; tl < 4; tl++) {
      #pragma unroll 5
      for (int vv = 0; vv < 25; vv++) {
        const int s = tl*25 + vv;
        const float4 ra = *(const float4*)&xs[s][ci];
        const float4 rb = *(const float4*)&xs[s][cj];
        if ((tl & 1) == 0) {
          OUT16(ae, ra, rb);
          if (cj == 0) { se[0] += ra.x; se[1] += ra.y; se[2] += ra.z; se[3] += ra.w; }
        } else {
          OUT16(ao, ra, rb);
          if (cj == 0) { so[0] += ra.x; so[1] += ra.y; so[2] += ra.z; so[3] += ra.w; }
        }
      }
    }
    __syncthreads();
  }
  float* pb = part + (size_t)blockIdx.x * 8320;
  #pragma unroll
  for (int i = 0; i < 4; i++) {
    #pragma unroll
    for (int j = 0; j < 4; j++) {
      pb[tid*16 + i*4 + j]        = ae[i][j] + ao[i][j];
      pb[4096 + tid*16 + i*4 + j] = ae[i][j];
    }
  }
  if (cj == 0) {
    #pragma unroll
    for (int i = 0; i < 4; i++) {
      pb[8192 + (tid>>4)*4 + i] = se[i] + so[i];
      pb[8256 + (tid>>4)*4 + i] = se[i];
    }
  }
}

// ---------- reduce k_mom partials ----------
__global__ __launch_bounds__(256) void k_red(const float* __restrict__ part,
    float* __restrict__ Sxa, float* __restrict__ Sxe,
    float* __restrict__ suma, float* __restrict__ sume) {
  const int f = blockIdx.x*256 + threadIdx.x;
  if (f >= 8320) return;
  const int b0 = blockIdx.y * 64;
  float s = 0.f;
  for (int b = b0; b < b0 + 64; b++) s += part[(size_t)b*8320 + f];
  if (f < 8192) {
    const int half = f >> 12;
    const int q = f & 4095;
    const int t0 = q >> 4, idx = q & 15;
    const int ci = (t0 >> 4)*4 + (idx >> 2);
    const int cj = (t0 & 15)*4 + (idx & 3);
    atomicAdd(half ? &Sxe[ci*64 + cj] : &Sxa[ci*64 + cj], s);
  } else if (f < 8256) {
    atomicAdd(&suma[f - 8192], s);
  } else {
    atomicAdd(&sume[f - 8256], s);
  }
}

// ---------- analytic bn scale/shift for down (perm1) & res (perm2) ----------
__global__ __launch_bounds__(256) void k_fin(
    const float* __restrict__ dw, const float* __restrict__ dbg, const float* __restrict__ dbb,
    const float* __restrict__ rw, const float* __restrict__ rbg, const float* __restrict__ rbb,
    const int* __restrict__ perm1, const int* __restrict__ perm2,
    const float* __restrict__ Sxa, const float* __restrict__ Sxe,
    const float* __restrict__ suma, const float* __restrict__ sume,
    float* __restrict__ scDP, float* __restrict__ shDP,
    float* __restrict__ scRP, float* __restrict__ shRP) {
  __shared__ float SA[4096], SE[4096], sa[64], seL[64];
  const int tid = threadIdx.x;
  for (int i = tid; i < 4096; i += 256) { SA[i] = Sxa[i]; SE[i] = Sxe[i]; }
  if (tid < 64) { sa[tid] = suma[tid]; seL[tid] = sume[tid]; }
  __syncthreads();
  const bool down = tid < 128;
  const int p = tid & 127;
  const int o = down ? perm1[p] : perm2[p];
  const float* w = down ? dw : rw;
  const float* SS = down ? SA : SE;
  const float* sv = down ? sa : seL;
  const float iS = down ? (1.f/409600.f) : (1.f/204800.f);
  float wr[64];
  #pragma unroll
  for (int c = 0; c < 64; c += 4) {
    float4 t = *(const float4*)&w[o*64 + c];
    wr[c] = t.x; wr[c+1] = t.y; wr[c+2] = t.z; wr[c+3] = t.w;
  }
  float mu = 0.f, q = 0.f;
  for (int c = 0; c < 64; c++) {
    mu = fmaf(wr[c], sv[c], mu);
    float pp = 0.f;
    #pragma unroll 8
    for (int c2 = 0; c2 < 64; c2++) pp = fmaf(SS[c*64 + c2], wr[c2], pp);
    q = fmaf(wr[c], pp, q);
  }
  mu *= iS; q *= iS;
  float var = fmaxf(q - mu*mu, 0.f);
  float g = down ? dbg[o] : rbg[o];
  float b = down ? dbb[o] : rbb[o];
  float sc = g * rsqrtf(var + EPS_);
  if (down) { scDP[p] = sc; shDP[p] = b - mu*sc; }
  else      { scRP[p] = sc; shRP[p] = b - mu*sc; }
}

// ---------- K1 (MFMA): GCN GEMM (mask+shift in, vertex shuffle out) -> A[n][t][v][dp] bf16 ----------
__global__ __launch_bounds__(256) void k1(
    const float* __restrict__ x, const u16* __restrict__ WlB,
    const float* __restrict__ mskT, const int* __restrict__ perm1,
    u16* __restrict__ A) {
  __shared__ __align__(16) u16 xmT[64][72];
  __shared__ __align__(16) u16 ys[50][136];
  __shared__ int dmL[128];
  const int tg = blockIdx.x, n = blockIdx.y, tid = threadIdx.x;
  const int t2 = tg * 2;
  if (tid < 128) dmL[tid] = perm1[tid] % 25;
  const float* xb = x + (size_t)n * 102400;
  for (int e = tid; e < 3200; e += 256) {
    int tl = e / 1600, r = e - tl*1600, c = r / 25, w_ = r - c*25;
    int cm = c; if (cm >= 50) cm -= 50; else if (cm >= 25) cm -= 25;
    int vs = w_ + cm; if (vs >= 25) vs -= 25;
    xmT[tl*25 + w_][c] = f2bf(xb[(size_t)c*1600 + (t2+tl)*25 + vs] * mskT[c*25 + w_]);
  }
  __syncthreads();
  const int w = tid >> 6, l = tid & 63;
  const int lc = l & 15, kg = l >> 4;
  f32x4 acc[8];
  #pragma unroll
  for (int nt = 0; nt < 8; nt++) { acc[nt][0]=0.f; acc[nt][1]=0.f; acc[nt][2]=0.f; acc[nt][3]=0.f; }
  #pragma unroll
  for (int ks = 0; ks < 2; ks++) {
    const bf16x8 a = *(const bf16x8*)&xmT[w*16 + lc][ks*32 + kg*8];
    #pragma unroll
    for (int nt = 0; nt < 8; nt++) {
      const bf16x8 b = *(const bf16x8*)&WlB[(size_t)(nt*16 + lc)*64 + ks*32 + kg*8];
      acc[nt] = __builtin_amdgcn_mfma_f32_16x16x32_bf16(a, b, acc[nt], 0, 0, 0);
    }
  }
  #pragma unroll
  for (int nt = 0; nt < 8; nt++) {
    const int dp = nt*16 + lc;
    const int dm = dmL[dp];
    #pragma unroll
    for (int r = 0; r < 4; r++) {
      const int s = w*16 + kg*4 + r;
      if (s < 50) {
        int tl = 0, wv = s; if (wv >= 25) { tl = 1; wv -= 25; }
        int v = wv + dm; if (v >= 25) v -= 25;
        ys[tl*25 + v][dp] = f2bf(acc[nt][r]);
      }
    }
  }
  __syncthreads();
  u16* Aslab = A + (size_t)n*204800 + (size_t)t2*3200;
  for (int i = tid; i < 800; i += 256) {
    int s = i >> 4, ch = i & 15;
    *(int4*)(Aslab + s*128 + ch*8) = *(const int4*)&ys[s][ch*8];
  }
}

// ---------- stats over 3200 features (v,dp) of A ----------
__global__ __launch_bounds__(256) void k_statsA(const u16* __restrict__ A,
    float* __restrict__ gs1, float* __restrict__ gs2) {
  const int foct = blockIdx.x*256 + threadIdx.x;
  if (foct >= 400) return;
  const int rb = blockIdx.y * 128;
  const size_t f0 = (size_t)foct * 8;
  float s1[8], s2[8];
  #pragma unroll
  for (int i = 0; i < 8; i++) { s1[i] = 0.f; s2[i] = 0.f; }
  for (int r = 0; r < 128; r++) {
    union { int4 i4; u16 u[8]; } raw;
    raw.i4 = *(const int4*)(A + (size_t)(rb + r)*3200 + f0);
    #pragma unroll
    for (int i = 0; i < 8; i++) { float v = bf2f(raw.u[i]); s1[i] += v; s2[i] = fmaf(v, v, s2[i]); }
  }
  #pragma unroll
  for (int i = 0; i < 8; i++) { atomicAdd(&gs1[f0+i], s1[i]); atomicAdd(&gs2[f0+i], s2[i]); }
}

// ---------- finalize gcn bn scale/shift per (v,dp) ----------
__global__ __launch_bounds__(256) void k_fin2(
    const float* __restrict__ gs1, const float* __restrict__ gs2,
    const float* __restrict__ gg, const float* __restrict__ gb,
    const int* __restrict__ perm1,
    float* __restrict__ scG, float* __restrict__ shG) {
  int f = blockIdx.x*256 + threadIdx.x;
  if (f >= 3200) return;
  int v = f >> 7, dp = f & 127;
  int d = perm1[dp];
  float m = gs1[f] * (1.f/16384.f);
  float var = fmaxf(gs2[f]*(1.f/16384.f) - m*m, 0.f);
  float r = rsqrtf(var + EPS_);
  float sc = gg[v*128 + d] * r;
  scG[f] = sc; shG[f] = gb[v*128 + d] - m*sc;
}

// ---------- K2 (MFMA): down GEMM + y = relu(bn1d(h)+bn(down)), A in place ----------
__global__ __launch_bounds__(256) void k2(
    const float* __restrict__ x, const u16* __restrict__ dwB,
    const float* __restrict__ scG, const float* __restrict__ shG,
    const float* __restrict__ scDP, const float* __restrict__ shDP,
    u16* __restrict__ A) {
  __shared__ __align__(16) u16 xsT[64][72];
  __shared__ __align__(16) u16 ah[6400];
  __shared__ __align__(16) u16 ys[50][136];
  const int tg = blockIdx.x, n = blockIdx.y, tid = threadIdx.x;
  const int t2 = tg * 2;
  const float* xb = x + (size_t)n * 102400;
  u16* Aslab = A + (size_t)n*204800 + (size_t)t2*3200;
  {
    int4* dst = (int4*)ah;
    const int4* src = (const int4*)Aslab;
    for (int i = tid; i < 800; i += 256) dst[i] = src[i];
  }
  for (int e = tid; e < 3200; e += 256) {
    int tl = e / 1600, r = e - tl*1600, c = r / 25, v = r - c*25;
    xsT[tl*25 + v][c] = f2bf(xb[(size_t)c*1600 + (t2+tl)*25 + v]);
  }
  __syncthreads();
  const int w = tid >> 6, l = tid & 63;
  const int lc = l & 15, kg = l >> 4;
  f32x4 acc[8];
  #pragma unroll
  for (int nt = 0; nt < 8; nt++) { acc[nt][0]=0.f; acc[nt][1]=0.f; acc[nt][2]=0.f; acc[nt][3]=0.f; }
  #pragma unroll
  for (int ks = 0; ks < 2; ks++) {
    const bf16x8 a = *(const bf16x8*)&xsT[w*16 + lc][ks*32 + kg*8];
    #pragma unroll
    for (int nt = 0; nt < 8; nt++) {
      const bf16x8 b = *(const bf16x8*)&dwB[(size_t)(nt*16 + lc)*64 + ks*32 + kg*8];
      acc[nt] = __builtin_amdgcn_mfma_f32_16x16x32_bf16(a, b, acc[nt], 0, 0, 0);
    }
  }
  #pragma unroll
  for (int nt = 0; nt < 8; nt++) {
    const int dp = nt*16 + lc;
    const float sD = scDP[dp], hD = shDP[dp];
    #pragma unroll
    for (int r = 0; r < 4; r++) {
      const int s = w*16 + kg*4 + r;
      if (s < 50) {
        int v = s; if (v >= 25) v -= 25;
        int f = v*128 + dp;
        float hb = fmaf(bf2f(ah[s*128 + dp]), scG[f], shG[f]);
        float dd = fmaf(acc[nt][r], sD, hD);
        ys[s][dp] = f2bf(fmaxf(hb + dd, 0.f));
      }
    }
  }
  __syncthreads();
  for (int i = tid; i < 800; i += 256) {
    int s = i >> 4, ch = i & 15;
    *(int4*)(Aslab + s*128 + ch*8) = *(const int4*)&ys[s][ch*8];
  }
}

// ---------- per-128-channel stats (channel-last rows) ----------
__global__ __launch_bounds__(256) void k_statsP(const u16* __restrict__ P, long nrows,
    float* __restrict__ s1g, float* __restrict__ s2g) {
  const int tid = threadIdx.x;
  const int f0 = (tid & 15) * 8;
  const int rg = tid >> 4;
  long rpb = nrows / gridDim.x;
  long rb = (long)blockIdx.x * rpb;
  float s1[8], s2[8];
  #pragma unroll
  for (int i = 0; i < 8; i++) { s1[i] = 0.f; s2[i] = 0.f; }
  for (long r = rg; r < rpb; r += 16) {
    union { int4 i4; u16 u[8]; } raw;
    raw.i4 = *(const int4*)(P + (rb + r)*128 + f0);
    #pragma unroll
    for (int i = 0; i < 8; i++) { float v = bf2f(raw.u[i]); s1[i] += v; s2[i] = fmaf(v, v, s2[i]); }
  }
  __shared__ float m1[16][128], m2[16][128];
  #pragma unroll
  for (int i = 0; i < 8; i++) { m1[rg][f0+i] = s1[i]; m2[rg][f0+i] = s2[i]; }
  __syncthreads();
  if (tid < 128) {
    float a = 0.f, b = 0.f;
    #pragma unroll
    for (int g = 0; g < 16; g++) { a += m1[g][tid]; b += m2[g][tid]; }
    atomicAdd(&s1g[tid], a); atomicAdd(&s2g[tid], b);
  }
}

// ---------- K3 (MFMA, TB=4): bn(y)+shift(theta_in,1)+tl GEMM+bias+relu -> Z bf16 (d_out) ----------
__global__ __launch_bounds__(256) void k3(
    const u16* __restrict__ Y,
    const float* __restrict__ ts1, const float* __restrict__ ts2,
    const float* __restrict__ tgamma, const float* __restrict__ tbeta,
    const int* __restrict__ perm1, const int* __restrict__ perm2,
    const float* __restrict__ ikPf, const float* __restrict__ frP,
    const u16* __restrict__ tlBP, const float* __restrict__ tlb,
    u16* __restrict__ Z) {
  __shared__ __align__(16) u16 smem[128*136];
  __shared__ float scL[128], shL[128], frL[128], tlbL[128];
  __shared__ int ikL[128];
  const int tg = blockIdx.x, n = blockIdx.y, tid = threadIdx.x;
  const int t4 = tg * 4;
  if (tid < 128) {
    int cp = tid, c = perm1[cp];
    float m = ts1[cp] * (1.f/409600.f);
    float var = fmaxf(ts2[cp]*(1.f/409600.f) - m*m, 0.f);
    float r = rsqrtf(var + EPS_);
    float sc = tgamma[c] * r;
    scL[cp] = sc; shL[cp] = tbeta[c] - m*sc;
    ikL[cp] = (int)ikPf[cp]; frL[cp] = frP[cp];
    tlbL[cp] = tlb[perm2[cp]];
  }
  __syncthreads();
  const u16* Yb = Y + (size_t)n * 204800;
  for (int e = tid; e < 3200; e += 256) {
    int cp = e & 127, v = e >> 7;
    int ik = ikL[cp];
    float fr = frL[cp], sc = scL[cp], sh = shL[cp];
    const u16* base = Yb + v*128 + cp;
    float y[5];
    #pragma unroll
    for (int j = 0; j < 5; j++) {
      int t = t4 + ik + j;
      y[j] = (t >= 0 && t < 64) ? fmaf(bf2f(base[(size_t)t*3200]), sc, sh) : 0.f;
    }
    #pragma unroll
    for (int tl = 0; tl < 4; tl++)
      smem[(tl*25 + v)*136 + cp] = f2bf((1.f - fr)*y[tl] + fr*y[tl+1]);
  }
  __syncthreads();
  const int w = tid >> 6, l = tid & 63;
  const int lc = l & 15, kg = l >> 4;
  bf16x8 a[2][4];
  #pragma unroll
  for (int mi = 0; mi < 2; mi++) {
    const int row = (w + mi*4)*16 + lc;
    #pragma unroll
    for (int ks = 0; ks < 4; ks++)
      a[mi][ks] = *(const bf16x8*)&smem[row*136 + ks*32 + kg*8];
  }
  __syncthreads();
  #pragma unroll
  for (int nt = 0; nt < 8; nt++) {
    const int op = nt*16 + lc;
    bf16x8 b[4];
    #pragma unroll
    for (int ks = 0; ks < 4; ks++)
      b[ks] = *(const bf16x8*)&tlBP[(size_t)op*128 + ks*32 + kg*8];
    const float bb = tlbL[op];
    #pragma unroll
    for (int mi = 0; mi < 2; mi++) {
      f32x4 acc; acc[0]=bb; acc[1]=bb; acc[2]=bb; acc[3]=bb;
      #pragma unroll
      for (int ks = 0; ks < 4; ks++)
        acc = __builtin_amdgcn_mfma_f32_16x16x32_bf16(a[mi][ks], b[ks], acc, 0, 0, 0);
      #pragma unroll
      for (int r = 0; r < 4; r++) {
        const int s = (w + mi*4)*16 + kg*4 + r;
        if (s < 100) smem[s*136 + op] = f2bf(fmaxf(acc[r], 0.f));
      }
    }
  }
  __syncthreads();
  u16* Zb = Z + (size_t)n*204800 + (size_t)t4*3200;
  for (int i = tid; i < 1600; i += 256) {
    int s = i >> 4, ch = i & 15;
    *(int4*)(Zb + s*128 + ch*8) = *(const int4*)&smem[s*136 + ch*8];
  }
}

// ---------- K4: stride-2 shift(theta_out) Z -> C[n][tp][v][op] bf16 ----------
__global__ __launch_bounds__(256) void k4(const u16* __restrict__ Z,
    const float* __restrict__ ik2Pf, const float* __restrict__ fr2P,
    u16* __restrict__ C) {
  __shared__ int ikL[128];
  __shared__ float frL[128];
  if (threadIdx.x < 128) { ikL[threadIdx.x] = (int)ik2Pf[threadIdx.x]; frL[threadIdx.x] = fr2P[threadIdx.x]; }
  __syncthreads();
  for (size_t idx = (size_t)blockIdx.x*256 + threadIdx.x; idx < 26214400ull; idx += (size_t)gridDim.x*256) {
    int op = (int)(idx & 127);
    int v  = (int)((idx >> 7) % 25);
    int tp = (int)((idx / 3200) & 31);
    int n  = (int)(idx / 102400);
    int t0 = 2*tp + ikL[op];
    float fr = frL[op];
    const u16* base = Z + (size_t)n*204800 + v*128 + op;
    float a0 = (t0 >= 0 && t0 < 64) ? bf2f(base[(size_t)t0*3200]) : 0.f;
    int t1 = t0 + 1;
    float a1 = (t1 >= 0 && t1 < 64) ? bf2f(base[(size_t)t1*3200]) : 0.f;
    C[idx] = f2bf((1.f - fr)*a0 + fr*a1);
  }
}

// ---------- K5 (MFMA, 8tp/block): res GEMM + out = relu(bn2(C)+bn(res)) -> NCHW fp32 ----------
// Block owns 8 consecutive tp (4 sub-chunks of 2) so each (n,o)'s 800-B output segment is
// written by ONE block within a short window -> L2 merges partial lines.
__global__ __launch_bounds__(256) void k5(
    const float* __restrict__ x, const u16* __restrict__ C,
    const u16* __restrict__ rwB,
    const float* __restrict__ scRP, const float* __restrict__ shRP,
    const float* __restrict__ zs1, const float* __restrict__ zs2,
    const float* __restrict__ t2g, const float* __restrict__ t2b,
    const int* __restrict__ perm2, float* __restrict__ out) {
  __shared__ __align__(16) u16 xsT[50][72];
  __shared__ __align__(16) u16 ch[6400];
  __shared__ float ys[128][52];
  __shared__ float sc2L[128], sh2L[128];
  __shared__ int p2L[128];
  const int tpg = blockIdx.x, n = blockIdx.y, tid = threadIdx.x;
  if (tid < 128) {
    int op = tid, o = perm2[op];
    float m = zs1[op] * (1.f/204800.f);
    float var = fmaxf(zs2[op]*(1.f/204800.f) - m*m, 0.f);
    float r = rsqrtf(var + EPS_);
    float sc = t2g[o] * r;
    sc2L[op] = sc; sh2L[op] = t2b[o] - m*sc;
    p2L[op] = o;
  }
  const float* xb = x + (size_t)n * 102400;
  const int w = tid >> 6, l = tid & 63;
  const int lc = l & 15, kg = l >> 4;
  for (int sub = 0; sub < 4; sub++) {
    const int tp2 = tpg*8 + sub*2;
    for (int e = tid; e < 3200; e += 256) {
      int tl = e / 1600, r = e - tl*1600, c = r / 25, v = r - c*25;
      xsT[tl*25 + v][c] = f2bf(xb[(size_t)c*1600 + 2*(tp2+tl)*25 + v]);
    }
    {
      int4* dst = (int4*)ch;
      const int4* src = (const int4*)(C + (size_t)n*102400 + (size_t)tp2*3200);
      for (int i = tid; i < 800; i += 256) dst[i] = src[i];
    }
    __syncthreads();
    f32x4 acc[8];
    #pragma unroll
    for (int nt = 0; nt < 8; nt++) { acc[nt][0]=0.f; acc[nt][1]=0.f; acc[nt][2]=0.f; acc[nt][3]=0.f; }
    #pragma unroll
    for (int ks = 0; ks < 2; ks++) {
      const bf16x8 a = *(const bf16x8*)&xsT[w*16 + lc][ks*32 + kg*8];
      #pragma unroll
      for (int nt = 0; nt < 8; nt++) {
        const bf16x8 b = *(const bf16x8*)&rwB[(size_t)(nt*16 + lc)*64 + ks*32 + kg*8];
        acc[nt] = __builtin_amdgcn_mfma_f32_16x16x32_bf16(a, b, acc[nt], 0, 0, 0);
      }
    }
    #pragma unroll
    for (int nt = 0; nt < 8; nt++) {
      const int op = nt*16 + lc;
      const float sR = scRP[op], hR = shRP[op];
      const float sz = sc2L[op], hz = sh2L[op];
      #pragma unroll
      for (int r = 0; r < 4; r++) {
        const int s = w*16 + kg*4 + r;
        if (s < 50) {
          float zv = fmaf(bf2f(ch[s*128 + op]), sz, hz);
          float rv = fmaf(acc[nt][r], sR, hR);
          ys[op][s] = fmaxf(zv + rv, 0.f);
        }
      }
    }
    __syncthreads();
    // coalesced-ish write: per op a contiguous 200-B run; block covers 800 B per (n,o) over 4 subs
    for (int i = tid; i < 6400; i += 256) {
      int op = i / 50, k = i - op*50;
      out[((size_t)(n*128 + p2L[op]))*800 + tp2*25 + k] = ys[op][k];
    }
    __syncthreads();
  }
}

extern "C" void kernel_launch(void* const* d_in, const int* in_sizes, int n_in,
                              void* d_out, int out_size, void* d_ws, size_t ws_size,
                              hipStream_t stream) {
  (void)in_sizes; (void)n_in; (void)out_size;
  if (ws_size < 105200000ull) return;  // clean fail instead of OOB crash
  const float* x     = (const float*)d_in[0];
  const float* Wl    = (const float*)d_in[1];
  const float* fm    = (const float*)d_in[3];
  const float* gg    = (const float*)d_in[4];
  const float* gb    = (const float*)d_in[5];
  const float* dw    = (const float*)d_in[6];
  const float* dbg   = (const float*)d_in[8];
  const float* dbb   = (const float*)d_in[9];
  const float* tgam  = (const float*)d_in[10];
  const float* tbet  = (const float*)d_in[11];
  const float* thin  = (const float*)d_in[12];
  const float* tw    = (const float*)d_in[13];
  const float* tlb   = (const float*)d_in[14];
  const float* thout = (const float*)d_in[15];
  const float* t2g   = (const float*)d_in[16];
  const float* t2b   = (const float*)d_in[17];
  const float* rw    = (const float*)d_in[18];
  const float* rbg   = (const float*)d_in[20];
  const float* rbb   = (const float*)d_in[21];
  float* out = (float*)d_out;
  u16* Zd = (u16*)d_out;            // Z bf16 lives in d_out until k5 overwrites

  u16* A  = (u16*)d_ws;             // [256][64][25][128] bf16 = 104,857,600 B
  u16* Cb = A;                      // C aliases A (A dead after k3)
  float* part = (float*)d_ws;       // k_mom partials (34 MB) — dead before k1 writes A
  float* mskT = (float*)((char*)d_ws + 104857600);   // 1600 f
  u16*  WlB   = (u16*)(mskT + 1600);                 // 8192 u16
  u16*  dwB   = WlB + 8192;                          // 8192 u16
  u16*  rwB   = dwB + 8192;                          // 8192 u16 (in old rwTP slot)
  u16*  tlBP  = (u16*)((float*)(dwB + 8192) + 8192); // 16384 u16
  float* scG  = (float*)(tlBP + 16384);              // 3200
  float* shG  = scG + 3200;         // 3200
  float* scDP = shG + 3200;         // 128
  float* shDP = scDP + 128;
  float* scRP = shDP + 128;
  float* shRP = scRP + 128;
  float* ikPf = shRP + 128;
  float* frP  = ikPf + 128;
  float* ik2Pf= frP + 128;
  float* fr2P = ik2Pf + 128;
  float* Sxa  = fr2P + 128;         // zero region start (15232 floats)
  float* Sxe  = Sxa + 4096;
  float* suma = Sxe + 4096;
  float* sume = suma + 64;
  float* gs1  = sume + 64;
  float* gs2  = gs1 + 3200;
  float* ts1  = gs2 + 3200;
  float* ts2  = ts1 + 128;
  float* zs1  = ts2 + 128;
  float* zs2  = zs1 + 128;
  int* perm1  = (int*)(zs2 + 128);
  int* perm2  = perm1 + 128;

  (void)hipMemsetAsync(Sxa, 0, 15232 * sizeof(float), stream);
  k_prep0<<<1, 128, 0, stream>>>(thin, thout, perm1, perm2, ikPf, frP, ik2Pf, fr2P);
  k_prep1<<<64, 256, 0, stream>>>(fm, Wl, dw, rw, tw, perm1, perm2, mskT, WlB, dwB, rwB, tlBP);
  k_mom<<<1024, 256, 0, stream>>>(x, part);
  k_red<<<dim3(33, 16), 256, 0, stream>>>(part, Sxa, Sxe, suma, sume);
  k_fin<<<1, 256, 0, stream>>>(dw, dbg, dbb, rw, rbg, rbb, perm1, perm2,
                               Sxa, Sxe, suma, sume, scDP, shDP, scRP, shRP);
  k1<<<dim3(32, 256), 256, 0, stream>>>(x, WlB, mskT, perm1, A);
  k_statsA<<<dim3(2, 128), 256, 0, stream>>>(A, gs1, gs2);
  k_fin2<<<13, 256, 0, stream>>>(gs1, gs2, gg, gb, perm1, scG, shG);
  k2<<<dim3(32, 256), 256, 0, stream>>>(x, dwB, scG, shG, scDP, shDP, A);
  k_statsP<<<400, 256, 0, stream>>>(A, 409600L, ts1, ts2);
  k3<<<dim3(16, 256), 256, 0, stream>>>(A, ts1, ts2, tgam, tbet, perm1, perm2,
                                        ikPf, frP, tlBP, tlb, Zd);
  k4<<<2048, 256, 0, stream>>>(Zd, ik2Pf, fr2P, Cb);
  k_statsP<<<400, 256, 0, stream>>>(Cb, 204800L, zs1, zs2);
  k5<<<dim3(4, 256), 256, 0, stream>>>(x, Cb, rwB, scRP, shRP, zs1, zs2, t2g, t2b, perm2, out);
}

// Round 12
// 892.840 us; speedup vs baseline: 2.0877x; 1.0419x over previous
//
#include <hip/hip_runtime.h>
#include <cstdint>
#include <cstddef>

namespace {
constexpr float EPS_ = 1e-5f;
}

using u16 = unsigned short;
typedef __attribute__((ext_vector_type(8))) short bf16x8;
typedef __attribute__((ext_vector_type(4))) float f32x4;

static __device__ __forceinline__ float bf2f(u16 u) {
  union { unsigned int i; float f; } x; x.i = ((unsigned int)u) << 16; return x.f;
}
static __device__ __forceinline__ u16 f2bf(float f) {
  union { float f; unsigned int i; } x; x.f = f;
  unsigned int r = x.i + 0x7fff + ((x.i >> 16) & 1);
  return (u16)(r >> 16);
}

#define OUT16(a, wv, xv) \
  a[0][0]=fmaf(wv.x,xv.x,a[0][0]); a[0][1]=fmaf(wv.x,xv.y,a[0][1]); \
  a[0][2]=fmaf(wv.x,xv.z,a[0][2]); a[0][3]=fmaf(wv.x,xv.w,a[0][3]); \
  a[1][0]=fmaf(wv.y,xv.x,a[1][0]); a[1][1]=fmaf(wv.y,xv.y,a[1][1]); \
  a[1][2]=fmaf(wv.y,xv.z,a[1][2]); a[1][3]=fmaf(wv.y,xv.w,a[1][3]); \
  a[2][0]=fmaf(wv.z,xv.x,a[2][0]); a[2][1]=fmaf(wv.z,xv.y,a[2][1]); \
  a[2][2]=fmaf(wv.z,xv.z,a[2][2]); a[2][3]=fmaf(wv.z,xv.w,a[2][3]); \
  a[3][0]=fmaf(wv.w,xv.x,a[3][0]); a[3][1]=fmaf(wv.w,xv.y,a[3][1]); \
  a[3][2]=fmaf(wv.w,xv.z,a[3][2]); a[3][3]=fmaf(wv.w,xv.w,a[3][3]);

// ---------- prep0: channel permutations sorted by floor(theta) ----------
__global__ __launch_bounds__(128) void k_prep0(
    const float* __restrict__ thin, const float* __restrict__ thout,
    int* __restrict__ perm1, int* __restrict__ perm2,
    float* __restrict__ ikPf, float* __restrict__ frP,
    float* __restrict__ ik2Pf, float* __restrict__ fr2P) {
  __shared__ float ikL[128], ik2L[128];
  const int c = threadIdx.x;
  float t1 = thin[c], t2 = thout[c];
  float f1 = floorf(t1), f2 = floorf(t2);
  ikL[c] = f1; ik2L[c] = f2;
  __syncthreads();
  int r1 = 0, r2 = 0;
  for (int j = 0; j < 128; j++) {
    r1 += (ikL[j] < f1) || (ikL[j] == f1 && j < c);
    r2 += (ik2L[j] < f2) || (ik2L[j] == f2 && j < c);
  }
  perm1[r1] = c; ikPf[r1] = f1; frP[r1] = t1 - f1;
  perm2[r2] = c; ik2Pf[r2] = f2; fr2P[r2] = t2 - f2;
}

// ---------- prep1: mask + permuted weight tables (bf16 op-major for MFMA B) ----------
__global__ __launch_bounds__(256) void k_prep1(
    const float* __restrict__ fm, const float* __restrict__ Wl,
    const float* __restrict__ dw, const float* __restrict__ rw, const float* __restrict__ tw,
    const int* __restrict__ perm1, const int* __restrict__ perm2,
    float* __restrict__ mskT, u16* __restrict__ WlB, u16* __restrict__ dwB,
    u16* __restrict__ rwB, u16* __restrict__ tlBP) {
  int i = blockIdx.x * 256 + threadIdx.x;
  if (i < 1600) { int c = i / 25, w = i % 25; mskT[c*25 + w] = tanhf(fm[w*64 + c]) + 1.0f; }
  if (i < 8192) {
    int dp = i >> 6, c = i & 63;
    WlB[i] = f2bf(Wl[c*128 + perm1[dp]]);
    dwB[i] = f2bf(dw[perm1[dp]*64 + c]);
    rwB[i] = f2bf(rw[perm2[dp]*64 + c]);
  }
  if (i < 16384) { int op = i >> 7, cp = i & 127; tlBP[i] = f2bf(tw[perm2[op]*128 + perm1[cp]]); }
}

// ---------- second moments of x: per-block partials, NO global atomics ----------
__global__ __launch_bounds__(256) void k_mom(const float* __restrict__ x,
    float* __restrict__ part) {
  __shared__ float xs[100][68];
  const int n = blockIdx.x >> 2, quarter = blockIdx.x & 3, tid = threadIdx.x;
  const int ci = (tid >> 4) * 4, cj = (tid & 15) * 4;
  float ae[4][4], ao[4][4], se[4], so[4];
  #pragma unroll
  for (int i = 0; i < 4; i++) {
    se[i] = 0.f; so[i] = 0.f;
    #pragma unroll
    for (int j = 0; j < 4; j++) { ae[i][j] = 0.f; ao[i][j] = 0.f; }
  }
  const float* xb = x + (size_t)n * 102400;
  float4 pf[7];
  #pragma unroll
  for (int k = 0; k < 7; k++) {
    int e = tid + k*256;
    if (e < 1600) { int c = e/25, q = e - c*25;
      pf[k] = *(const float4*)&xb[(size_t)c*1600 + (quarter*16)*25 + q*4]; }
  }
  for (int it = 0; it < 4; it++) {
    #pragma unroll
    for (int k = 0; k < 7; k++) {
      int e = tid + k*256;
      if (e < 1600) {
        int c = e/25, q = e - c*25;
        xs[q*4+0][c] = pf[k].x; xs[q*4+1][c] = pf[k].y;
        xs[q*4+2][c] = pf[k].z; xs[q*4+3][c] = pf[k].w;
      }
    }
    __syncthreads();
    if (it < 3) {
      const int toff = quarter*16 + (it+1)*4;
      #pragma unroll
      for (int k = 0; k < 7; k++) {
        int e = tid + k*256;
        if (e < 1600) { int c = e/25, q = e - c*25;
          pf[k] = *(const float4*)&xb[(size_t)c*1600 + toff*25 + q*4]; }
      }
    }
    #pragma unroll
    for (int tl = 0; tl < 4; tl++) {
      #pragma unroll 5
      for (int vv = 0; vv < 25; vv++) {
        const int s = tl*25 + vv;
        const float4 ra = *(const float4*)&xs[s][ci];
        const float4 rb = *(const float4*)&xs[s][cj];
        if ((tl & 1) == 0) {
          OUT16(ae, ra, rb);
          if (cj == 0) { se[0] += ra.x; se[1] += ra.y; se[2] += ra.z; se[3] += ra.w; }
        } else {
          OUT16(ao, ra, rb);
          if (cj == 0) { so[0] += ra.x; so[1] += ra.y; so[2] += ra.z; so[3] += ra.w; }
        }
      }
    }
    __syncthreads();
  }
  float* pb = part + (size_t)blockIdx.x * 8320;
  #pragma unroll
  for (int i = 0; i < 4; i++) {
    #pragma unroll
    for (int j = 0; j < 4; j++) {
      pb[tid*16 + i*4 + j]        = ae[i][j] + ao[i][j];
      pb[4096 + tid*16 + i*4 + j] = ae[i][j];
    }
  }
  if (cj == 0) {
    #pragma unroll
    for (int i = 0; i < 4; i++) {
      pb[8192 + (tid>>4)*4 + i] = se[i] + so[i];
      pb[8256 + (tid>>4)*4 + i] = se[i];
    }
  }
}

// ---------- reduce k_mom partials ----------
__global__ __launch_bounds__(256) void k_red(const float* __restrict__ part,
    float* __restrict__ Sxa, float* __restrict__ Sxe,
    float* __restrict__ suma, float* __restrict__ sume) {
  const int f = blockIdx.x*256 + threadIdx.x;
  if (f >= 8320) return;
  const int b0 = blockIdx.y * 64;
  float s = 0.f;
  for (int b = b0; b < b0 + 64; b++) s += part[(size_t)b*8320 + f];
  if (f < 8192) {
    const int half = f >> 12;
    const int q = f & 4095;
    const int t0 = q >> 4, idx = q & 15;
    const int ci = (t0 >> 4)*4 + (idx >> 2);
    const int cj = (t0 & 15)*4 + (idx & 3);
    atomicAdd(half ? &Sxe[ci*64 + cj] : &Sxa[ci*64 + cj], s);
  } else if (f < 8256) {
    atomicAdd(&suma[f - 8192], s);
  } else {
    atomicAdd(&sume[f - 8256], s);
  }
}

// ---------- analytic bn scale/shift for down (perm1) & res (perm2) ----------
__global__ __launch_bounds__(256) void k_fin(
    const float* __restrict__ dw, const float* __restrict__ dbg, const float* __restrict__ dbb,
    const float* __restrict__ rw, const float* __restrict__ rbg, const float* __restrict__ rbb,
    const int* __restrict__ perm1, const int* __restrict__ perm2,
    const float* __restrict__ Sxa, const float* __restrict__ Sxe,
    const float* __restrict__ suma, const float* __restrict__ sume,
    float* __restrict__ scDP, float* __restrict__ shDP,
    float* __restrict__ scRP, float* __restrict__ shRP) {
  __shared__ float SA[4096], SE[4096], sa[64], seL[64];
  const int tid = threadIdx.x;
  for (int i = tid; i < 4096; i += 256) { SA[i] = Sxa[i]; SE[i] = Sxe[i]; }
  if (tid < 64) { sa[tid] = suma[tid]; seL[tid] = sume[tid]; }
  __syncthreads();
  const bool down = tid < 128;
  const int p = tid & 127;
  const int o = down ? perm1[p] : perm2[p];
  const float* w = down ? dw : rw;
  const float* SS = down ? SA : SE;
  const float* sv = down ? sa : seL;
  const float iS = down ? (1.f/409600.f) : (1.f/204800.f);
  float wr[64];
  #pragma unroll
  for (int c = 0; c < 64; c += 4) {
    float4 t = *(const float4*)&w[o*64 + c];
    wr[c] = t.x; wr[c+1] = t.y; wr[c+2] = t.z; wr[c+3] = t.w;
  }
  float mu = 0.f, q = 0.f;
  for (int c = 0; c < 64; c++) {
    mu = fmaf(wr[c], sv[c], mu);
    float pp = 0.f;
    #pragma unroll 8
    for (int c2 = 0; c2 < 64; c2++) pp = fmaf(SS[c*64 + c2], wr[c2], pp);
    q = fmaf(wr[c], pp, q);
  }
  mu *= iS; q *= iS;
  float var = fmaxf(q - mu*mu, 0.f);
  float g = down ? dbg[o] : rbg[o];
  float b = down ? dbb[o] : rbb[o];
  float sc = g * rsqrtf(var + EPS_);
  if (down) { scDP[p] = sc; shDP[p] = b - mu*sc; }
  else      { scRP[p] = sc; shRP[p] = b - mu*sc; }
}

// ---------- K1 (fused MFMA): GCN GEMM -> A  AND  down GEMM -> D (bf16, lives in d_out) ----------
__global__ __launch_bounds__(256) void k1(
    const float* __restrict__ x, const u16* __restrict__ WlB, const u16* __restrict__ dwB,
    const float* __restrict__ mskT, const int* __restrict__ perm1,
    u16* __restrict__ A, u16* __restrict__ D) {
  __shared__ __align__(16) u16 xsT[64][72];   // raw x^T bf16 (rows 50..63 garbage, outputs discarded)
  __shared__ __align__(16) u16 xmT[64][72];   // masked+shifted bf16
  __shared__ __align__(16) u16 ys[50][136];
  __shared__ int dmL[128];
  const int tg = blockIdx.x, n = blockIdx.y, tid = threadIdx.x;
  const int t2 = tg * 2;
  if (tid < 128) dmL[tid] = perm1[tid] % 25;
  const float* xb = x + (size_t)n * 102400 + (size_t)t2 * 25;
  // stage raw x, float2-vectorized: 64 c x 25 float2 (50 consecutive floats per c cover both t-slices)
  for (int e = tid; e < 1600; e += 256) {
    int c = e / 25, q = e - c*25;
    const float2 v2 = *(const float2*)&xb[(size_t)c*1600 + q*2];
    xsT[q*2 + 0][c] = f2bf(v2.x);
    xsT[q*2 + 1][c] = f2bf(v2.y);
  }
  __syncthreads();
  // masked + vertex-shifted copy (from LDS)
  for (int e = tid; e < 3200; e += 256) {
    int c = e / 50, r = e - c*50, tl = r / 25, w_ = r - tl*25;
    int cm = c; if (cm >= 50) cm -= 50; else if (cm >= 25) cm -= 25;
    int vs = w_ + cm; if (vs >= 25) vs -= 25;
    xmT[tl*25 + w_][c] = f2bf(bf2f(xsT[tl*25 + vs][c]) * mskT[c*25 + w_]);
  }
  __syncthreads();
  const int w = tid >> 6, l = tid & 63;
  const int lc = l & 15, kg = l >> 4;
  f32x4 accA[8], accD[8];
  #pragma unroll
  for (int nt = 0; nt < 8; nt++) {
    accA[nt][0]=0.f; accA[nt][1]=0.f; accA[nt][2]=0.f; accA[nt][3]=0.f;
    accD[nt][0]=0.f; accD[nt][1]=0.f; accD[nt][2]=0.f; accD[nt][3]=0.f;
  }
  #pragma unroll
  for (int ks = 0; ks < 2; ks++) {
    const bf16x8 am = *(const bf16x8*)&xmT[w*16 + lc][ks*32 + kg*8];
    const bf16x8 ax = *(const bf16x8*)&xsT[w*16 + lc][ks*32 + kg*8];
    #pragma unroll
    for (int nt = 0; nt < 8; nt++) {
      const bf16x8 bW = *(const bf16x8*)&WlB[(size_t)(nt*16 + lc)*64 + ks*32 + kg*8];
      const bf16x8 bD = *(const bf16x8*)&dwB[(size_t)(nt*16 + lc)*64 + ks*32 + kg*8];
      accA[nt] = __builtin_amdgcn_mfma_f32_16x16x32_bf16(am, bW, accA[nt], 0, 0, 0);
      accD[nt] = __builtin_amdgcn_mfma_f32_16x16x32_bf16(ax, bD, accD[nt], 0, 0, 0);
    }
  }
  // ---- D epilogue (straight) ----
  #pragma unroll
  for (int nt = 0; nt < 8; nt++) {
    const int dp = nt*16 + lc;
    #pragma unroll
    for (int r = 0; r < 4; r++) {
      const int s = w*16 + kg*4 + r;
      if (s < 50) ys[s][dp] = f2bf(accD[nt][r]);
    }
  }
  __syncthreads();
  {
    u16* Dslab = D + (size_t)n*204800 + (size_t)t2*3200;
    for (int i = tid; i < 800; i += 256) {
      int s = i >> 4, ch = i & 15;
      *(int4*)(Dslab + s*128 + ch*8) = *(const int4*)&ys[s][ch*8];
    }
  }
  __syncthreads();
  // ---- A epilogue (vertex shuffle) ----
  #pragma unroll
  for (int nt = 0; nt < 8; nt++) {
    const int dp = nt*16 + lc;
    const int dm = dmL[dp];
    #pragma unroll
    for (int r = 0; r < 4; r++) {
      const int s = w*16 + kg*4 + r;
      if (s < 50) {
        int tl = 0, wv = s; if (wv >= 25) { tl = 1; wv -= 25; }
        int v = wv + dm; if (v >= 25) v -= 25;
        ys[tl*25 + v][dp] = f2bf(accA[nt][r]);
      }
    }
  }
  __syncthreads();
  u16* Aslab = A + (size_t)n*204800 + (size_t)t2*3200;
  for (int i = tid; i < 800; i += 256) {
    int s = i >> 4, ch = i & 15;
    *(int4*)(Aslab + s*128 + ch*8) = *(const int4*)&ys[s][ch*8];
  }
}

// ---------- stats over 3200 features (v,dp) of A ----------
__global__ __launch_bounds__(256) void k_statsA(const u16* __restrict__ A,
    float* __restrict__ gs1, float* __restrict__ gs2) {
  const int foct = blockIdx.x*256 + threadIdx.x;
  if (foct >= 400) return;
  const int rb = blockIdx.y * 128;
  const size_t f0 = (size_t)foct * 8;
  float s1[8], s2[8];
  #pragma unroll
  for (int i = 0; i < 8; i++) { s1[i] = 0.f; s2[i] = 0.f; }
  for (int r = 0; r < 128; r++) {
    union { int4 i4; u16 u[8]; } raw;
    raw.i4 = *(const int4*)(A + (size_t)(rb + r)*3200 + f0);
    #pragma unroll
    for (int i = 0; i < 8; i++) { float v = bf2f(raw.u[i]); s1[i] += v; s2[i] = fmaf(v, v, s2[i]); }
  }
  #pragma unroll
  for (int i = 0; i < 8; i++) { atomicAdd(&gs1[f0+i], s1[i]); atomicAdd(&gs2[f0+i], s2[i]); }
}

// ---------- finalize gcn bn scale/shift per (v,dp) ----------
__global__ __launch_bounds__(256) void k_fin2(
    const float* __restrict__ gs1, const float* __restrict__ gs2,
    const float* __restrict__ gg, const float* __restrict__ gb,
    const int* __restrict__ perm1,
    float* __restrict__ scG, float* __restrict__ shG) {
  int f = blockIdx.x*256 + threadIdx.x;
  if (f >= 3200) return;
  int v = f >> 7, dp = f & 127;
  int d = perm1[dp];
  float m = gs1[f] * (1.f/16384.f);
  float var = fmaxf(gs2[f]*(1.f/16384.f) - m*m, 0.f);
  float r = rsqrtf(var + EPS_);
  float sc = gg[v*128 + d] * r;
  scG[f] = sc; shG[f] = gb[v*128 + d] - m*sc;
}

// ---------- K2f: streaming y = relu(bn1d(h)+bn(down)) with fused ts1/ts2 stats ----------
__global__ __launch_bounds__(256) void k2f(
    u16* __restrict__ A, const u16* __restrict__ D,
    const float* __restrict__ scG, const float* __restrict__ shG,
    const float* __restrict__ scDP, const float* __restrict__ shDP,
    float* __restrict__ ts1, float* __restrict__ ts2) {
  const int tid = threadIdx.x;
  const int f0 = (tid & 15) * 8;
  const int rg = tid >> 4;
  const long rb = (long)blockIdx.x * 400;
  float sD[8], hD[8];
  #pragma unroll
  for (int i = 0; i < 8; i++) { sD[i] = scDP[f0+i]; hD[i] = shDP[f0+i]; }
  float s1[8], s2[8];
  #pragma unroll
  for (int i = 0; i < 8; i++) { s1[i] = 0.f; s2[i] = 0.f; }
  for (int r = rg; r < 400; r += 16) {
    const long row = rb + r;
    const int v = (int)(row % 25);
    union { int4 i4; u16 u[8]; } araw, draw, o;
    araw.i4 = *(const int4*)(A + row*128 + f0);
    draw.i4 = *(const int4*)(D + row*128 + f0);
    const float4 g0 = *(const float4*)&scG[v*128 + f0];
    const float4 g1 = *(const float4*)&scG[v*128 + f0 + 4];
    const float4 b0 = *(const float4*)&shG[v*128 + f0];
    const float4 b1 = *(const float4*)&shG[v*128 + f0 + 4];
    const float gg_[8] = {g0.x,g0.y,g0.z,g0.w,g1.x,g1.y,g1.z,g1.w};
    const float bb_[8] = {b0.x,b0.y,b0.z,b0.w,b1.x,b1.y,b1.z,b1.w};
    #pragma unroll
    for (int i = 0; i < 8; i++) {
      float y = fmaf(bf2f(araw.u[i]), gg_[i], bb_[i]) + fmaf(bf2f(draw.u[i]), sD[i], hD[i]);
      y = fmaxf(y, 0.f);
      s1[i] += y; s2[i] = fmaf(y, y, s2[i]);
      o.u[i] = f2bf(y);
    }
    *(int4*)(A + row*128 + f0) = o.i4;
  }
  __shared__ float m1[16][128], m2[16][128];
  #pragma unroll
  for (int i = 0; i < 8; i++) { m1[rg][f0+i] = s1[i]; m2[rg][f0+i] = s2[i]; }
  __syncthreads();
  if (tid < 128) {
    float a = 0.f, b = 0.f;
    #pragma unroll
    for (int g = 0; g < 16; g++) { a += m1[g][tid]; b += m2[g][tid]; }
    atomicAdd(&ts1[tid], a); atomicAdd(&ts2[tid], b);
  }
}

// ---------- per-128-channel stats (channel-last rows) ----------
__global__ __launch_bounds__(256) void k_statsP(const u16* __restrict__ P, long nrows,
    float* __restrict__ s1g, float* __restrict__ s2g) {
  const int tid = threadIdx.x;
  const int f0 = (tid & 15) * 8;
  const int rg = tid >> 4;
  long rpb = nrows / gridDim.x;
  long rb = (long)blockIdx.x * rpb;
  float s1[8], s2[8];
  #pragma unroll
  for (int i = 0; i < 8; i++) { s1[i] = 0.f; s2[i] = 0.f; }
  for (long r = rg; r < rpb; r += 16) {
    union { int4 i4; u16 u[8]; } raw;
    raw.i4 = *(const int4*)(P + (rb + r)*128 + f0);
    #pragma unroll
    for (int i = 0; i < 8; i++) { float v = bf2f(raw.u[i]); s1[i] += v; s2[i] = fmaf(v, v, s2[i]); }
  }
  __shared__ float m1[16][128], m2[16][128];
  #pragma unroll
  for (int i = 0; i < 8; i++) { m1[rg][f0+i] = s1[i]; m2[rg][f0+i] = s2[i]; }
  __syncthreads();
  if (tid < 128) {
    float a = 0.f, b = 0.f;
    #pragma unroll
    for (int g = 0; g < 16; g++) { a += m1[g][tid]; b += m2[g][tid]; }
    atomicAdd(&s1g[tid], a); atomicAdd(&s2g[tid], b);
  }
}

// ---------- K3 (MFMA, TB=4): bn(y)+shift(theta_in,1)+tl GEMM+bias+relu -> Z bf16 (d_out) ----------
__global__ __launch_bounds__(256) void k3(
    const u16* __restrict__ Y,
    const float* __restrict__ ts1, const float* __restrict__ ts2,
    const float* __restrict__ tgamma, const float* __restrict__ tbeta,
    const int* __restrict__ perm1, const int* __restrict__ perm2,
    const float* __restrict__ ikPf, const float* __restrict__ frP,
    const u16* __restrict__ tlBP, const float* __restrict__ tlb,
    u16* __restrict__ Z) {
  __shared__ __align__(16) u16 smem[128*136];
  __shared__ float scL[128], shL[128], frL[128], tlbL[128];
  __shared__ int ikL[128];
  const int tg = blockIdx.x, n = blockIdx.y, tid = threadIdx.x;
  const int t4 = tg * 4;
  if (tid < 128) {
    int cp = tid, c = perm1[cp];
    float m = ts1[cp] * (1.f/409600.f);
    float var = fmaxf(ts2[cp]*(1.f/409600.f) - m*m, 0.f);
    float r = rsqrtf(var + EPS_);
    float sc = tgamma[c] * r;
    scL[cp] = sc; shL[cp] = tbeta[c] - m*sc;
    ikL[cp] = (int)ikPf[cp]; frL[cp] = frP[cp];
    tlbL[cp] = tlb[perm2[cp]];
  }
  __syncthreads();
  const u16* Yb = Y + (size_t)n * 204800;
  for (int e = tid; e < 3200; e += 256) {
    int cp = e & 127, v = e >> 7;
    int ik = ikL[cp];
    float fr = frL[cp], sc = scL[cp], sh = shL[cp];
    const u16* base = Yb + v*128 + cp;
    float y[5];
    #pragma unroll
    for (int j = 0; j < 5; j++) {
      int t = t4 + ik + j;
      y[j] = (t >= 0 && t < 64) ? fmaf(bf2f(base[(size_t)t*3200]), sc, sh) : 0.f;
    }
    #pragma unroll
    for (int tl = 0; tl < 4; tl++)
      smem[(tl*25 + v)*136 + cp] = f2bf((1.f - fr)*y[tl] + fr*y[tl+1]);
  }
  __syncthreads();
  const int w = tid >> 6, l = tid & 63;
  const int lc = l & 15, kg = l >> 4;
  bf16x8 a[2][4];
  #pragma unroll
  for (int mi = 0; mi < 2; mi++) {
    const int row = (w + mi*4)*16 + lc;
    #pragma unroll
    for (int ks = 0; ks < 4; ks++)
      a[mi][ks] = *(const bf16x8*)&smem[row*136 + ks*32 + kg*8];
  }
  __syncthreads();
  #pragma unroll
  for (int nt = 0; nt < 8; nt++) {
    const int op = nt*16 + lc;
    bf16x8 b[4];
    #pragma unroll
    for (int ks = 0; ks < 4; ks++)
      b[ks] = *(const bf16x8*)&tlBP[(size_t)op*128 + ks*32 + kg*8];
    const float bb = tlbL[op];
    #pragma unroll
    for (int mi = 0; mi < 2; mi++) {
      f32x4 acc; acc[0]=bb; acc[1]=bb; acc[2]=bb; acc[3]=bb;
      #pragma unroll
      for (int ks = 0; ks < 4; ks++)
        acc = __builtin_amdgcn_mfma_f32_16x16x32_bf16(a[mi][ks], b[ks], acc, 0, 0, 0);
      #pragma unroll
      for (int r = 0; r < 4; r++) {
        const int s = (w + mi*4)*16 + kg*4 + r;
        if (s < 100) smem[s*136 + op] = f2bf(fmaxf(acc[r], 0.f));
      }
    }
  }
  __syncthreads();
  u16* Zb = Z + (size_t)n*204800 + (size_t)t4*3200;
  for (int i = tid; i < 1600; i += 256) {
    int s = i >> 4, ch = i & 15;
    *(int4*)(Zb + s*128 + ch*8) = *(const int4*)&smem[s*136 + ch*8];
  }
}

// ---------- K4: stride-2 shift(theta_out) Z -> C[n][tp][v][op] bf16 ----------
__global__ __launch_bounds__(256) void k4(const u16* __restrict__ Z,
    const float* __restrict__ ik2Pf, const float* __restrict__ fr2P,
    u16* __restrict__ C) {
  __shared__ int ikL[128];
  __shared__ float frL[128];
  if (threadIdx.x < 128) { ikL[threadIdx.x] = (int)ik2Pf[threadIdx.x]; frL[threadIdx.x] = fr2P[threadIdx.x]; }
  __syncthreads();
  for (size_t idx = (size_t)blockIdx.x*256 + threadIdx.x; idx < 26214400ull; idx += (size_t)gridDim.x*256) {
    int op = (int)(idx & 127);
    int v  = (int)((idx >> 7) % 25);
    int tp = (int)((idx / 3200) & 31);
    int n  = (int)(idx / 102400);
    int t0 = 2*tp + ikL[op];
    float fr = frL[op];
    const u16* base = Z + (size_t)n*204800 + v*128 + op;
    float a0 = (t0 >= 0 && t0 < 64) ? bf2f(base[(size_t)t0*3200]) : 0.f;
    int t1 = t0 + 1;
    float a1 = (t1 >= 0 && t1 < 64) ? bf2f(base[(size_t)t1*3200]) : 0.f;
    C[idx] = f2bf((1.f - fr)*a0 + fr*a1);
  }
}

// ---------- K5 (MFMA, 8tp/block): res GEMM + out = relu(bn2(C)+bn(res)) -> NCHW fp32 ----------
__global__ __launch_bounds__(256) void k5(
    const float* __restrict__ x, const u16* __restrict__ C,
    const u16* __restrict__ rwB,
    const float* __restrict__ scRP, const float* __restrict__ shRP,
    const float* __restrict__ zs1, const float* __restrict__ zs2,
    const float* __restrict__ t2g, const float* __restrict__ t2b,
    const int* __restrict__ perm2, float* __restrict__ out) {
  __shared__ __align__(16) u16 xsT[50][72];
  __shared__ __align__(16) u16 ch[6400];
  __shared__ float ys[128][52];
  __shared__ float sc2L[128], sh2L[128];
  __shared__ int p2L[128];
  const int tpg = blockIdx.x, n = blockIdx.y, tid = threadIdx.x;
  if (tid < 128) {
    int op = tid, o = perm2[op];
    float m = zs1[op] * (1.f/204800.f);
    float var = fmaxf(zs2[op]*(1.f/204800.f) - m*m, 0.f);
    float r = rsqrtf(var + EPS_);
    float sc = t2g[o] * r;
    sc2L[op] = sc; sh2L[op] = t2b[o] - m*sc;
    p2L[op] = o;
  }
  const float* xb = x + (size_t)n * 102400;
  const int w = tid >> 6, l = tid & 63;
  const int lc = l & 15, kg = l >> 4;
  for (int sub = 0; sub < 4; sub++) {
    const int tp2 = tpg*8 + sub*2;
    for (int e = tid; e < 3200; e += 256) {
      int tl = e / 1600, r = e - tl*1600, c = r / 25, v = r - c*25;
      xsT[tl*25 + v][c] = f2bf(xb[(size_t)c*1600 + 2*(tp2+tl)*25 + v]);
    }
    {
      int4* dst = (int4*)ch;
      const int4* src = (const int4*)(C + (size_t)n*102400 + (size_t)tp2*3200);
      for (int i = tid; i < 800; i += 256) dst[i] = src[i];
    }
    __syncthreads();
    f32x4 acc[8];
    #pragma unroll
    for (int nt = 0; nt < 8; nt++) { acc[nt][0]=0.f; acc[nt][1]=0.f; acc[nt][2]=0.f; acc[nt][3]=0.f; }
    #pragma unroll
    for (int ks = 0; ks < 2; ks++) {
      const bf16x8 a = *(const bf16x8*)&xsT[w*16 + lc][ks*32 + kg*8];
      #pragma unroll
      for (int nt = 0; nt < 8; nt++) {
        const bf16x8 b = *(const bf16x8*)&rwB[(size_t)(nt*16 + lc)*64 + ks*32 + kg*8];
        acc[nt] = __builtin_amdgcn_mfma_f32_16x16x32_bf16(a, b, acc[nt], 0, 0, 0);
      }
    }
    #pragma unroll
    for (int nt = 0; nt < 8; nt++) {
      const int op = nt*16 + lc;
      const float sR = scRP[op], hR = shRP[op];
      const float sz = sc2L[op], hz = sh2L[op];
      #pragma unroll
      for (int r = 0; r < 4; r++) {
        const int s = w*16 + kg*4 + r;
        if (s < 50) {
          float zv = fmaf(bf2f(ch[s*128 + op]), sz, hz);
          float rv = fmaf(acc[nt][r], sR, hR);
          ys[op][s] = fmaxf(zv + rv, 0.f);
        }
      }
    }
    __syncthreads();
    for (int i = tid; i < 6400; i += 256) {
      int op = i / 50, k = i - op*50;
      out[((size_t)(n*128 + p2L[op]))*800 + tp2*25 + k] = ys[op][k];
    }
    __syncthreads();
  }
}

extern "C" void kernel_launch(void* const* d_in, const int* in_sizes, int n_in,
                              void* d_out, int out_size, void* d_ws, size_t ws_size,
                              hipStream_t stream) {
  (void)in_sizes; (void)n_in; (void)out_size;
  if (ws_size < 105200000ull) return;  // clean fail instead of OOB crash
  const float* x     = (const float*)d_in[0];
  const float* Wl    = (const float*)d_in[1];
  const float* fm    = (const float*)d_in[3];
  const float* gg    = (const float*)d_in[4];
  const float* gb    = (const float*)d_in[5];
  const float* dw    = (const float*)d_in[6];
  const float* dbg   = (const float*)d_in[8];
  const float* dbb   = (const float*)d_in[9];
  const float* tgam  = (const float*)d_in[10];
  const float* tbet  = (const float*)d_in[11];
  const float* thin  = (const float*)d_in[12];
  const float* tw    = (const float*)d_in[13];
  const float* tlb   = (const float*)d_in[14];
  const float* thout = (const float*)d_in[15];
  const float* t2g   = (const float*)d_in[16];
  const float* t2b   = (const float*)d_in[17];
  const float* rw    = (const float*)d_in[18];
  const float* rbg   = (const float*)d_in[20];
  const float* rbb   = (const float*)d_in[21];
  float* out = (float*)d_out;
  u16* Zd = (u16*)d_out;            // d_out hosts: D (k1->k2f), then Z (k3->k4), then final out
  u16* Dd = (u16*)d_out;

  u16* A  = (u16*)d_ws;             // [256][64][25][128] bf16 = 104,857,600 B
  u16* Cb = A;                      // C aliases A (A dead after k3)
  float* part = (float*)d_ws;       // k_mom partials (34 MB) — dead before k1 writes A
  float* mskT = (float*)((char*)d_ws + 104857600);   // 1600 f
  u16*  WlB   = (u16*)(mskT + 1600);                 // 8192 u16
  u16*  dwB   = WlB + 8192;                          // 8192 u16
  u16*  rwB   = dwB + 8192;                          // 8192 u16
  u16*  tlBP  = (u16*)((float*)(dwB + 8192) + 8192); // 16384 u16
  float* scG  = (float*)(tlBP + 16384);              // 3200
  float* shG  = scG + 3200;         // 3200
  float* scDP = shG + 3200;         // 128
  float* shDP = scDP + 128;
  float* scRP = shDP + 128;
  float* shRP = scRP + 128;
  float* ikPf = shRP + 128;
  float* frP  = ikPf + 128;
  float* ik2Pf= frP + 128;
  float* fr2P = ik2Pf + 128;
  float* Sxa  = fr2P + 128;         // zero region start (15232 floats)
  float* Sxe  = Sxa + 4096;
  float* suma = Sxe + 4096;
  float* sume = suma + 64;
  float* gs1  = sume + 64;
  float* gs2  = gs1 + 3200;
  float* ts1  = gs2 + 3200;
  float* ts2  = ts1 + 128;
  float* zs1  = ts2 + 128;
  float* zs2  = zs1 + 128;
  int* perm1  = (int*)(zs2 + 128);
  int* perm2  = perm1 + 128;

  (void)hipMemsetAsync(Sxa, 0, 15232 * sizeof(float), stream);
  k_prep0<<<1, 128, 0, stream>>>(thin, thout, perm1, perm2, ikPf, frP, ik2Pf, fr2P);
  k_prep1<<<64, 256, 0, stream>>>(fm, Wl, dw, rw, tw, perm1, perm2, mskT, WlB, dwB, rwB, tlBP);
  k_mom<<<1024, 256, 0, stream>>>(x, part);
  k_red<<<dim3(33, 16), 256, 0, stream>>>(part, Sxa, Sxe, suma, sume);
  k_fin<<<1, 256, 0, stream>>>(dw, dbg, dbb, rw, rbg, rbb, perm1, perm2,
                               Sxa, Sxe, suma, sume, scDP, shDP, scRP, shRP);
  k1<<<dim3(32, 256), 256, 0, stream>>>(x, WlB, dwB, mskT, perm1, A, Dd);
  k_statsA<<<dim3(2, 128), 256, 0, stream>>>(A, gs1, gs2);
  k_fin2<<<13, 256, 0, stream>>>(gs1, gs2, gg, gb, perm1, scG, shG);
  k2f<<<1024, 256, 0, stream>>>(A, Dd, scG, shG, scDP, shDP, ts1, ts2);
  k3<<<dim3(16, 256), 256, 0, stream>>>(A, ts1, ts2, tgam, tbet, perm1, perm2,
                                        ikPf, frP, tlBP, tlb, Zd);
  k4<<<2048, 256, 0, stream>>>(Zd, ik2Pf, fr2P, Cb);
  k_statsP<<<400, 256, 0, stream>>>(Cb, 204800L, zs1, zs2);
  k5<<<dim3(4, 256), 256, 0, stream>>>(x, Cb, rwB, scRP, shRP, zs1, zs2, t2g, t2b, perm2, out);
}

// Round 13
// 872.834 us; speedup vs baseline: 2.1356x; 1.0229x over previous
//
#include <hip/hip_runtime.h>
#include <cstdint>
#include <cstddef>

namespace {
constexpr float EPS_ = 1e-5f;
}

using u16 = unsigned short;
typedef __attribute__((ext_vector_type(8))) short bf16x8;
typedef __attribute__((ext_vector_type(4))) float f32x4;

static __device__ __forceinline__ float bf2f(u16 u) {
  union { unsigned int i; float f; } x; x.i = ((unsigned int)u) << 16; return x.f;
}
static __device__ __forceinline__ u16 f2bf(float f) {
  union { float f; unsigned int i; } x; x.f = f;
  unsigned int r = x.i + 0x7fff + ((x.i >> 16) & 1);
  return (u16)(r >> 16);
}

#define OUT16(a, wv, xv) \
  a[0][0]=fmaf(wv.x,xv.x,a[0][0]); a[0][1]=fmaf(wv.x,xv.y,a[0][1]); \
  a[0][2]=fmaf(wv.x,xv.z,a[0][2]); a[0][3]=fmaf(wv.x,xv.w,a[0][3]); \
  a[1][0]=fmaf(wv.y,xv.x,a[1][0]); a[1][1]=fmaf(wv.y,xv.y,a[1][1]); \
  a[1][2]=fmaf(wv.y,xv.z,a[1][2]); a[1][3]=fmaf(wv.y,xv.w,a[1][3]); \
  a[2][0]=fmaf(wv.z,xv.x,a[2][0]); a[2][1]=fmaf(wv.z,xv.y,a[2][1]); \
  a[2][2]=fmaf(wv.z,xv.z,a[2][2]); a[2][3]=fmaf(wv.z,xv.w,a[2][3]); \
  a[3][0]=fmaf(wv.w,xv.x,a[3][0]); a[3][1]=fmaf(wv.w,xv.y,a[3][1]); \
  a[3][2]=fmaf(wv.w,xv.z,a[3][2]); a[3][3]=fmaf(wv.w,xv.w,a[3][3]);

// ---------- prep0: channel permutations sorted by floor(theta) ----------
__global__ __launch_bounds__(128) void k_prep0(
    const float* __restrict__ thin, const float* __restrict__ thout,
    int* __restrict__ perm1, int* __restrict__ perm2,
    float* __restrict__ ikPf, float* __restrict__ frP,
    float* __restrict__ ik2Pf, float* __restrict__ fr2P) {
  __shared__ float ikL[128], ik2L[128];
  const int c = threadIdx.x;
  float t1 = thin[c], t2 = thout[c];
  float f1 = floorf(t1), f2 = floorf(t2);
  ikL[c] = f1; ik2L[c] = f2;
  __syncthreads();
  int r1 = 0, r2 = 0;
  for (int j = 0; j < 128; j++) {
    r1 += (ikL[j] < f1) || (ikL[j] == f1 && j < c);
    r2 += (ik2L[j] < f2) || (ik2L[j] == f2 && j < c);
  }
  perm1[r1] = c; ikPf[r1] = f1; frP[r1] = t1 - f1;
  perm2[r2] = c; ik2Pf[r2] = f2; fr2P[r2] = t2 - f2;
}

// ---------- prep1: mask + permuted weight tables (bf16 op-major for MFMA B) ----------
__global__ __launch_bounds__(256) void k_prep1(
    const float* __restrict__ fm, const float* __restrict__ Wl,
    const float* __restrict__ dw, const float* __restrict__ rw, const float* __restrict__ tw,
    const int* __restrict__ perm1, const int* __restrict__ perm2,
    float* __restrict__ mskT, u16* __restrict__ WlB, u16* __restrict__ dwB,
    u16* __restrict__ rwB, u16* __restrict__ tlBP) {
  int i = blockIdx.x * 256 + threadIdx.x;
  if (i < 1600) { int c = i / 25, w = i % 25; mskT[c*25 + w] = tanhf(fm[w*64 + c]) + 1.0f; }
  if (i < 8192) {
    int dp = i >> 6, c = i & 63;
    WlB[i] = f2bf(Wl[c*128 + perm1[dp]]);
    dwB[i] = f2bf(dw[perm1[dp]*64 + c]);
    rwB[i] = f2bf(rw[perm2[dp]*64 + c]);
  }
  if (i < 16384) { int op = i >> 7, cp = i & 127; tlBP[i] = f2bf(tw[perm2[op]*128 + perm1[cp]]); }
}

// ---------- second moments of x: per-block partials, NO global atomics ----------
__global__ __launch_bounds__(256) void k_mom(const float* __restrict__ x,
    float* __restrict__ part) {
  __shared__ float xs[100][68];
  const int n = blockIdx.x >> 2, quarter = blockIdx.x & 3, tid = threadIdx.x;
  const int ci = (tid >> 4) * 4, cj = (tid & 15) * 4;
  float ae[4][4], ao[4][4], se[4], so[4];
  #pragma unroll
  for (int i = 0; i < 4; i++) {
    se[i] = 0.f; so[i] = 0.f;
    #pragma unroll
    for (int j = 0; j < 4; j++) { ae[i][j] = 0.f; ao[i][j] = 0.f; }
  }
  const float* xb = x + (size_t)n * 102400;
  float4 pf[7];
  #pragma unroll
  for (int k = 0; k < 7; k++) {
    int e = tid + k*256;
    if (e < 1600) { int c = e/25, q = e - c*25;
      pf[k] = *(const float4*)&xb[(size_t)c*1600 + (quarter*16)*25 + q*4]; }
  }
  for (int it = 0; it < 4; it++) {
    #pragma unroll
    for (int k = 0; k < 7; k++) {
      int e = tid + k*256;
      if (e < 1600) {
        int c = e/25, q = e - c*25;
        xs[q*4+0][c] = pf[k].x; xs[q*4+1][c] = pf[k].y;
        xs[q*4+2][c] = pf[k].z; xs[q*4+3][c] = pf[k].w;
      }
    }
    __syncthreads();
    if (it < 3) {
      const int toff = quarter*16 + (it+1)*4;
      #pragma unroll
      for (int k = 0; k < 7; k++) {
        int e = tid + k*256;
        if (e < 1600) { int c = e/25, q = e - c*25;
          pf[k] = *(const float4*)&xb[(size_t)c*1600 + toff*25 + q*4]; }
      }
    }
    #pragma unroll
    for (int tl = 0; tl < 4; tl++) {
      #pragma unroll 5
      for (int vv = 0; vv < 25; vv++) {
        const int s = tl*25 + vv;
        const float4 ra = *(const float4*)&xs[s][ci];
        const float4 rb = *(const float4*)&xs[s][cj];
        if ((tl & 1) == 0) {
          OUT16(ae, ra, rb);
          if (cj == 0) { se[0] += ra.x; se[1] += ra.y; se[2] += ra.z; se[3] += ra.w; }
        } else {
          OUT16(ao, ra, rb);
          if (cj == 0) { so[0] += ra.x; so[1] += ra.y; so[2] += ra.z; so[3] += ra.w; }
        }
      }
    }
    __syncthreads();
  }
  float* pb = part + (size_t)blockIdx.x * 8320;
  #pragma unroll
  for (int i = 0; i < 4; i++) {
    #pragma unroll
    for (int j = 0; j < 4; j++) {
      pb[tid*16 + i*4 + j]        = ae[i][j] + ao[i][j];
      pb[4096 + tid*16 + i*4 + j] = ae[i][j];
    }
  }
  if (cj == 0) {
    #pragma unroll
    for (int i = 0; i < 4; i++) {
      pb[8192 + (tid>>4)*4 + i] = se[i] + so[i];
      pb[8256 + (tid>>4)*4 + i] = se[i];
    }
  }
}

// ---------- reduce k_mom partials ----------
__global__ __launch_bounds__(256) void k_red(const float* __restrict__ part,
    float* __restrict__ Sxa, float* __restrict__ Sxe,
    float* __restrict__ suma, float* __restrict__ sume) {
  const int f = blockIdx.x*256 + threadIdx.x;
  if (f >= 8320) return;
  const int b0 = blockIdx.y * 64;
  float s = 0.f;
  for (int b = b0; b < b0 + 64; b++) s += part[(size_t)b*8320 + f];
  if (f < 8192) {
    const int half = f >> 12;
    const int q = f & 4095;
    const int t0 = q >> 4, idx = q & 15;
    const int ci = (t0 >> 4)*4 + (idx >> 2);
    const int cj = (t0 & 15)*4 + (idx & 3);
    atomicAdd(half ? &Sxe[ci*64 + cj] : &Sxa[ci*64 + cj], s);
  } else if (f < 8256) {
    atomicAdd(&suma[f - 8192], s);
  } else {
    atomicAdd(&sume[f - 8256], s);
  }
}

// ---------- analytic bn scale/shift for down (perm1) & res (perm2) ----------
__global__ __launch_bounds__(256) void k_fin(
    const float* __restrict__ dw, const float* __restrict__ dbg, const float* __restrict__ dbb,
    const float* __restrict__ rw, const float* __restrict__ rbg, const float* __restrict__ rbb,
    const int* __restrict__ perm1, const int* __restrict__ perm2,
    const float* __restrict__ Sxa, const float* __restrict__ Sxe,
    const float* __restrict__ suma, const float* __restrict__ sume,
    float* __restrict__ scDP, float* __restrict__ shDP,
    float* __restrict__ scRP, float* __restrict__ shRP) {
  __shared__ float SA[4096], SE[4096], sa[64], seL[64];
  const int tid = threadIdx.x;
  for (int i = tid; i < 4096; i += 256) { SA[i] = Sxa[i]; SE[i] = Sxe[i]; }
  if (tid < 64) { sa[tid] = suma[tid]; seL[tid] = sume[tid]; }
  __syncthreads();
  const bool down = tid < 128;
  const int p = tid & 127;
  const int o = down ? perm1[p] : perm2[p];
  const float* w = down ? dw : rw;
  const float* SS = down ? SA : SE;
  const float* sv = down ? sa : seL;
  const float iS = down ? (1.f/409600.f) : (1.f/204800.f);
  float wr[64];
  #pragma unroll
  for (int c = 0; c < 64; c += 4) {
    float4 t = *(const float4*)&w[o*64 + c];
    wr[c] = t.x; wr[c+1] = t.y; wr[c+2] = t.z; wr[c+3] = t.w;
  }
  float mu = 0.f, q = 0.f;
  for (int c = 0; c < 64; c++) {
    mu = fmaf(wr[c], sv[c], mu);
    float pp = 0.f;
    #pragma unroll 8
    for (int c2 = 0; c2 < 64; c2++) pp = fmaf(SS[c*64 + c2], wr[c2], pp);
    q = fmaf(wr[c], pp, q);
  }
  mu *= iS; q *= iS;
  float var = fmaxf(q - mu*mu, 0.f);
  float g = down ? dbg[o] : rbg[o];
  float b = down ? dbb[o] : rbb[o];
  float sc = g * rsqrtf(var + EPS_);
  if (down) { scDP[p] = sc; shDP[p] = b - mu*sc; }
  else      { scRP[p] = sc; shRP[p] = b - mu*sc; }
}

// ---------- K1 (fused MFMA): GCN GEMM -> A  AND  down GEMM -> D (bf16, lives in d_out) ----------
// Direct dual staging (xsT + masked/shifted xmT built from registers, no remap pass),
// dual ys buffers -> single barrier epilogue with fused copy-out.
__global__ __launch_bounds__(256) void k1(
    const float* __restrict__ x, const u16* __restrict__ WlB, const u16* __restrict__ dwB,
    const float* __restrict__ mskT, const int* __restrict__ perm1,
    u16* __restrict__ A, u16* __restrict__ D) {
  __shared__ __align__(16) u16 xsT[64][72];   // raw x^T bf16 (rows 50..63 garbage, outputs discarded)
  __shared__ __align__(16) u16 xmT[64][72];   // masked+shifted bf16
  __shared__ __align__(16) u16 ysD[50][136];
  __shared__ __align__(16) u16 ysA[50][136];
  __shared__ int dmL[128];
  const int tg = blockIdx.x, n = blockIdx.y, tid = threadIdx.x;
  const int t2 = tg * 2;
  if (tid < 128) dmL[tid] = perm1[tid] % 25;
  const float* xb = x + (size_t)n * 102400 + (size_t)t2 * 25;
  // stage raw + masked/shifted in one pass (float2 per lane covers samples q*2, q*2+1)
  for (int e = tid; e < 1600; e += 256) {
    int c = e / 25, q = e - c*25;
    int cm = c; if (cm >= 50) cm -= 50; else if (cm >= 25) cm -= 25;
    const float2 v2 = *(const float2*)&xb[(size_t)c*1600 + q*2];
    const int s0 = q*2, s1 = q*2 + 1;
    const int tl0 = (s0 >= 25), v0 = s0 - tl0*25;
    const int tl1 = (s1 >= 25), v1 = s1 - tl1*25;
    xsT[s0][c] = f2bf(v2.x);
    xsT[s1][c] = f2bf(v2.y);
    int w0 = v0 - cm; if (w0 < 0) w0 += 25;
    int w1 = v1 - cm; if (w1 < 0) w1 += 25;
    xmT[tl0*25 + w0][c] = f2bf(v2.x * mskT[c*25 + w0]);
    xmT[tl1*25 + w1][c] = f2bf(v2.y * mskT[c*25 + w1]);
  }
  __syncthreads();
  const int w = tid >> 6, l = tid & 63;
  const int lc = l & 15, kg = l >> 4;
  f32x4 accA[8], accD[8];
  #pragma unroll
  for (int nt = 0; nt < 8; nt++) {
    accA[nt][0]=0.f; accA[nt][1]=0.f; accA[nt][2]=0.f; accA[nt][3]=0.f;
    accD[nt][0]=0.f; accD[nt][1]=0.f; accD[nt][2]=0.f; accD[nt][3]=0.f;
  }
  #pragma unroll
  for (int ks = 0; ks < 2; ks++) {
    const bf16x8 am = *(const bf16x8*)&xmT[w*16 + lc][ks*32 + kg*8];
    const bf16x8 ax = *(const bf16x8*)&xsT[w*16 + lc][ks*32 + kg*8];
    #pragma unroll
    for (int nt = 0; nt < 8; nt++) {
      const bf16x8 bW = *(const bf16x8*)&WlB[(size_t)(nt*16 + lc)*64 + ks*32 + kg*8];
      const bf16x8 bD = *(const bf16x8*)&dwB[(size_t)(nt*16 + lc)*64 + ks*32 + kg*8];
      accA[nt] = __builtin_amdgcn_mfma_f32_16x16x32_bf16(am, bW, accA[nt], 0, 0, 0);
      accD[nt] = __builtin_amdgcn_mfma_f32_16x16x32_bf16(ax, bD, accD[nt], 0, 0, 0);
    }
  }
  // D frags -> ysD, A frags (vertex shuffle) -> ysA : no barrier between, one after
  #pragma unroll
  for (int nt = 0; nt < 8; nt++) {
    const int dp = nt*16 + lc;
    const int dm = dmL[dp];
    #pragma unroll
    for (int r = 0; r < 4; r++) {
      const int s = w*16 + kg*4 + r;
      if (s < 50) {
        ysD[s][dp] = f2bf(accD[nt][r]);
        int tl = 0, wv = s; if (wv >= 25) { tl = 1; wv -= 25; }
        int v = wv + dm; if (v >= 25) v -= 25;
        ysA[tl*25 + v][dp] = f2bf(accA[nt][r]);
      }
    }
  }
  __syncthreads();
  u16* Dslab = D + (size_t)n*204800 + (size_t)t2*3200;
  u16* Aslab = A + (size_t)n*204800 + (size_t)t2*3200;
  for (int i = tid; i < 1600; i += 256) {
    if (i < 800) {
      int s = i >> 4, ch = i & 15;
      *(int4*)(Dslab + s*128 + ch*8) = *(const int4*)&ysD[s][ch*8];
    } else {
      int j = i - 800;
      int s = j >> 4, ch = j & 15;
      *(int4*)(Aslab + s*128 + ch*8) = *(const int4*)&ysA[s][ch*8];
    }
  }
}

// ---------- stats over 3200 features (v,dp) of A ----------
__global__ __launch_bounds__(256) void k_statsA(const u16* __restrict__ A,
    float* __restrict__ gs1, float* __restrict__ gs2) {
  const int foct = blockIdx.x*256 + threadIdx.x;
  if (foct >= 400) return;
  const int rb = blockIdx.y * 128;
  const size_t f0 = (size_t)foct * 8;
  float s1[8], s2[8];
  #pragma unroll
  for (int i = 0; i < 8; i++) { s1[i] = 0.f; s2[i] = 0.f; }
  for (int r = 0; r < 128; r++) {
    union { int4 i4; u16 u[8]; } raw;
    raw.i4 = *(const int4*)(A + (size_t)(rb + r)*3200 + f0);
    #pragma unroll
    for (int i = 0; i < 8; i++) { float v = bf2f(raw.u[i]); s1[i] += v; s2[i] = fmaf(v, v, s2[i]); }
  }
  #pragma unroll
  for (int i = 0; i < 8; i++) { atomicAdd(&gs1[f0+i], s1[i]); atomicAdd(&gs2[f0+i], s2[i]); }
}

// ---------- finalize gcn bn scale/shift per (v,dp) ----------
__global__ __launch_bounds__(256) void k_fin2(
    const float* __restrict__ gs1, const float* __restrict__ gs2,
    const float* __restrict__ gg, const float* __restrict__ gb,
    const int* __restrict__ perm1,
    float* __restrict__ scG, float* __restrict__ shG) {
  int f = blockIdx.x*256 + threadIdx.x;
  if (f >= 3200) return;
  int v = f >> 7, dp = f & 127;
  int d = perm1[dp];
  float m = gs1[f] * (1.f/16384.f);
  float var = fmaxf(gs2[f]*(1.f/16384.f) - m*m, 0.f);
  float r = rsqrtf(var + EPS_);
  float sc = gg[v*128 + d] * r;
  scG[f] = sc; shG[f] = gb[v*128 + d] - m*sc;
}

// ---------- K2f: streaming y = relu(bn1d(h)+bn(down)) with fused ts1/ts2 stats ----------
__global__ __launch_bounds__(256) void k2f(
    u16* __restrict__ A, const u16* __restrict__ D,
    const float* __restrict__ scG, const float* __restrict__ shG,
    const float* __restrict__ scDP, const float* __restrict__ shDP,
    float* __restrict__ ts1, float* __restrict__ ts2) {
  const int tid = threadIdx.x;
  const int f0 = (tid & 15) * 8;
  const int rg = tid >> 4;
  const long rb = (long)blockIdx.x * 400;
  float sD[8], hD[8];
  #pragma unroll
  for (int i = 0; i < 8; i++) { sD[i] = scDP[f0+i]; hD[i] = shDP[f0+i]; }
  float s1[8], s2[8];
  #pragma unroll
  for (int i = 0; i < 8; i++) { s1[i] = 0.f; s2[i] = 0.f; }
  for (int r = rg; r < 400; r += 16) {
    const long row = rb + r;
    const int v = (int)(row % 25);
    union { int4 i4; u16 u[8]; } araw, draw, o;
    araw.i4 = *(const int4*)(A + row*128 + f0);
    draw.i4 = *(const int4*)(D + row*128 + f0);
    const float4 g0 = *(const float4*)&scG[v*128 + f0];
    const float4 g1 = *(const float4*)&scG[v*128 + f0 + 4];
    const float4 b0 = *(const float4*)&shG[v*128 + f0];
    const float4 b1 = *(const float4*)&shG[v*128 + f0 + 4];
    const float gg_[8] = {g0.x,g0.y,g0.z,g0.w,g1.x,g1.y,g1.z,g1.w};
    const float bb_[8] = {b0.x,b0.y,b0.z,b0.w,b1.x,b1.y,b1.z,b1.w};
    #pragma unroll
    for (int i = 0; i < 8; i++) {
      float y = fmaf(bf2f(araw.u[i]), gg_[i], bb_[i]) + fmaf(bf2f(draw.u[i]), sD[i], hD[i]);
      y = fmaxf(y, 0.f);
      s1[i] += y; s2[i] = fmaf(y, y, s2[i]);
      o.u[i] = f2bf(y);
    }
    *(int4*)(A + row*128 + f0) = o.i4;
  }
  __shared__ float m1[16][128], m2[16][128];
  #pragma unroll
  for (int i = 0; i < 8; i++) { m1[rg][f0+i] = s1[i]; m2[rg][f0+i] = s2[i]; }
  __syncthreads();
  if (tid < 128) {
    float a = 0.f, b = 0.f;
    #pragma unroll
    for (int g = 0; g < 16; g++) { a += m1[g][tid]; b += m2[g][tid]; }
    atomicAdd(&ts1[tid], a); atomicAdd(&ts2[tid], b);
  }
}

// ---------- per-128-channel stats (channel-last rows) ----------
__global__ __launch_bounds__(256) void k_statsP(const u16* __restrict__ P, long nrows,
    float* __restrict__ s1g, float* __restrict__ s2g) {
  const int tid = threadIdx.x;
  const int f0 = (tid & 15) * 8;
  const int rg = tid >> 4;
  long rpb = nrows / gridDim.x;
  long rb = (long)blockIdx.x * rpb;
  float s1[8], s2[8];
  #pragma unroll
  for (int i = 0; i < 8; i++) { s1[i] = 0.f; s2[i] = 0.f; }
  for (long r = rg; r < rpb; r += 16) {
    union { int4 i4; u16 u[8]; } raw;
    raw.i4 = *(const int4*)(P + (rb + r)*128 + f0);
    #pragma unroll
    for (int i = 0; i < 8; i++) { float v = bf2f(raw.u[i]); s1[i] += v; s2[i] = fmaf(v, v, s2[i]); }
  }
  __shared__ float m1[16][128], m2[16][128];
  #pragma unroll
  for (int i = 0; i < 8; i++) { m1[rg][f0+i] = s1[i]; m2[rg][f0+i] = s2[i]; }
  __syncthreads();
  if (tid < 128) {
    float a = 0.f, b = 0.f;
    #pragma unroll
    for (int g = 0; g < 16; g++) { a += m1[g][tid]; b += m2[g][tid]; }
    atomicAdd(&s1g[tid], a); atomicAdd(&s2g[tid], b);
  }
}

// ---------- K3 (MFMA, TB=4): bn(y)+shift(theta_in,1)+tl GEMM+bias+relu -> Z bf16 (d_out) ----------
__global__ __launch_bounds__(256) void k3(
    const u16* __restrict__ Y,
    const float* __restrict__ ts1, const float* __restrict__ ts2,
    const float* __restrict__ tgamma, const float* __restrict__ tbeta,
    const int* __restrict__ perm1, const int* __restrict__ perm2,
    const float* __restrict__ ikPf, const float* __restrict__ frP,
    const u16* __restrict__ tlBP, const float* __restrict__ tlb,
    u16* __restrict__ Z) {
  __shared__ __align__(16) u16 smem[128*136];
  __shared__ float scL[128], shL[128], frL[128], tlbL[128];
  __shared__ int ikL[128];
  const int tg = blockIdx.x, n = blockIdx.y, tid = threadIdx.x;
  const int t4 = tg * 4;
  if (tid < 128) {
    int cp = tid, c = perm1[cp];
    float m = ts1[cp] * (1.f/409600.f);
    float var = fmaxf(ts2[cp]*(1.f/409600.f) - m*m, 0.f);
    float r = rsqrtf(var + EPS_);
    float sc = tgamma[c] * r;
    scL[cp] = sc; shL[cp] = tbeta[c] - m*sc;
    ikL[cp] = (int)ikPf[cp]; frL[cp] = frP[cp];
    tlbL[cp] = tlb[perm2[cp]];
  }
  __syncthreads();
  const u16* Yb = Y + (size_t)n * 204800;
  for (int e = tid; e < 3200; e += 256) {
    int cp = e & 127, v = e >> 7;
    int ik = ikL[cp];
    float fr = frL[cp], sc = scL[cp], sh = shL[cp];
    const u16* base = Yb + v*128 + cp;
    float y[5];
    #pragma unroll
    for (int j = 0; j < 5; j++) {
      int t = t4 + ik + j;
      y[j] = (t >= 0 && t < 64) ? fmaf(bf2f(base[(size_t)t*3200]), sc, sh) : 0.f;
    }
    #pragma unroll
    for (int tl = 0; tl < 4; tl++)
      smem[(tl*25 + v)*136 + cp] = f2bf((1.f - fr)*y[tl] + fr*y[tl+1]);
  }
  __syncthreads();
  const int w = tid >> 6, l = tid & 63;
  const int lc = l & 15, kg = l >> 4;
  bf16x8 a[2][4];
  #pragma unroll
  for (int mi = 0; mi < 2; mi++) {
    const int row = (w + mi*4)*16 + lc;
    #pragma unroll
    for (int ks = 0; ks < 4; ks++)
      a[mi][ks] = *(const bf16x8*)&smem[row*136 + ks*32 + kg*8];
  }
  __syncthreads();
  #pragma unroll
  for (int nt = 0; nt < 8; nt++) {
    const int op = nt*16 + lc;
    bf16x8 b[4];
    #pragma unroll
    for (int ks = 0; ks < 4; ks++)
      b[ks] = *(const bf16x8*)&tlBP[(size_t)op*128 + ks*32 + kg*8];
    const float bb = tlbL[op];
    #pragma unroll
    for (int mi = 0; mi < 2; mi++) {
      f32x4 acc; acc[0]=bb; acc[1]=bb; acc[2]=bb; acc[3]=bb;
      #pragma unroll
      for (int ks = 0; ks < 4; ks++)
        acc = __builtin_amdgcn_mfma_f32_16x16x32_bf16(a[mi][ks], b[ks], acc, 0, 0, 0);
      #pragma unroll
      for (int r = 0; r < 4; r++) {
        const int s = (w + mi*4)*16 + kg*4 + r;
        if (s < 100) smem[s*136 + op] = f2bf(fmaxf(acc[r], 0.f));
      }
    }
  }
  __syncthreads();
  u16* Zb = Z + (size_t)n*204800 + (size_t)t4*3200;
  for (int i = tid; i < 1600; i += 256) {
    int s = i >> 4, ch = i & 15;
    *(int4*)(Zb + s*128 + ch*8) = *(const int4*)&smem[s*136 + ch*8];
  }
}

// ---------- K4: stride-2 shift(theta_out) Z -> C[n][tp][v][op] bf16 ----------
__global__ __launch_bounds__(256) void k4(const u16* __restrict__ Z,
    const float* __restrict__ ik2Pf, const float* __restrict__ fr2P,
    u16* __restrict__ C) {
  __shared__ int ikL[128];
  __shared__ float frL[128];
  if (threadIdx.x < 128) { ikL[threadIdx.x] = (int)ik2Pf[threadIdx.x]; frL[threadIdx.x] = fr2P[threadIdx.x]; }
  __syncthreads();
  for (size_t idx = (size_t)blockIdx.x*256 + threadIdx.x; idx < 26214400ull; idx += (size_t)gridDim.x*256) {
    int op = (int)(idx & 127);
    int v  = (int)((idx >> 7) % 25);
    int tp = (int)((idx / 3200) & 31);
    int n  = (int)(idx / 102400);
    int t0 = 2*tp + ikL[op];
    float fr = frL[op];
    const u16* base = Z + (size_t)n*204800 + v*128 + op;
    float a0 = (t0 >= 0 && t0 < 64) ? bf2f(base[(size_t)t0*3200]) : 0.f;
    int t1 = t0 + 1;
    float a1 = (t1 >= 0 && t1 < 64) ? bf2f(base[(size_t)t1*3200]) : 0.f;
    C[idx] = f2bf((1.f - fr)*a0 + fr*a1);
  }
}

// ---------- K5 (MFMA, 8tp/block): res GEMM + out = relu(bn2(C)+bn(res)) -> NCHW fp32 ----------
__global__ __launch_bounds__(256) void k5(
    const float* __restrict__ x, const u16* __restrict__ C,
    const u16* __restrict__ rwB,
    const float* __restrict__ scRP, const float* __restrict__ shRP,
    const float* __restrict__ zs1, const float* __restrict__ zs2,
    const float* __restrict__ t2g, const float* __restrict__ t2b,
    const int* __restrict__ perm2, float* __restrict__ out) {
  __shared__ __align__(16) u16 xsT[50][72];
  __shared__ __align__(16) u16 ch[6400];
  __shared__ float ys[128][52];
  __shared__ float sc2L[128], sh2L[128];
  __shared__ int p2L[128];
  const int tpg = blockIdx.x, n = blockIdx.y, tid = threadIdx.x;
  if (tid < 128) {
    int op = tid, o = perm2[op];
    float m = zs1[op] * (1.f/204800.f);
    float var = fmaxf(zs2[op]*(1.f/204800.f) - m*m, 0.f);
    float r = rsqrtf(var + EPS_);
    float sc = t2g[o] * r;
    sc2L[op] = sc; sh2L[op] = t2b[o] - m*sc;
    p2L[op] = o;
  }
  const float* xb = x + (size_t)n * 102400;
  const int w = tid >> 6, l = tid & 63;
  const int lc = l & 15, kg = l >> 4;
  for (int sub = 0; sub < 4; sub++) {
    const int tp2 = tpg*8 + sub*2;
    for (int e = tid; e < 3200; e += 256) {
      int tl = e / 1600, r = e - tl*1600, c = r / 25, v = r - c*25;
      xsT[tl*25 + v][c] = f2bf(xb[(size_t)c*1600 + 2*(tp2+tl)*25 + v]);
    }
    {
      int4* dst = (int4*)ch;
      const int4* src = (const int4*)(C + (size_t)n*102400 + (size_t)tp2*3200);
      for (int i = tid; i < 800; i += 256) dst[i] = src[i];
    }
    __syncthreads();
    f32x4 acc[8];
    #pragma unroll
    for (int nt = 0; nt < 8; nt++) { acc[nt][0]=0.f; acc[nt][1]=0.f; acc[nt][2]=0.f; acc[nt][3]=0.f; }
    #pragma unroll
    for (int ks = 0; ks < 2; ks++) {
      const bf16x8 a = *(const bf16x8*)&xsT[w*16 + lc][ks*32 + kg*8];
      #pragma unroll
      for (int nt = 0; nt < 8; nt++) {
        const bf16x8 b = *(const bf16x8*)&rwB[(size_t)(nt*16 + lc)*64 + ks*32 + kg*8];
        acc[nt] = __builtin_amdgcn_mfma_f32_16x16x32_bf16(a, b, acc[nt], 0, 0, 0);
      }
    }
    #pragma unroll
    for (int nt = 0; nt < 8; nt++) {
      const int op = nt*16 + lc;
      const float sR = scRP[op], hR = shRP[op];
      const float sz = sc2L[op], hz = sh2L[op];
      #pragma unroll
      for (int r = 0; r < 4; r++) {
        const int s = w*16 + kg*4 + r;
        if (s < 50) {
          float zv = fmaf(bf2f(ch[s*128 + op]), sz, hz);
          float rv = fmaf(acc[nt][r], sR, hR);
          ys[op][s] = fmaxf(zv + rv, 0.f);
        }
      }
    }
    __syncthreads();
    for (int i = tid; i < 6400; i += 256) {
      int op = i / 50, k = i - op*50;
      out[((size_t)(n*128 + p2L[op]))*800 + tp2*25 + k] = ys[op][k];
    }
    __syncthreads();
  }
}

extern "C" void kernel_launch(void* const* d_in, const int* in_sizes, int n_in,
                              void* d_out, int out_size, void* d_ws, size_t ws_size,
                              hipStream_t stream) {
  (void)in_sizes; (void)n_in; (void)out_size;
  if (ws_size < 105200000ull) return;  // clean fail instead of OOB crash
  const float* x     = (const float*)d_in[0];
  const float* Wl    = (const float*)d_in[1];
  const float* fm    = (const float*)d_in[3];
  const float* gg    = (const float*)d_in[4];
  const float* gb    = (const float*)d_in[5];
  const float* dw    = (const float*)d_in[6];
  const float* dbg   = (const float*)d_in[8];
  const float* dbb   = (const float*)d_in[9];
  const float* tgam  = (const float*)d_in[10];
  const float* tbet  = (const float*)d_in[11];
  const float* thin  = (const float*)d_in[12];
  const float* tw    = (const float*)d_in[13];
  const float* tlb   = (const float*)d_in[14];
  const float* thout = (const float*)d_in[15];
  const float* t2g   = (const float*)d_in[16];
  const float* t2b   = (const float*)d_in[17];
  const float* rw    = (const float*)d_in[18];
  const float* rbg   = (const float*)d_in[20];
  const float* rbb   = (const float*)d_in[21];
  float* out = (float*)d_out;
  u16* Zd = (u16*)d_out;            // d_out hosts: D (k1->k2f), then Z (k3->k4), then final out
  u16* Dd = (u16*)d_out;

  u16* A  = (u16*)d_ws;             // [256][64][25][128] bf16 = 104,857,600 B
  u16* Cb = A;                      // C aliases A (A dead after k3)
  float* part = (float*)d_ws;       // k_mom partials (34 MB) — dead before k1 writes A
  float* mskT = (float*)((char*)d_ws + 104857600);   // 1600 f
  u16*  WlB   = (u16*)(mskT + 1600);                 // 8192 u16
  u16*  dwB   = WlB + 8192;                          // 8192 u16
  u16*  rwB   = dwB + 8192;                          // 8192 u16
  u16*  tlBP  = (u16*)((float*)(dwB + 8192) + 8192); // 16384 u16
  float* scG  = (float*)(tlBP + 16384);              // 3200
  float* shG  = scG + 3200;         // 3200
  float* scDP = shG + 3200;         // 128
  float* shDP = scDP + 128;
  float* scRP = shDP + 128;
  float* shRP = scRP + 128;
  float* ikPf = shRP + 128;
  float* frP  = ikPf + 128;
  float* ik2Pf= frP + 128;
  float* fr2P = ik2Pf + 128;
  float* Sxa  = fr2P + 128;         // zero region start (15232 floats)
  float* Sxe  = Sxa + 4096;
  float* suma = Sxe + 4096;
  float* sume = suma + 64;
  float* gs1  = sume + 64;
  float* gs2  = gs1 + 3200;
  float* ts1  = gs2 + 3200;
  float* ts2  = ts1 + 128;
  float* zs1  = ts2 + 128;
  float* zs2  = zs1 + 128;
  int* perm1  = (int*)(zs2 + 128);
  int* perm2  = perm1 + 128;

  (void)hipMemsetAsync(Sxa, 0, 15232 * sizeof(float), stream);
  k_prep0<<<1, 128, 0, stream>>>(thin, thout, perm1, perm2, ikPf, frP, ik2Pf, fr2P);
  k_prep1<<<64, 256, 0, stream>>>(fm, Wl, dw, rw, tw, perm1, perm2, mskT, WlB, dwB, rwB, tlBP);
  k_mom<<<1024, 256, 0, stream>>>(x, part);
  k_red<<<dim3(33, 16), 256, 0, stream>>>(part, Sxa, Sxe, suma, sume);
  k_fin<<<1, 256, 0, stream>>>(dw, dbg, dbb, rw, rbg, rbb, perm1, perm2,
                               Sxa, Sxe, suma, sume, scDP, shDP, scRP, shRP);
  k1<<<dim3(32, 256), 256, 0, stream>>>(x, WlB, dwB, mskT, perm1, A, Dd);
  k_statsA<<<dim3(2, 128), 256, 0, stream>>>(A, gs1, gs2);
  k_fin2<<<13, 256, 0, stream>>>(gs1, gs2, gg, gb, perm1, scG, shG);
  k2f<<<1024, 256, 0, stream>>>(A, Dd, scG, shG, scDP, shDP, ts1, ts2);
  k3<<<dim3(16, 256), 256, 0, stream>>>(A, ts1, ts2, tgam, tbet, perm1, perm2,
                                        ikPf, frP, tlBP, tlb, Zd);
  k4<<<2048, 256, 0, stream>>>(Zd, ik2Pf, fr2P, Cb);
  k_statsP<<<400, 256, 0, stream>>>(Cb, 204800L, zs1, zs2);
  k5<<<dim3(4, 256), 256, 0, stream>>>(x, Cb, rwB, scRP, shRP, zs1, zs2, t2g, t2b, perm2, out);
}